// Round 4
// baseline (6254.062 us; speedup 1.0000x reference)
//
#include <hip/hip_runtime.h>
#include <hip/hip_bf16.h>
#include <math.h>

#define H 768
#define NH 12
#define DH 64
#define NL 6
#define FF 3072
#define LL 4096
#define GG 64
#define NCMAX 32

typedef unsigned short u16;
typedef __attribute__((ext_vector_type(8))) unsigned short us8;
typedef __attribute__((ext_vector_type(4))) unsigned short us4;
typedef __attribute__((ext_vector_type(8))) __bf16 bf16x8;
typedef __attribute__((ext_vector_type(4))) float f32x4;

__device__ __forceinline__ float bf2f(u16 u) {
  unsigned v = ((unsigned)u) << 16;
  return __builtin_bit_cast(float, v);
}
__device__ __forceinline__ u16 f2bf(float f) {
  unsigned u = __builtin_bit_cast(unsigned, f);
  unsigned r = (u + 0x7fffu + ((u >> 16) & 1u)) >> 16;
  return (u16)r;
}
__device__ __forceinline__ float geluf(float a) {
  return 0.5f * a * (1.f + erff(a * 0.70710678118654752440f));
}
__device__ __forceinline__ float wredsum(float v) {
  #pragma unroll
  for (int o = 32; o; o >>= 1) v += __shfl_xor(v, o);
  return v;
}
__device__ __forceinline__ float wredmax(float v) {
  #pragma unroll
  for (int o = 32; o; o >>= 1) v = fmaxf(v, __shfl_xor(v, o));
  return v;
}

// ---------------- embed + LN (f32 inputs) ----------------
__global__ __launch_bounds__(256) void embed_ln_k(
    const float* __restrict__ et, const float* __restrict__ ep, const int* __restrict__ ids,
    const float* __restrict__ sc, const float* __restrict__ bi,
    float* __restrict__ x, u16* __restrict__ xb)
{
  int r = blockIdx.x, t = threadIdx.x;
  int tok = ids[r];
  if (tok < 0) tok = 0;
  if (tok >= 50272) tok = 50271;
  __shared__ float red[4];
  float v[3];
  #pragma unroll
  for (int e = 0; e < 3; ++e) {
    int c = t + e * 256;
    v[e] = et[(size_t)tok * H + c] + ep[(size_t)r * H + c];
  }
  float s = v[0] + v[1] + v[2];
  s = wredsum(s);
  if ((t & 63) == 0) red[t >> 6] = s;
  __syncthreads();
  float mean = (red[0] + red[1] + red[2] + red[3]) * (1.f / 768.f);
  __syncthreads();
  float q = 0.f;
  #pragma unroll
  for (int e = 0; e < 3; ++e) { float d = v[e] - mean; q += d * d; }
  q = wredsum(q);
  if ((t & 63) == 0) red[t >> 6] = q;
  __syncthreads();
  float var = (red[0] + red[1] + red[2] + red[3]) * (1.f / 768.f);
  float rs = rsqrtf(var + 1e-5f);
  #pragma unroll
  for (int e = 0; e < 3; ++e) {
    int c = t + e * 256;
    float o = (v[e] - mean) * rs * sc[c] + bi[c];
    x[(size_t)r * H + c] = o;
    xb[(size_t)r * H + c] = f2bf(o);
  }
}

// ---------------- LN in place over f32 buffer ----------------
__global__ __launch_bounds__(256) void ln_k(
    const float* __restrict__ y, const float* __restrict__ sc, const float* __restrict__ bi,
    float* __restrict__ x, u16* __restrict__ xb)
{
  int r = blockIdx.x, t = threadIdx.x;
  __shared__ float red[4];
  float v[3];
  #pragma unroll
  for (int e = 0; e < 3; ++e) v[e] = y[(size_t)r * H + t + e * 256];
  float s = v[0] + v[1] + v[2];
  s = wredsum(s);
  if ((t & 63) == 0) red[t >> 6] = s;
  __syncthreads();
  float mean = (red[0] + red[1] + red[2] + red[3]) * (1.f / 768.f);
  __syncthreads();
  float q = 0.f;
  #pragma unroll
  for (int e = 0; e < 3; ++e) { float d = v[e] - mean; q += d * d; }
  q = wredsum(q);
  if ((t & 63) == 0) red[t >> 6] = q;
  __syncthreads();
  float var = (red[0] + red[1] + red[2] + red[3]) * (1.f / 768.f);
  float rs = rsqrtf(var + 1e-5f);
  #pragma unroll
  for (int e = 0; e < 3; ++e) {
    int c = t + e * 256;
    float o = (v[e] - mean) * rs * sc[c] + bi[c];
    x[(size_t)r * H + c] = o;
    xb[(size_t)r * H + c] = f2bf(o);
  }
}

// ---- MFMA GEMM: out = A(M,K)bf16 @ B(K,N)f32->bf16 + bias(f32) (+res, may be in-place) ----
template<int ACT, bool RES, bool OUTF32>
__global__ __launch_bounds__(256) void gemm_k(
    const u16* __restrict__ A, const float* __restrict__ B, const float* __restrict__ bias,
    const float* res, float* outF, u16* outB,
    int M, int N, int K)
{
  __shared__ u16 lsA[128 * 64];
  __shared__ u16 lsB[128 * 64];
  int t = threadIdx.x;
  int n0 = blockIdx.x * 128;
  int m0 = blockIdx.y * 128;
  int w = t >> 6, lane = t & 63;
  int wm = (w >> 1) * 64, wn = (w & 1) * 64;
  int cl = lane & 15, kgr = lane >> 4;
  f32x4 zero4 = {0.f, 0.f, 0.f, 0.f};
  f32x4 acc[4][4];
  #pragma unroll
  for (int i = 0; i < 4; ++i)
    #pragma unroll
    for (int j = 0; j < 4; ++j) acc[i][j] = zero4;
  us8 z8 = {0, 0, 0, 0, 0, 0, 0, 0};

  for (int k0 = 0; k0 < K; k0 += 64) {
    // stage A (bf16 activations)
    #pragma unroll
    for (int it = 0; it < 4; ++it) {
      int c = t + it * 256;
      int m = c >> 3, k8 = c & 7;
      us8 val = z8;
      int gm = m0 + m;
      if (gm < M) val = *reinterpret_cast<const us8*>(A + (size_t)gm * K + k0 + k8 * 8);
      *reinterpret_cast<us8*>(&lsA[m * 64 + ((k8 ^ (m & 7)) * 8)]) = val;
    }
    // stage B (f32 weights -> bf16), transposed into [n][k]
    #pragma unroll
    for (int it = 0; it < 4; ++it) {
      int c = t + it * 256;
      int n = c & 127, k8 = c >> 7;
      const float* bp = B + (size_t)(k0 + k8 * 8) * N + n0 + n;
      us8 val;
      #pragma unroll
      for (int jj = 0; jj < 8; ++jj) val[jj] = f2bf(bp[(size_t)jj * N]);
      *reinterpret_cast<us8*>(&lsB[n * 64 + ((k8 ^ (n & 7)) * 8)]) = val;
    }
    __syncthreads();
    #pragma unroll
    for (int kk = 0; kk < 2; ++kk) {
      bf16x8 fa[4], fb[4];
      int k8 = kk * 4 + kgr;
      #pragma unroll
      for (int i = 0; i < 4; ++i) {
        int mr = wm + i * 16 + cl;
        fa[i] = __builtin_bit_cast(bf16x8,
            *reinterpret_cast<const us8*>(&lsA[mr * 64 + ((k8 ^ (mr & 7)) * 8)]));
        int nr = wn + i * 16 + cl;
        fb[i] = __builtin_bit_cast(bf16x8,
            *reinterpret_cast<const us8*>(&lsB[nr * 64 + ((k8 ^ (nr & 7)) * 8)]));
      }
      #pragma unroll
      for (int i = 0; i < 4; ++i)
        #pragma unroll
        for (int j = 0; j < 4; ++j)
          acc[i][j] = __builtin_amdgcn_mfma_f32_16x16x32_bf16(fa[i], fb[j], acc[i][j], 0, 0, 0);
    }
    __syncthreads();
  }
  #pragma unroll
  for (int j = 0; j < 4; ++j) {
    int n = n0 + wn + j * 16 + cl;
    float bv = bias[n];
    #pragma unroll
    for (int i = 0; i < 4; ++i) {
      #pragma unroll
      for (int r = 0; r < 4; ++r) {
        int m = m0 + wm + i * 16 + kgr * 4 + r;
        if (m < M) {
          float vv = acc[i][j][r] + bv;
          if (ACT == 1) vv = geluf(vv);
          if (RES) vv += res[(size_t)m * N + n];
          if (OUTF32) outF[(size_t)m * N + n] = vv;
          else outB[(size_t)m * N + n] = f2bf(vv);
        }
      }
    }
  }
}

// ---------------- local (banded) attention ----------------
__global__ __launch_bounds__(256) void attn_local_k(
    const u16* __restrict__ q, const u16* __restrict__ k, const u16* __restrict__ v,
    const u16* __restrict__ kgp, const u16* __restrict__ vgp,
    const int* __restrict__ gpos, const unsigned char* __restrict__ isg,
    u16* __restrict__ out)
{
  int h = blockIdx.x;
  int q0 = blockIdx.y * 16;
  int nb = q0 >> 8;
  int cs = (nb - 1) * 256;
  int t = threadIdx.x;
  int i = t >> 4;
  int ql = t & 15;
  __shared__ float sS[16][840];
  __shared__ u16 sKV[64 * 64];
  __shared__ u16 sQ[16 * 64];
  us8 z8 = {0, 0, 0, 0, 0, 0, 0, 0};
  if (t < 128) {
    int r = t >> 3, d0 = (t & 7) * 8;
    *reinterpret_cast<us8*>(&sQ[r * 64 + d0]) =
        *reinterpret_cast<const us8*>(&q[(size_t)(q0 + r) * H + h * 64 + d0]);
  }
  for (int c = 0; c < 13; ++c) {
    #pragma unroll
    for (int it = 0; it < 2; ++it) {
      int idx = t + it * 256;
      int jj = idx >> 3, d8 = idx & 7;
      us8 val = z8;
      int j = c * 64 + jj;
      if (j < 768) {
        int pos = cs + j;
        if (pos >= 0 && pos < LL)
          val = *reinterpret_cast<const us8*>(&k[(size_t)pos * H + h * 64 + d8 * 8]);
      } else {
        int pos = gpos[j - 768];
        if (pos < 0) pos = 0;
        if (pos >= LL) pos = LL - 1;
        val = *reinterpret_cast<const us8*>(&kgp[(size_t)pos * H + h * 64 + d8 * 8]);
      }
      *reinterpret_cast<us8*>(&sKV[jj * 64 + ((d8 ^ (jj & 7)) * 8)]) = val;
    }
    __syncthreads();
    #pragma unroll
    for (int s = 0; s < 4; ++s) {
      int jj = ql + s * 16;
      float sc = 0.f;
      #pragma unroll
      for (int c8 = 0; c8 < 8; ++c8) {
        us8 qa = *reinterpret_cast<const us8*>(&sQ[i * 64 + c8 * 8]);
        us8 ka = *reinterpret_cast<const us8*>(&sKV[jj * 64 + ((c8 ^ (jj & 7)) * 8)]);
        #pragma unroll
        for (int u = 0; u < 8; ++u) sc += bf2f(qa[u]) * bf2f(ka[u]);
      }
      sc *= 0.125f;
      int j = c * 64 + jj;
      bool ok = true;
      if (j < 768) {
        int pos = cs + j;
        int d = pos - (q0 + i);
        int psafe = pos < 0 ? 0 : (pos >= LL ? LL - 1 : pos);
        ok = (pos >= 0) && (pos < LL) && (d >= -256) && (d <= 256) && (isg[psafe] == 0);
      }
      sS[i][j] = ok ? sc : -1e9f;
    }
    __syncthreads();
  }
  float mx = -1e30f;
  #pragma unroll
  for (int mm = 0; mm < 52; ++mm) mx = fmaxf(mx, sS[i][ql + mm * 16]);
  mx = fmaxf(mx, __shfl_xor(mx, 1));
  mx = fmaxf(mx, __shfl_xor(mx, 2));
  mx = fmaxf(mx, __shfl_xor(mx, 4));
  mx = fmaxf(mx, __shfl_xor(mx, 8));
  float sum = 0.f;
  #pragma unroll
  for (int mm = 0; mm < 52; ++mm) {
    int j = ql + mm * 16;
    float e = __expf(sS[i][j] - mx);
    sS[i][j] = e;
    sum += e;
  }
  sum += __shfl_xor(sum, 1);
  sum += __shfl_xor(sum, 2);
  sum += __shfl_xor(sum, 4);
  sum += __shfl_xor(sum, 8);
  float inv = 1.f / sum;
  __syncthreads();
  float acc[4] = {0.f, 0.f, 0.f, 0.f};
  for (int c = 0; c < 13; ++c) {
    #pragma unroll
    for (int it = 0; it < 2; ++it) {
      int idx = t + it * 256;
      int jj = idx >> 3, d8 = idx & 7;
      us8 val = z8;
      int j = c * 64 + jj;
      if (j < 768) {
        int pos = cs + j;
        if (pos >= 0 && pos < LL)
          val = *reinterpret_cast<const us8*>(&v[(size_t)pos * H + h * 64 + d8 * 8]);
      } else {
        int pos = gpos[j - 768];
        if (pos < 0) pos = 0;
        if (pos >= LL) pos = LL - 1;
        val = *reinterpret_cast<const us8*>(&vgp[(size_t)pos * H + h * 64 + d8 * 8]);
      }
      *reinterpret_cast<us8*>(&sKV[jj * 64 + ((d8 ^ (jj & 7)) * 8)]) = val;
    }
    __syncthreads();
    for (int jj = 0; jj < 64; ++jj) {
      float p = sS[i][c * 64 + jj];
      us4 va = *reinterpret_cast<const us4*>(
          &sKV[jj * 64 + (((ql >> 1) ^ (jj & 7)) * 8) + (ql & 1) * 4]);
      #pragma unroll
      for (int u = 0; u < 4; ++u) acc[u] += p * bf2f(va[u]);
    }
    __syncthreads();
  }
  us4 ov;
  #pragma unroll
  for (int u = 0; u < 4; ++u) ov[u] = f2bf(acc[u] * inv);
  *reinterpret_cast<us4*>(&out[(size_t)(q0 + i) * H + h * 64 + ql * 4]) = ov;
}

// ---------------- global-query attention (overwrites gpos rows) ----------------
__global__ __launch_bounds__(256) void attn_global_k(
    const u16* __restrict__ qg, const u16* __restrict__ kg, const u16* __restrict__ vg,
    const int* __restrict__ gpos, u16* __restrict__ out)
{
  int h = blockIdx.x, g = blockIdx.y, t = threadIdx.x;
  __shared__ float sS[LL];
  __shared__ float sQ[64];
  __shared__ float red[4];
  __shared__ float sO[4][64];
  if (t < 64) sQ[t] = bf2f(qg[(size_t)g * H + h * 64 + t]);
  __syncthreads();
  float sv[16];
  float lm = -1e30f;
  #pragma unroll
  for (int rep = 0; rep < 16; ++rep) {
    int j = t + rep * 256;
    const u16* kr = &kg[(size_t)j * H + h * 64];
    float s = 0.f;
    #pragma unroll
    for (int c8 = 0; c8 < 8; ++c8) {
      us8 ka = *reinterpret_cast<const us8*>(&kr[c8 * 8]);
      #pragma unroll
      for (int u = 0; u < 8; ++u) s += sQ[c8 * 8 + u] * bf2f(ka[u]);
    }
    s *= 0.125f;
    sv[rep] = s;
    lm = fmaxf(lm, s);
  }
  lm = wredmax(lm);
  if ((t & 63) == 0) red[t >> 6] = lm;
  __syncthreads();
  float m = fmaxf(fmaxf(red[0], red[1]), fmaxf(red[2], red[3]));
  __syncthreads();
  float ls = 0.f;
  #pragma unroll
  for (int rep = 0; rep < 16; ++rep) {
    int j = t + rep * 256;
    float e = __expf(sv[rep] - m);
    sS[j] = e;
    ls += e;
  }
  ls = wredsum(ls);
  if ((t & 63) == 0) red[t >> 6] = ls;
  __syncthreads();
  float inv = 1.f / (red[0] + red[1] + red[2] + red[3]);
  int d = t & 63, c = t >> 6;
  float acc = 0.f;
  for (int it = 0; it < 1024; ++it) {
    int j = c * 1024 + it;
    acc += sS[j] * bf2f(vg[(size_t)j * H + h * 64 + d]);
  }
  sO[c][d] = acc;
  __syncthreads();
  if (t < 64) {
    float o = (sO[0][t] + sO[1][t] + sO[2][t] + sO[3][t]) * inv;
    int gp = gpos[g];
    if (gp >= 0 && gp < LL) out[(size_t)gp * H + h * 64 + t] = f2bf(o);
  }
}

// ---------------- misc small kernels ----------------
__global__ void isglob_k(const int* __restrict__ gpos, unsigned char* __restrict__ isg) {
  int t = threadIdx.x;
  for (int i = t; i < LL; i += 256) isg[i] = 0;
  __syncthreads();
  if (t < GG) {
    int gp = gpos[t];
    if (gp >= 0 && gp < LL) isg[gp] = 1;
  }
}

__global__ void gather_k(const u16* __restrict__ xb, const int* __restrict__ gpos,
                         u16* __restrict__ xgb) {
  int g = blockIdx.x, t = threadIdx.x;
  int p = gpos[g];
  if (p < 0) p = 0;
  if (p >= LL) p = LL - 1;
  #pragma unroll
  for (int e = 0; e < 3; ++e)
    xgb[(size_t)g * H + t + e * 256] = xb[(size_t)p * H + t + e * 256];
}

__global__ void positions_k(const int* __restrict__ ids, const int* __restrict__ candp,
                            int* __restrict__ posb, float* __restrict__ outp) {
  int t = threadIdx.x;
  int cand = candp[0];
  __shared__ int cnt[257];
  int base = t * 16, c0 = 0;
  for (int u = 0; u < 16; ++u) c0 += (ids[base + u] == cand) ? 1 : 0;
  cnt[t + 1] = c0;
  __syncthreads();
  if (t == 0) {
    cnt[0] = 0;
    for (int i2 = 1; i2 <= 256; ++i2) cnt[i2] += cnt[i2 - 1];
  }
  __syncthreads();
  int ncand = cnt[256];
  int cr = cnt[t];
  for (int u = 0; u < 16; ++u) {
    int i2 = base + u;
    bool isC = (ids[i2] == cand);
    if (isC) {
      if (cr < NCMAX) posb[cr] = i2;
      cr++;
    } else {
      int nc = i2 - cr;
      int slot = ncand + nc;
      if (slot < NCMAX && nc >= 0) posb[slot] = i2;
    }
  }
  if (t < NCMAX) outp[NCMAX + t] = (t < ncand) ? 1.f : 0.f;
}

__global__ __launch_bounds__(256) void head_k(
    const float* __restrict__ x, const int* __restrict__ posb,
    const float* __restrict__ Wh1, const float* __restrict__ bh1,
    const float* __restrict__ Wh2, const float* __restrict__ bh2, float* __restrict__ outp) {
  int s = blockIdx.x, t = threadIdx.x;
  int p = posb[s];
  if (p < 0) p = 0;
  if (p >= LL) p = LL - 1;
  __shared__ float sx[H];
  __shared__ float sh[384];
  __shared__ float red[4];
  #pragma unroll
  for (int e = 0; e < 3; ++e) sx[t + e * 256] = x[(size_t)p * H + t + e * 256];
  __syncthreads();
  for (int j = t; j < 384; j += 256) {
    float a = bh1[j];
    for (int c = 0; c < H; ++c) a += sx[c] * Wh1[(size_t)c * 384 + j];
    sh[j] = geluf(a);
  }
  __syncthreads();
  float part = 0.f;
  for (int j = t; j < 384; j += 256) part += sh[j] * Wh2[j];
  part = wredsum(part);
  if ((t & 63) == 0) red[t >> 6] = part;
  __syncthreads();
  if (t == 0) {
    float tot = red[0] + red[1] + red[2] + red[3] + bh2[0];
    outp[s] = tot;
  }
}

// ---------------- launch ----------------
extern "C" void kernel_launch(void* const* d_in, const int* in_sizes, int n_in,
                              void* d_out, int out_size, void* d_ws, size_t ws_size,
                              hipStream_t stream) {
  const float* emb_tok = (const float*)d_in[0];
  const float* emb_pos = (const float*)d_in[1];
  const float* lnes = (const float*)d_in[2];
  const float* lneb = (const float*)d_in[3];
  const float* Wq = (const float*)d_in[4];
  const float* bq = (const float*)d_in[5];
  const float* Wk = (const float*)d_in[6];
  const float* bk = (const float*)d_in[7];
  const float* Wv = (const float*)d_in[8];
  const float* bv = (const float*)d_in[9];
  const float* Wqg = (const float*)d_in[10];
  const float* bqg = (const float*)d_in[11];
  const float* Wkg = (const float*)d_in[12];
  const float* bkg = (const float*)d_in[13];
  const float* Wvg = (const float*)d_in[14];
  const float* bvg = (const float*)d_in[15];
  const float* Wo = (const float*)d_in[16];
  const float* bo = (const float*)d_in[17];
  const float* ln1s = (const float*)d_in[18];
  const float* ln1b = (const float*)d_in[19];
  const float* W1 = (const float*)d_in[20];
  const float* b1 = (const float*)d_in[21];
  const float* W2 = (const float*)d_in[22];
  const float* b2 = (const float*)d_in[23];
  const float* ln2s = (const float*)d_in[24];
  const float* ln2b = (const float*)d_in[25];
  const float* Wh1 = (const float*)d_in[26];
  const float* bh1 = (const float*)d_in[27];
  const float* Wh2 = (const float*)d_in[28];
  const float* bh2 = (const float*)d_in[29];
  const int* ids = (const int*)d_in[30];
  int i_gpos = 32, i_cand = 33;
  if (!(n_in >= 34 && in_sizes[32] == GG)) {
    if (n_in >= 33 && in_sizes[31] == GG) { i_gpos = 31; i_cand = 32; }
  }
  const int* gpos = (const int*)d_in[i_gpos];
  const int* cand = (const int*)d_in[i_cand];
  float* outp = (float*)d_out;

  char* p = (char*)d_ws;
  auto alloc = [&](size_t bytes) {
    char* r = p;
    p += (bytes + 255) & ~(size_t)255;
    return r;
  };
  float* x = (float*)alloc((size_t)LL * H * 4);
  u16* xb = (u16*)alloc((size_t)LL * H * 2);
  u16* qb = (u16*)alloc((size_t)LL * H * 2);   // hb aliases qb..kgb (exactly LL*FF*2)
  u16* kb = (u16*)alloc((size_t)LL * H * 2);
  u16* vb = (u16*)alloc((size_t)LL * H * 2);
  u16* kgb = (u16*)alloc((size_t)LL * H * 2);
  u16* vgb = (u16*)alloc((size_t)LL * H * 2);
  u16* ob = (u16*)alloc((size_t)LL * H * 2);
  u16* qgb = (u16*)alloc((size_t)GG * H * 2);
  u16* xgb = (u16*)alloc((size_t)GG * H * 2);
  unsigned char* isg = (unsigned char*)alloc(LL);
  int* posb = (int*)alloc(64 * 4);
  u16* hb = qb;

  size_t used = (size_t)(p - (char*)d_ws);
  if (used > ws_size) used = ws_size;
  hipMemsetAsync(d_ws, 0, used, stream);

  embed_ln_k<<<LL, 256, 0, stream>>>(emb_tok, emb_pos, ids, lnes, lneb, x, xb);
  isglob_k<<<1, 256, 0, stream>>>(gpos, isg);
  positions_k<<<1, 256, 0, stream>>>(ids, cand, posb, outp);

  dim3 gP(H / 128, LL / 128);
  dim3 gF(FF / 128, LL / 128);
  for (int l = 0; l < NL; ++l) {
    const float* wq = Wq + (size_t)l * H * H;
    const float* wk = Wk + (size_t)l * H * H;
    const float* wv = Wv + (size_t)l * H * H;
    const float* wqg = Wqg + (size_t)l * H * H;
    const float* wkg = Wkg + (size_t)l * H * H;
    const float* wvg = Wvg + (size_t)l * H * H;
    const float* wo = Wo + (size_t)l * H * H;
    const float* w1 = W1 + (size_t)l * H * FF;
    const float* w2 = W2 + (size_t)l * FF * H;

    gemm_k<0, false, false><<<gP, 256, 0, stream>>>(xb, wq, bq + l * H, nullptr, nullptr, qb, LL, H, H);
    gemm_k<0, false, false><<<gP, 256, 0, stream>>>(xb, wk, bk + l * H, nullptr, nullptr, kb, LL, H, H);
    gemm_k<0, false, false><<<gP, 256, 0, stream>>>(xb, wv, bv + l * H, nullptr, nullptr, vb, LL, H, H);
    gemm_k<0, false, false><<<gP, 256, 0, stream>>>(xb, wkg, bkg + l * H, nullptr, nullptr, kgb, LL, H, H);
    gemm_k<0, false, false><<<gP, 256, 0, stream>>>(xb, wvg, bvg + l * H, nullptr, nullptr, vgb, LL, H, H);
    gather_k<<<GG, 256, 0, stream>>>(xb, gpos, xgb);
    gemm_k<0, false, false><<<dim3(H / 128, 1), 256, 0, stream>>>(xgb, wqg, bqg + l * H, nullptr, nullptr, qgb, GG, H, H);
    attn_local_k<<<dim3(NH, LL / 16), 256, 0, stream>>>(qb, kb, vb, kgb, vgb, gpos, isg, ob);
    attn_global_k<<<dim3(NH, GG), 256, 0, stream>>>(qgb, kgb, vgb, gpos, ob);
    gemm_k<0, true, true><<<gP, 256, 0, stream>>>(ob, wo, bo + l * H, x, x, nullptr, LL, H, H);
    ln_k<<<LL, 256, 0, stream>>>(x, ln1s + l * H, ln1b + l * H, x, xb);
    gemm_k<1, false, false><<<gF, 256, 0, stream>>>(xb, w1, b1 + l * FF, nullptr, nullptr, hb, LL, FF, H);
    gemm_k<0, true, true><<<gP, 256, 0, stream>>>(hb, w2, b2 + l * H, x, x, nullptr, LL, H, FF);
    ln_k<<<LL, 256, 0, stream>>>(x, ln2s + l * H, ln2b + l * H, x, xb);
  }
  head_k<<<NCMAX, 256, 0, stream>>>(x, posb, Wh1, bh1, Wh2, bh2, outp);
}

// Round 5
// 3365.115 us; speedup vs baseline: 1.8585x; 1.8585x over previous
//
#include <hip/hip_runtime.h>
#include <hip/hip_bf16.h>
#include <math.h>

#define H 768
#define NH 12
#define DH 64
#define NL 6
#define FF 3072
#define LL 4096
#define GG 64
#define NCMAX 32

typedef unsigned short u16;
typedef __attribute__((ext_vector_type(8))) unsigned short us8;
typedef __attribute__((ext_vector_type(4))) unsigned short us4;
typedef __attribute__((ext_vector_type(8))) __bf16 bf16x8;
typedef __attribute__((ext_vector_type(4))) float f32x4;

__device__ __forceinline__ float bf2f(u16 u) {
  unsigned v = ((unsigned)u) << 16;
  return __builtin_bit_cast(float, v);
}
__device__ __forceinline__ u16 f2bf(float f) {
  unsigned u = __builtin_bit_cast(unsigned, f);
  unsigned r = (u + 0x7fffu + ((u >> 16) & 1u)) >> 16;
  return (u16)r;
}
__device__ __forceinline__ float geluf(float a) {
  return 0.5f * a * (1.f + erff(a * 0.70710678118654752440f));
}
__device__ __forceinline__ float wredsum(float v) {
  #pragma unroll
  for (int o = 32; o; o >>= 1) v += __shfl_xor(v, o);
  return v;
}
__device__ __forceinline__ float wredmax(float v) {
  #pragma unroll
  for (int o = 32; o; o >>= 1) v = fmaxf(v, __shfl_xor(v, o));
  return v;
}

// ---------------- embed + LN (f32 inputs) ----------------
__global__ __launch_bounds__(256) void embed_ln_k(
    const float* __restrict__ et, const float* __restrict__ ep, const int* __restrict__ ids,
    const float* __restrict__ sc, const float* __restrict__ bi,
    float* __restrict__ x, u16* __restrict__ xb)
{
  int r = blockIdx.x, t = threadIdx.x;
  int tok = ids[r];
  if (tok < 0) tok = 0;
  if (tok >= 50272) tok = 50271;
  __shared__ float red[4];
  float v[3];
  #pragma unroll
  for (int e = 0; e < 3; ++e) {
    int c = t + e * 256;
    v[e] = et[(size_t)tok * H + c] + ep[(size_t)r * H + c];
  }
  float s = v[0] + v[1] + v[2];
  s = wredsum(s);
  if ((t & 63) == 0) red[t >> 6] = s;
  __syncthreads();
  float mean = (red[0] + red[1] + red[2] + red[3]) * (1.f / 768.f);
  __syncthreads();
  float q = 0.f;
  #pragma unroll
  for (int e = 0; e < 3; ++e) { float d = v[e] - mean; q += d * d; }
  q = wredsum(q);
  if ((t & 63) == 0) red[t >> 6] = q;
  __syncthreads();
  float var = (red[0] + red[1] + red[2] + red[3]) * (1.f / 768.f);
  float rs = rsqrtf(var + 1e-5f);
  #pragma unroll
  for (int e = 0; e < 3; ++e) {
    int c = t + e * 256;
    float o = (v[e] - mean) * rs * sc[c] + bi[c];
    x[(size_t)r * H + c] = o;
    xb[(size_t)r * H + c] = f2bf(o);
  }
}

// ---------------- LN in place over f32 buffer ----------------
__global__ __launch_bounds__(256) void ln_k(
    const float* __restrict__ y, const float* __restrict__ sc, const float* __restrict__ bi,
    float* __restrict__ x, u16* __restrict__ xb)
{
  int r = blockIdx.x, t = threadIdx.x;
  __shared__ float red[4];
  float v[3];
  #pragma unroll
  for (int e = 0; e < 3; ++e) v[e] = y[(size_t)r * H + t + e * 256];
  float s = v[0] + v[1] + v[2];
  s = wredsum(s);
  if ((t & 63) == 0) red[t >> 6] = s;
  __syncthreads();
  float mean = (red[0] + red[1] + red[2] + red[3]) * (1.f / 768.f);
  __syncthreads();
  float q = 0.f;
  #pragma unroll
  for (int e = 0; e < 3; ++e) { float d = v[e] - mean; q += d * d; }
  q = wredsum(q);
  if ((t & 63) == 0) red[t >> 6] = q;
  __syncthreads();
  float var = (red[0] + red[1] + red[2] + red[3]) * (1.f / 768.f);
  float rs = rsqrtf(var + 1e-5f);
  #pragma unroll
  for (int e = 0; e < 3; ++e) {
    int c = t + e * 256;
    float o = (v[e] - mean) * rs * sc[c] + bi[c];
    x[(size_t)r * H + c] = o;
    xb[(size_t)r * H + c] = f2bf(o);
  }
}

// ---- MFMA GEMM body: out = A(M,K)bf16 @ B(K,N)f32->bf16 + bias(f32) (+res) ----
template<int ACT, bool RES, bool OUTF32>
__device__ __forceinline__ void gemm_body(
    const u16* __restrict__ A, const float* __restrict__ B, const float* __restrict__ bias,
    const float* res, float* outF, u16* outB,
    int M, int N, int K, int n0, int m0)
{
  __shared__ u16 lsA[128 * 64];
  __shared__ u16 lsB[128 * 64];
  int t = threadIdx.x;
  int w = t >> 6, lane = t & 63;
  int wm = (w >> 1) * 64, wn = (w & 1) * 64;
  int cl = lane & 15, kgr = lane >> 4;
  f32x4 zero4 = {0.f, 0.f, 0.f, 0.f};
  f32x4 acc[4][4];
  #pragma unroll
  for (int i = 0; i < 4; ++i)
    #pragma unroll
    for (int j = 0; j < 4; ++j) acc[i][j] = zero4;
  us8 z8 = {0, 0, 0, 0, 0, 0, 0, 0};

  for (int k0 = 0; k0 < K; k0 += 64) {
    #pragma unroll
    for (int it = 0; it < 4; ++it) {
      int c = t + it * 256;
      int m = c >> 3, k8 = c & 7;
      us8 val = z8;
      int gm = m0 + m;
      if (gm < M) val = *reinterpret_cast<const us8*>(A + (size_t)gm * K + k0 + k8 * 8);
      *reinterpret_cast<us8*>(&lsA[m * 64 + ((k8 ^ (m & 7)) * 8)]) = val;
    }
    #pragma unroll
    for (int it = 0; it < 4; ++it) {
      int c = t + it * 256;
      int n = c & 127, k8 = c >> 7;
      const float* bp = B + (size_t)(k0 + k8 * 8) * N + n0 + n;
      us8 val;
      #pragma unroll
      for (int jj = 0; jj < 8; ++jj) val[jj] = f2bf(bp[(size_t)jj * N]);
      *reinterpret_cast<us8*>(&lsB[n * 64 + ((k8 ^ (n & 7)) * 8)]) = val;
    }
    __syncthreads();
    #pragma unroll
    for (int kk = 0; kk < 2; ++kk) {
      bf16x8 fa[4], fb[4];
      int k8 = kk * 4 + kgr;
      #pragma unroll
      for (int i = 0; i < 4; ++i) {
        int mr = wm + i * 16 + cl;
        fa[i] = __builtin_bit_cast(bf16x8,
            *reinterpret_cast<const us8*>(&lsA[mr * 64 + ((k8 ^ (mr & 7)) * 8)]));
        int nr = wn + i * 16 + cl;
        fb[i] = __builtin_bit_cast(bf16x8,
            *reinterpret_cast<const us8*>(&lsB[nr * 64 + ((k8 ^ (nr & 7)) * 8)]));
      }
      #pragma unroll
      for (int i = 0; i < 4; ++i)
        #pragma unroll
        for (int j = 0; j < 4; ++j)
          acc[i][j] = __builtin_amdgcn_mfma_f32_16x16x32_bf16(fa[i], fb[j], acc[i][j], 0, 0, 0);
    }
    __syncthreads();
  }
  #pragma unroll
  for (int j = 0; j < 4; ++j) {
    int n = n0 + wn + j * 16 + cl;
    float bv = bias[n];
    #pragma unroll
    for (int i = 0; i < 4; ++i) {
      #pragma unroll
      for (int r = 0; r < 4; ++r) {
        int m = m0 + wm + i * 16 + kgr * 4 + r;
        if (m < M) {
          float vv = acc[i][j][r] + bv;
          if (ACT == 1) vv = geluf(vv);
          if (RES) vv += res[(size_t)m * N + n];
          if (OUTF32) outF[(size_t)m * N + n] = vv;
          else outB[(size_t)m * N + n] = f2bf(vv);
        }
      }
    }
  }
}

template<int ACT, bool RES, bool OUTF32>
__global__ __launch_bounds__(256) void gemm_k(
    const u16* __restrict__ A, const float* __restrict__ B, const float* __restrict__ bias,
    const float* res, float* outF, u16* outB, int M, int N, int K)
{
  gemm_body<ACT, RES, OUTF32>(A, B, bias, res, outF, outB, M, N, K,
                              blockIdx.x * 128, blockIdx.y * 128);
}

// fused 5-way projection GEMM: z selects (Wq,Wk,Wv,Wkg,Wvg)
__global__ __launch_bounds__(256) void gemm_qkv_k(
    const u16* __restrict__ A,
    const float* B0, const float* B1, const float* B2, const float* B3, const float* B4,
    const float* c0, const float* c1, const float* c2, const float* c3, const float* c4,
    u16* o0, u16* o1, u16* o2, u16* o3, u16* o4)
{
  int z = blockIdx.z;
  const float* B = z == 0 ? B0 : z == 1 ? B1 : z == 2 ? B2 : z == 3 ? B3 : B4;
  const float* c = z == 0 ? c0 : z == 1 ? c1 : z == 2 ? c2 : z == 3 ? c3 : c4;
  u16* o = z == 0 ? o0 : z == 1 ? o1 : z == 2 ? o2 : z == 3 ? o3 : o4;
  gemm_body<0, false, false>(A, B, c, nullptr, nullptr, o, LL, H, H,
                             blockIdx.x * 128, blockIdx.y * 128);
}

// ---------------- MFMA flash local attention ----------------
// grid (NH, LL/64). 4 waves; wave w owns 16 queries. 13 chunks x 64 keys
// (768 local + 64 global). K in LDS [key][dim], V^T in LDS [dim][key],
// P round-trips LDS wave-locally. All tiles XOR-swizzled (k8 ^= row&7).
__global__ __launch_bounds__(256) void attn_local_k(
    const u16* __restrict__ q, const u16* __restrict__ k, const u16* __restrict__ v,
    const u16* __restrict__ kgp, const u16* __restrict__ vgp,
    const int* __restrict__ gpos, const unsigned char* __restrict__ isg,
    u16* __restrict__ out)
{
  int h = blockIdx.x;
  int q0 = blockIdx.y * 64;
  int nb = q0 >> 8;
  int cs = (nb - 1) * 256;
  int t = threadIdx.x;
  int w = t >> 6, lane = t & 63;
  int cl = lane & 15, g = lane >> 4;
  __shared__ u16 sK[64 * 64];
  __shared__ u16 sVt[64 * 64];
  __shared__ u16 sP[64 * 64];
  __shared__ unsigned char sOk[64];
  us8 z8 = {0, 0, 0, 0, 0, 0, 0, 0};
  f32x4 zero4 = {0.f, 0.f, 0.f, 0.f};

  int qrow = q0 + w * 16 + cl;
  bf16x8 qa[2];
  #pragma unroll
  for (int ks = 0; ks < 2; ++ks)
    qa[ks] = __builtin_bit_cast(bf16x8, *reinterpret_cast<const us8*>(
        &q[(size_t)qrow * H + h * 64 + ks * 32 + g * 8]));

  f32x4 O[4];
  #pragma unroll
  for (int dt = 0; dt < 4; ++dt) O[dt] = zero4;
  float mrow[4], lrow[4];
  #pragma unroll
  for (int r = 0; r < 4; ++r) { mrow[r] = -1e30f; lrow[r] = 0.f; }

  for (int c = 0; c < 13; ++c) {
    // ---- stage K [key][dim] ----
    #pragma unroll
    for (int it = 0; it < 2; ++it) {
      int idx = t + it * 256;
      int key = idx >> 3, d8 = idx & 7;
      us8 val = z8;
      if (c < 12) {
        int pos = cs + c * 64 + key;
        if (pos >= 0 && pos < LL)
          val = *reinterpret_cast<const us8*>(&k[(size_t)pos * H + h * 64 + d8 * 8]);
      } else {
        int pos = gpos[key];
        if (pos < 0) pos = 0;
        if (pos >= LL) pos = LL - 1;
        val = *reinterpret_cast<const us8*>(&kgp[(size_t)pos * H + h * 64 + d8 * 8]);
      }
      *reinterpret_cast<us8*>(&sK[key * 64 + ((d8 ^ (key & 7)) * 8)]) = val;
    }
    // ---- stage V^T [dim][key] ----
    #pragma unroll
    for (int it = 0; it < 2; ++it) {
      int idx = t + it * 256;
      int dim = idx >> 3, k8 = idx & 7;
      us8 val = z8;
      if (c < 12) {
        #pragma unroll
        for (int jj = 0; jj < 8; ++jj) {
          int pos = cs + c * 64 + k8 * 8 + jj;
          val[jj] = (pos >= 0 && pos < LL) ? v[(size_t)pos * H + h * 64 + dim] : (u16)0;
        }
      } else {
        #pragma unroll
        for (int jj = 0; jj < 8; ++jj) {
          int pos = gpos[k8 * 8 + jj];
          if (pos < 0) pos = 0;
          if (pos >= LL) pos = LL - 1;
          val[jj] = vgp[(size_t)pos * H + h * 64 + dim];
        }
      }
      *reinterpret_cast<us8*>(&sVt[dim * 64 + ((k8 ^ (dim & 7)) * 8)]) = val;
    }
    // ---- key_ok flags ----
    if (t < 64) {
      int ok = 1;
      if (c < 12) {
        int pos = cs + c * 64 + t;
        ok = (pos >= 0 && pos < LL) ? (isg[pos] ? 0 : 1) : 0;
      }
      sOk[t] = (unsigned char)ok;
    }
    __syncthreads();

    // ---- QK^T: 4 key-tiles ----
    f32x4 S[4];
    #pragma unroll
    for (int T = 0; T < 4; ++T) {
      S[T] = zero4;
      int key = T * 16 + cl;
      #pragma unroll
      for (int ks = 0; ks < 2; ++ks) {
        bf16x8 kf = __builtin_bit_cast(bf16x8, *reinterpret_cast<const us8*>(
            &sK[key * 64 + (((ks * 4 + g) ^ (key & 7)) * 8)]));
        S[T] = __builtin_amdgcn_mfma_f32_16x16x32_bf16(qa[ks], kf, S[T], 0, 0, 0);
      }
    }
    // ---- mask + scale ----
    #pragma unroll
    for (int T = 0; T < 4; ++T) {
      int key = T * 16 + cl;
      int okk = sOk[key];
      int pos = cs + c * 64 + key;
      #pragma unroll
      for (int r = 0; r < 4; ++r) {
        int qp = q0 + w * 16 + g * 4 + r;
        int d = pos - qp;
        bool ok = okk && (c == 12 || (d >= -256 && d <= 256));
        S[T][r] = ok ? S[T][r] * 0.125f : -1e9f;
      }
    }
    // ---- online softmax ----
    float cm[4];
    #pragma unroll
    for (int r = 0; r < 4; ++r) {
      cm[r] = fmaxf(fmaxf(S[0][r], S[1][r]), fmaxf(S[2][r], S[3][r]));
      cm[r] = fmaxf(cm[r], __shfl_xor(cm[r], 1));
      cm[r] = fmaxf(cm[r], __shfl_xor(cm[r], 2));
      cm[r] = fmaxf(cm[r], __shfl_xor(cm[r], 4));
      cm[r] = fmaxf(cm[r], __shfl_xor(cm[r], 8));
    }
    float sc[4];
    #pragma unroll
    for (int r = 0; r < 4; ++r) {
      float mn = fmaxf(mrow[r], cm[r]);
      sc[r] = __expf(mrow[r] - mn);
      mrow[r] = mn;
    }
    float rs[4] = {0.f, 0.f, 0.f, 0.f};
    #pragma unroll
    for (int T = 0; T < 4; ++T) {
      int key = T * 16 + cl;
      #pragma unroll
      for (int r = 0; r < 4; ++r) {
        float sv = S[T][r];
        float pv = sv > -1e8f ? __expf(sv - mrow[r]) : 0.f;
        rs[r] += pv;
        int qloc = w * 16 + g * 4 + r;
        int k8s = (key >> 3) ^ (qloc & 7);
        sP[qloc * 64 + k8s * 8 + (key & 7)] = f2bf(pv);
      }
    }
    #pragma unroll
    for (int r = 0; r < 4; ++r) {
      rs[r] += __shfl_xor(rs[r], 1);
      rs[r] += __shfl_xor(rs[r], 2);
      rs[r] += __shfl_xor(rs[r], 4);
      rs[r] += __shfl_xor(rs[r], 8);
      lrow[r] = lrow[r] * sc[r] + rs[r];
    }
    #pragma unroll
    for (int dt = 0; dt < 4; ++dt)
      #pragma unroll
      for (int r = 0; r < 4; ++r) O[dt][r] *= sc[r];
    // ---- PV (P read is wave-local; no barrier needed before) ----
    int prow = w * 16 + cl;
    #pragma unroll
    for (int ks = 0; ks < 2; ++ks) {
      bf16x8 pf = __builtin_bit_cast(bf16x8, *reinterpret_cast<const us8*>(
          &sP[prow * 64 + (((ks * 4 + g) ^ (prow & 7)) * 8)]));
      #pragma unroll
      for (int dt = 0; dt < 4; ++dt) {
        int dim = dt * 16 + cl;
        bf16x8 vf = __builtin_bit_cast(bf16x8, *reinterpret_cast<const us8*>(
            &sVt[dim * 64 + (((ks * 4 + g) ^ (dim & 7)) * 8)]));
        O[dt] = __builtin_amdgcn_mfma_f32_16x16x32_bf16(pf, vf, O[dt], 0, 0, 0);
      }
    }
    __syncthreads();
  }
  // ---- write out ----
  #pragma unroll
  for (int r = 0; r < 4; ++r) {
    float inv = 1.f / lrow[r];
    int qp = q0 + w * 16 + g * 4 + r;
    #pragma unroll
    for (int dt = 0; dt < 4; ++dt)
      out[(size_t)qp * H + h * 64 + dt * 16 + cl] = f2bf(O[dt][r] * inv);
  }
}

// ---------------- global-query attention (overwrites gpos rows) ----------------
__global__ __launch_bounds__(256) void attn_global_k(
    const u16* __restrict__ qg, const u16* __restrict__ kg, const u16* __restrict__ vg,
    const int* __restrict__ gpos, u16* __restrict__ out)
{
  int h = blockIdx.x, g = blockIdx.y, t = threadIdx.x;
  __shared__ float sS[LL];
  __shared__ float sQ[64];
  __shared__ float red[4];
  __shared__ float sO[4][64];
  if (t < 64) sQ[t] = bf2f(qg[(size_t)g * H + h * 64 + t]);
  __syncthreads();
  float sv[16];
  float lm = -1e30f;
  #pragma unroll
  for (int rep = 0; rep < 16; ++rep) {
    int j = t + rep * 256;
    const u16* kr = &kg[(size_t)j * H + h * 64];
    float s = 0.f;
    #pragma unroll
    for (int c8 = 0; c8 < 8; ++c8) {
      us8 ka = *reinterpret_cast<const us8*>(&kr[c8 * 8]);
      #pragma unroll
      for (int u = 0; u < 8; ++u) s += sQ[c8 * 8 + u] * bf2f(ka[u]);
    }
    s *= 0.125f;
    sv[rep] = s;
    lm = fmaxf(lm, s);
  }
  lm = wredmax(lm);
  if ((t & 63) == 0) red[t >> 6] = lm;
  __syncthreads();
  float m = fmaxf(fmaxf(red[0], red[1]), fmaxf(red[2], red[3]));
  __syncthreads();
  float ls = 0.f;
  #pragma unroll
  for (int rep = 0; rep < 16; ++rep) {
    int j = t + rep * 256;
    float e = __expf(sv[rep] - m);
    sS[j] = e;
    ls += e;
  }
  ls = wredsum(ls);
  if ((t & 63) == 0) red[t >> 6] = ls;
  __syncthreads();
  float inv = 1.f / (red[0] + red[1] + red[2] + red[3]);
  int d = t & 63, c = t >> 6;
  float acc = 0.f;
  for (int it = 0; it < 1024; ++it) {
    int j = c * 1024 + it;
    acc += sS[j] * bf2f(vg[(size_t)j * H + h * 64 + d]);
  }
  sO[c][d] = acc;
  __syncthreads();
  if (t < 64) {
    float o = (sO[0][t] + sO[1][t] + sO[2][t] + sO[3][t]) * inv;
    int gp = gpos[g];
    if (gp >= 0 && gp < LL) out[(size_t)gp * H + h * 64 + t] = f2bf(o);
  }
}

// ---------------- misc small kernels ----------------
__global__ void isglob_k(const int* __restrict__ gpos, unsigned char* __restrict__ isg) {
  int t = threadIdx.x;
  for (int i = t; i < LL; i += 256) isg[i] = 0;
  __syncthreads();
  if (t < GG) {
    int gp = gpos[t];
    if (gp >= 0 && gp < LL) isg[gp] = 1;
  }
}

__global__ void gather_k(const u16* __restrict__ xb, const int* __restrict__ gpos,
                         u16* __restrict__ xgb) {
  int g = blockIdx.x, t = threadIdx.x;
  int p = gpos[g];
  if (p < 0) p = 0;
  if (p >= LL) p = LL - 1;
  #pragma unroll
  for (int e = 0; e < 3; ++e)
    xgb[(size_t)g * H + t + e * 256] = xb[(size_t)p * H + t + e * 256];
}

__global__ void positions_k(const int* __restrict__ ids, const int* __restrict__ candp,
                            int* __restrict__ posb, float* __restrict__ outp) {
  int t = threadIdx.x;
  int cand = candp[0];
  __shared__ int cnt[257];
  int base = t * 16, c0 = 0;
  for (int u = 0; u < 16; ++u) c0 += (ids[base + u] == cand) ? 1 : 0;
  cnt[t + 1] = c0;
  __syncthreads();
  if (t == 0) {
    cnt[0] = 0;
    for (int i2 = 1; i2 <= 256; ++i2) cnt[i2] += cnt[i2 - 1];
  }
  __syncthreads();
  int ncand = cnt[256];
  int cr = cnt[t];
  for (int u = 0; u < 16; ++u) {
    int i2 = base + u;
    bool isC = (ids[i2] == cand);
    if (isC) {
      if (cr < NCMAX) posb[cr] = i2;
      cr++;
    } else {
      int nc = i2 - cr;
      int slot = ncand + nc;
      if (slot < NCMAX && nc >= 0) posb[slot] = i2;
    }
  }
  if (t < NCMAX) outp[NCMAX + t] = (t < ncand) ? 1.f : 0.f;
}

__global__ __launch_bounds__(256) void head_k(
    const float* __restrict__ x, const int* __restrict__ posb,
    const float* __restrict__ Wh1, const float* __restrict__ bh1,
    const float* __restrict__ Wh2, const float* __restrict__ bh2, float* __restrict__ outp) {
  int s = blockIdx.x, t = threadIdx.x;
  int p = posb[s];
  if (p < 0) p = 0;
  if (p >= LL) p = LL - 1;
  __shared__ float sx[H];
  __shared__ float sh[384];
  __shared__ float red[4];
  #pragma unroll
  for (int e = 0; e < 3; ++e) sx[t + e * 256] = x[(size_t)p * H + t + e * 256];
  __syncthreads();
  for (int j = t; j < 384; j += 256) {
    float a = bh1[j];
    for (int c = 0; c < H; ++c) a += sx[c] * Wh1[(size_t)c * 384 + j];
    sh[j] = geluf(a);
  }
  __syncthreads();
  float part = 0.f;
  for (int j = t; j < 384; j += 256) part += sh[j] * Wh2[j];
  part = wredsum(part);
  if ((t & 63) == 0) red[t >> 6] = part;
  __syncthreads();
  if (t == 0) {
    float tot = red[0] + red[1] + red[2] + red[3] + bh2[0];
    outp[s] = tot;
  }
}

// ---------------- launch ----------------
extern "C" void kernel_launch(void* const* d_in, const int* in_sizes, int n_in,
                              void* d_out, int out_size, void* d_ws, size_t ws_size,
                              hipStream_t stream) {
  const float* emb_tok = (const float*)d_in[0];
  const float* emb_pos = (const float*)d_in[1];
  const float* lnes = (const float*)d_in[2];
  const float* lneb = (const float*)d_in[3];
  const float* Wq = (const float*)d_in[4];
  const float* bq = (const float*)d_in[5];
  const float* Wk = (const float*)d_in[6];
  const float* bk = (const float*)d_in[7];
  const float* Wv = (const float*)d_in[8];
  const float* bv = (const float*)d_in[9];
  const float* Wqg = (const float*)d_in[10];
  const float* bqg = (const float*)d_in[11];
  const float* Wkg = (const float*)d_in[12];
  const float* bkg = (const float*)d_in[13];
  const float* Wvg = (const float*)d_in[14];
  const float* bvg = (const float*)d_in[15];
  const float* Wo = (const float*)d_in[16];
  const float* bo = (const float*)d_in[17];
  const float* ln1s = (const float*)d_in[18];
  const float* ln1b = (const float*)d_in[19];
  const float* W1 = (const float*)d_in[20];
  const float* b1 = (const float*)d_in[21];
  const float* W2 = (const float*)d_in[22];
  const float* b2 = (const float*)d_in[23];
  const float* ln2s = (const float*)d_in[24];
  const float* ln2b = (const float*)d_in[25];
  const float* Wh1 = (const float*)d_in[26];
  const float* bh1 = (const float*)d_in[27];
  const float* Wh2 = (const float*)d_in[28];
  const float* bh2 = (const float*)d_in[29];
  const int* ids = (const int*)d_in[30];
  int i_gpos = 32, i_cand = 33;
  if (!(n_in >= 34 && in_sizes[32] == GG)) {
    if (n_in >= 33 && in_sizes[31] == GG) { i_gpos = 31; i_cand = 32; }
  }
  const int* gpos = (const int*)d_in[i_gpos];
  const int* cand = (const int*)d_in[i_cand];
  float* outp = (float*)d_out;

  char* p = (char*)d_ws;
  auto alloc = [&](size_t bytes) {
    char* r = p;
    p += (bytes + 255) & ~(size_t)255;
    return r;
  };
  float* x = (float*)alloc((size_t)LL * H * 4);
  u16* xb = (u16*)alloc((size_t)LL * H * 2);
  u16* qb = (u16*)alloc((size_t)LL * H * 2);   // hb aliases qb..kgb (exactly LL*FF*2)
  u16* kb = (u16*)alloc((size_t)LL * H * 2);
  u16* vb = (u16*)alloc((size_t)LL * H * 2);
  u16* kgb = (u16*)alloc((size_t)LL * H * 2);
  u16* vgb = (u16*)alloc((size_t)LL * H * 2);
  u16* ob = (u16*)alloc((size_t)LL * H * 2);
  u16* qgb = (u16*)alloc((size_t)GG * H * 2);
  u16* xgb = (u16*)alloc((size_t)GG * H * 2);
  unsigned char* isg = (unsigned char*)alloc(LL);
  int* posb = (int*)alloc(64 * 4);
  u16* hb = qb;

  size_t used = (size_t)(p - (char*)d_ws);
  if (used > ws_size) used = ws_size;
  hipMemsetAsync(d_ws, 0, used, stream);

  embed_ln_k<<<LL, 256, 0, stream>>>(emb_tok, emb_pos, ids, lnes, lneb, x, xb);
  isglob_k<<<1, 256, 0, stream>>>(gpos, isg);
  positions_k<<<1, 256, 0, stream>>>(ids, cand, posb, outp);

  dim3 gP(H / 128, LL / 128);
  dim3 gF(FF / 128, LL / 128);
  dim3 gQKV(H / 128, LL / 128, 5);
  for (int l = 0; l < NL; ++l) {
    const float* wq = Wq + (size_t)l * H * H;
    const float* wk = Wk + (size_t)l * H * H;
    const float* wv = Wv + (size_t)l * H * H;
    const float* wqg = Wqg + (size_t)l * H * H;
    const float* wkg = Wkg + (size_t)l * H * H;
    const float* wvg = Wvg + (size_t)l * H * H;
    const float* wo = Wo + (size_t)l * H * H;
    const float* w1 = W1 + (size_t)l * H * FF;
    const float* w2 = W2 + (size_t)l * FF * H;

    gemm_qkv_k<<<gQKV, 256, 0, stream>>>(xb,
        wq, wk, wv, wkg, wvg,
        bq + l * H, bk + l * H, bv + l * H, bkg + l * H, bvg + l * H,
        qb, kb, vb, kgb, vgb);
    gather_k<<<GG, 256, 0, stream>>>(xb, gpos, xgb);
    gemm_k<0, false, false><<<dim3(H / 128, 1), 256, 0, stream>>>(xgb, wqg, bqg + l * H, nullptr, nullptr, qgb, GG, H, H);
    attn_local_k<<<dim3(NH, LL / 64), 256, 0, stream>>>(qb, kb, vb, kgb, vgb, gpos, isg, ob);
    attn_global_k<<<dim3(NH, GG), 256, 0, stream>>>(qgb, kgb, vgb, gpos, ob);
    gemm_k<0, true, true><<<gP, 256, 0, stream>>>(ob, wo, bo + l * H, x, x, nullptr, LL, H, H);
    ln_k<<<LL, 256, 0, stream>>>(x, ln1s + l * H, ln1b + l * H, x, xb);
    gemm_k<1, false, false><<<gF, 256, 0, stream>>>(xb, w1, b1 + l * FF, nullptr, nullptr, hb, LL, FF, H);
    gemm_k<0, true, true><<<gP, 256, 0, stream>>>(hb, w2, b2 + l * H, x, x, nullptr, LL, H, FF);
    ln_k<<<LL, 256, 0, stream>>>(x, ln2s + l * H, ln2b + l * H, x, xb);
  }
  head_k<<<NCMAX, 256, 0, stream>>>(x, posb, Wh1, bh1, Wh2, bh2, outp);
}

// Round 6
// 2461.171 us; speedup vs baseline: 2.5411x; 1.3673x over previous
//
#include <hip/hip_runtime.h>
#include <hip/hip_bf16.h>
#include <math.h>

#define H 768
#define NH 12
#define DH 64
#define NL 6
#define FF 3072
#define LL 4096
#define GG 64
#define NCMAX 32

#define MATSZ (H * H)                 // 589824
#define OFF_QG ((size_t)5 * MATSZ)
#define OFF_O  ((size_t)6 * MATSZ)
#define OFF_W1 ((size_t)7 * MATSZ)    // 3072x768
#define OFF_W2 (OFF_W1 + (size_t)H * FF)
#define WT_ELEMS (OFF_W2 + (size_t)FF * H)   // 8847360

typedef unsigned short u16;
typedef __attribute__((ext_vector_type(8))) unsigned short us8;
typedef __attribute__((ext_vector_type(4))) unsigned short us4;
typedef __attribute__((ext_vector_type(8))) __bf16 bf16x8;
typedef __attribute__((ext_vector_type(4))) float f32x4;

__device__ __forceinline__ float bf2f(u16 u) {
  unsigned v = ((unsigned)u) << 16;
  return __builtin_bit_cast(float, v);
}
__device__ __forceinline__ u16 f2bf(float f) {
  unsigned u = __builtin_bit_cast(unsigned, f);
  unsigned r = (u + 0x7fffu + ((u >> 16) & 1u)) >> 16;
  return (u16)r;
}
__device__ __forceinline__ float geluf(float a) {
  return 0.5f * a * (1.f + erff(a * 0.70710678118654752440f));
}
__device__ __forceinline__ float wredsum(float v) {
  #pragma unroll
  for (int o = 32; o; o >>= 1) v += __shfl_xor(v, o);
  return v;
}
__device__ __forceinline__ float wredmax(float v) {
  #pragma unroll
  for (int o = 32; o; o >>= 1) v = fmaxf(v, __shfl_xor(v, o));
  return v;
}

// ---------------- embed + LN (f32 inputs) ----------------
__global__ __launch_bounds__(256) void embed_ln_k(
    const float* __restrict__ et, const float* __restrict__ ep, const int* __restrict__ ids,
    const float* __restrict__ sc, const float* __restrict__ bi,
    float* __restrict__ x, u16* __restrict__ xb)
{
  int r = blockIdx.x, t = threadIdx.x;
  int tok = ids[r];
  if (tok < 0) tok = 0;
  if (tok >= 50272) tok = 50271;
  __shared__ float red[4];
  float v[3];
  #pragma unroll
  for (int e = 0; e < 3; ++e) {
    int c = t + e * 256;
    v[e] = et[(size_t)tok * H + c] + ep[(size_t)r * H + c];
  }
  float s = v[0] + v[1] + v[2];
  s = wredsum(s);
  if ((t & 63) == 0) red[t >> 6] = s;
  __syncthreads();
  float mean = (red[0] + red[1] + red[2] + red[3]) * (1.f / 768.f);
  __syncthreads();
  float q = 0.f;
  #pragma unroll
  for (int e = 0; e < 3; ++e) { float d = v[e] - mean; q += d * d; }
  q = wredsum(q);
  if ((t & 63) == 0) red[t >> 6] = q;
  __syncthreads();
  float var = (red[0] + red[1] + red[2] + red[3]) * (1.f / 768.f);
  float rs = rsqrtf(var + 1e-5f);
  #pragma unroll
  for (int e = 0; e < 3; ++e) {
    int c = t + e * 256;
    float o = (v[e] - mean) * rs * sc[c] + bi[c];
    x[(size_t)r * H + c] = o;
    xb[(size_t)r * H + c] = f2bf(o);
  }
}

// ---------------- LN in place over f32 buffer ----------------
__global__ __launch_bounds__(256) void ln_k(
    const float* __restrict__ y, const float* __restrict__ sc, const float* __restrict__ bi,
    float* __restrict__ x, u16* __restrict__ xb)
{
  int r = blockIdx.x, t = threadIdx.x;
  __shared__ float red[4];
  float v[3];
  #pragma unroll
  for (int e = 0; e < 3; ++e) v[e] = y[(size_t)r * H + t + e * 256];
  float s = v[0] + v[1] + v[2];
  s = wredsum(s);
  if ((t & 63) == 0) red[t >> 6] = s;
  __syncthreads();
  float mean = (red[0] + red[1] + red[2] + red[3]) * (1.f / 768.f);
  __syncthreads();
  float q = 0.f;
  #pragma unroll
  for (int e = 0; e < 3; ++e) { float d = v[e] - mean; q += d * d; }
  q = wredsum(q);
  if ((t & 63) == 0) red[t >> 6] = q;
  __syncthreads();
  float var = (red[0] + red[1] + red[2] + red[3]) * (1.f / 768.f);
  float rs = rsqrtf(var + 1e-5f);
  #pragma unroll
  for (int e = 0; e < 3; ++e) {
    int c = t + e * 256;
    float o = (v[e] - mean) * rs * sc[c] + bi[c];
    x[(size_t)r * H + c] = o;
    xb[(size_t)r * H + c] = f2bf(o);
  }
}

// ---------------- per-layer weight convert+transpose: Wt[n][k] = bf16(W[k][n]) ----------------
// grid = 7*144 + 576 + 576 = 2160 blocks, 256 threads.
__global__ __launch_bounds__(256) void conv_layer_k(
    const float* __restrict__ Wq, const float* __restrict__ Wk, const float* __restrict__ Wv,
    const float* __restrict__ Wkg, const float* __restrict__ Wvg, const float* __restrict__ Wqg,
    const float* __restrict__ Wo, const float* __restrict__ W1, const float* __restrict__ W2,
    u16* __restrict__ wt)
{
  int bid = blockIdx.x, t = threadIdx.x;
  const float* src;
  size_t ooff;
  int K, N, tile;
  if (bid < 1008) {
    int m = bid / 144;
    tile = bid % 144;
    K = H; N = H;
    ooff = (size_t)m * MATSZ;
    src = m == 0 ? Wq : m == 1 ? Wk : m == 2 ? Wv : m == 3 ? Wkg : m == 4 ? Wvg : m == 5 ? Wqg : Wo;
  } else if (bid < 1584) {
    tile = bid - 1008;
    K = H; N = FF;
    ooff = OFF_W1;
    src = W1;
  } else {
    tile = bid - 1584;
    K = FF; N = H;
    ooff = OFF_W2;
    src = W2;
  }
  int KT = K / 64;
  int kt = tile % KT, nt = tile / KT;
  __shared__ u16 sT[64 * 72];
  #pragma unroll
  for (int it = 0; it < 16; ++it) {
    int idx = t + it * 256;
    int n = idx & 63, kk = idx >> 6;
    sT[n * 72 + kk] = f2bf(src[(size_t)(kt * 64 + kk) * N + nt * 64 + n]);
  }
  __syncthreads();
  #pragma unroll
  for (int it = 0; it < 2; ++it) {
    int idx = t + it * 256;
    int n = idx >> 3, k8 = idx & 7;
    us8 val = *reinterpret_cast<const us8*>(&sT[n * 72 + k8 * 8]);
    *reinterpret_cast<us8*>(&wt[ooff + (size_t)(nt * 64 + n) * K + kt * 64 + k8 * 8]) = val;
  }
}

// ---- MFMA GEMM body: out = A(M,K)bf16 @ Wt^T (Wt is [N][K] bf16) + bias(f32) (+res) ----
template<int ACT, bool RES, bool OUTF32>
__device__ __forceinline__ void gemm_body(
    const u16* __restrict__ A, const u16* __restrict__ Bt, const float* __restrict__ bias,
    const float* res, float* outF, u16* outB,
    int M, int N, int K, int n0, int m0)
{
  __shared__ u16 lsA[128 * 64];
  __shared__ u16 lsB[128 * 64];
  int t = threadIdx.x;
  int w = t >> 6, lane = t & 63;
  int wm = (w >> 1) * 64, wn = (w & 1) * 64;
  int cl = lane & 15, kgr = lane >> 4;
  f32x4 zero4 = {0.f, 0.f, 0.f, 0.f};
  f32x4 acc[4][4];
  #pragma unroll
  for (int i = 0; i < 4; ++i)
    #pragma unroll
    for (int j = 0; j < 4; ++j) acc[i][j] = zero4;
  us8 z8 = {0, 0, 0, 0, 0, 0, 0, 0};

  for (int k0 = 0; k0 < K; k0 += 64) {
    #pragma unroll
    for (int it = 0; it < 4; ++it) {
      int c = t + it * 256;
      int m = c >> 3, k8 = c & 7;
      us8 val = z8;
      int gm = m0 + m;
      if (gm < M) val = *reinterpret_cast<const us8*>(A + (size_t)gm * K + k0 + k8 * 8);
      *reinterpret_cast<us8*>(&lsA[m * 64 + ((k8 ^ (m & 7)) * 8)]) = val;
    }
    #pragma unroll
    for (int it = 0; it < 4; ++it) {
      int c = t + it * 256;
      int n = c >> 3, k8 = c & 7;
      us8 val = *reinterpret_cast<const us8*>(Bt + (size_t)(n0 + n) * K + k0 + k8 * 8);
      *reinterpret_cast<us8*>(&lsB[n * 64 + ((k8 ^ (n & 7)) * 8)]) = val;
    }
    __syncthreads();
    #pragma unroll
    for (int kk = 0; kk < 2; ++kk) {
      bf16x8 fa[4], fb[4];
      int k8 = kk * 4 + kgr;
      #pragma unroll
      for (int i = 0; i < 4; ++i) {
        int mr = wm + i * 16 + cl;
        fa[i] = __builtin_bit_cast(bf16x8,
            *reinterpret_cast<const us8*>(&lsA[mr * 64 + ((k8 ^ (mr & 7)) * 8)]));
        int nr = wn + i * 16 + cl;
        fb[i] = __builtin_bit_cast(bf16x8,
            *reinterpret_cast<const us8*>(&lsB[nr * 64 + ((k8 ^ (nr & 7)) * 8)]));
      }
      #pragma unroll
      for (int i = 0; i < 4; ++i)
        #pragma unroll
        for (int j = 0; j < 4; ++j)
          acc[i][j] = __builtin_amdgcn_mfma_f32_16x16x32_bf16(fa[i], fb[j], acc[i][j], 0, 0, 0);
    }
    __syncthreads();
  }
  #pragma unroll
  for (int j = 0; j < 4; ++j) {
    int n = n0 + wn + j * 16 + cl;
    float bv = bias[n];
    #pragma unroll
    for (int i = 0; i < 4; ++i) {
      #pragma unroll
      for (int r = 0; r < 4; ++r) {
        int m = m0 + wm + i * 16 + kgr * 4 + r;
        if (m < M) {
          float vv = acc[i][j][r] + bv;
          if (ACT == 1) vv = geluf(vv);
          if (RES) vv += res[(size_t)m * N + n];
          if (OUTF32) outF[(size_t)m * N + n] = vv;
          else outB[(size_t)m * N + n] = f2bf(vv);
        }
      }
    }
  }
}

template<int ACT, bool RES, bool OUTF32>
__global__ __launch_bounds__(256) void gemm_bf_k(
    const u16* __restrict__ A, const u16* __restrict__ Bt, const float* __restrict__ bias,
    const float* res, float* outF, u16* outB, int M, int N, int K)
{
  gemm_body<ACT, RES, OUTF32>(A, Bt, bias, res, outF, outB, M, N, K,
                              blockIdx.x * 128, blockIdx.y * 128);
}

// fused 5-way projection GEMM: z selects (Wq,Wk,Wv,Wkg,Wvg) from wt
__global__ __launch_bounds__(256) void gemm_qkv_k(
    const u16* __restrict__ A, const u16* __restrict__ wt,
    const float* c0, const float* c1, const float* c2, const float* c3, const float* c4,
    u16* o0, u16* o1, u16* o2, u16* o3, u16* o4)
{
  int z = blockIdx.z;
  const u16* Bt = wt + (size_t)z * MATSZ;
  const float* c = z == 0 ? c0 : z == 1 ? c1 : z == 2 ? c2 : z == 3 ? c3 : c4;
  u16* o = z == 0 ? o0 : z == 1 ? o1 : z == 2 ? o2 : z == 3 ? o3 : o4;
  gemm_body<0, false, false>(A, Bt, c, nullptr, nullptr, o, LL, H, H,
                             blockIdx.x * 128, blockIdx.y * 128);
}

// ---------------- MFMA flash local attention ----------------
__global__ __launch_bounds__(256) void attn_local_k(
    const u16* __restrict__ q, const u16* __restrict__ k, const u16* __restrict__ v,
    const u16* __restrict__ kgp, const u16* __restrict__ vgp,
    const int* __restrict__ gpos, const unsigned char* __restrict__ isg,
    u16* __restrict__ out)
{
  int h = blockIdx.x;
  int q0 = blockIdx.y * 64;
  int nb = q0 >> 8;
  int cs = (nb - 1) * 256;
  int t = threadIdx.x;
  int w = t >> 6, lane = t & 63;
  int cl = lane & 15, g = lane >> 4;
  __shared__ u16 sK[64 * 64];
  __shared__ u16 sVt[64 * 64];
  __shared__ u16 sP[64 * 64];
  __shared__ unsigned char sOk[64];
  us8 z8 = {0, 0, 0, 0, 0, 0, 0, 0};
  f32x4 zero4 = {0.f, 0.f, 0.f, 0.f};

  int qrow = q0 + w * 16 + cl;
  bf16x8 qa[2];
  #pragma unroll
  for (int ks = 0; ks < 2; ++ks)
    qa[ks] = __builtin_bit_cast(bf16x8, *reinterpret_cast<const us8*>(
        &q[(size_t)qrow * H + h * 64 + ks * 32 + g * 8]));

  f32x4 O[4];
  #pragma unroll
  for (int dt = 0; dt < 4; ++dt) O[dt] = zero4;
  float mrow[4], lrow[4];
  #pragma unroll
  for (int r = 0; r < 4; ++r) { mrow[r] = -1e30f; lrow[r] = 0.f; }

  for (int c = 0; c < 13; ++c) {
    #pragma unroll
    for (int it = 0; it < 2; ++it) {
      int idx = t + it * 256;
      int key = idx >> 3, d8 = idx & 7;
      us8 val = z8;
      if (c < 12) {
        int pos = cs + c * 64 + key;
        if (pos >= 0 && pos < LL)
          val = *reinterpret_cast<const us8*>(&k[(size_t)pos * H + h * 64 + d8 * 8]);
      } else {
        int pos = gpos[key];
        if (pos < 0) pos = 0;
        if (pos >= LL) pos = LL - 1;
        val = *reinterpret_cast<const us8*>(&kgp[(size_t)pos * H + h * 64 + d8 * 8]);
      }
      *reinterpret_cast<us8*>(&sK[key * 64 + ((d8 ^ (key & 7)) * 8)]) = val;
    }
    #pragma unroll
    for (int it = 0; it < 2; ++it) {
      int idx = t + it * 256;
      int dim = idx >> 3, k8 = idx & 7;
      us8 val = z8;
      if (c < 12) {
        #pragma unroll
        for (int jj = 0; jj < 8; ++jj) {
          int pos = cs + c * 64 + k8 * 8 + jj;
          val[jj] = (pos >= 0 && pos < LL) ? v[(size_t)pos * H + h * 64 + dim] : (u16)0;
        }
      } else {
        #pragma unroll
        for (int jj = 0; jj < 8; ++jj) {
          int pos = gpos[k8 * 8 + jj];
          if (pos < 0) pos = 0;
          if (pos >= LL) pos = LL - 1;
          val[jj] = vgp[(size_t)pos * H + h * 64 + dim];
        }
      }
      *reinterpret_cast<us8*>(&sVt[dim * 64 + ((k8 ^ (dim & 7)) * 8)]) = val;
    }
    if (t < 64) {
      int ok = 1;
      if (c < 12) {
        int pos = cs + c * 64 + t;
        ok = (pos >= 0 && pos < LL) ? (isg[pos] ? 0 : 1) : 0;
      }
      sOk[t] = (unsigned char)ok;
    }
    __syncthreads();

    f32x4 S[4];
    #pragma unroll
    for (int T = 0; T < 4; ++T) {
      S[T] = zero4;
      int key = T * 16 + cl;
      #pragma unroll
      for (int ks = 0; ks < 2; ++ks) {
        bf16x8 kf = __builtin_bit_cast(bf16x8, *reinterpret_cast<const us8*>(
            &sK[key * 64 + (((ks * 4 + g) ^ (key & 7)) * 8)]));
        S[T] = __builtin_amdgcn_mfma_f32_16x16x32_bf16(qa[ks], kf, S[T], 0, 0, 0);
      }
    }
    #pragma unroll
    for (int T = 0; T < 4; ++T) {
      int key = T * 16 + cl;
      int okk = sOk[key];
      int pos = cs + c * 64 + key;
      #pragma unroll
      for (int r = 0; r < 4; ++r) {
        int qp = q0 + w * 16 + g * 4 + r;
        int d = pos - qp;
        bool ok = okk && (c == 12 || (d >= -256 && d <= 256));
        S[T][r] = ok ? S[T][r] * 0.125f : -1e9f;
      }
    }
    float cm[4];
    #pragma unroll
    for (int r = 0; r < 4; ++r) {
      cm[r] = fmaxf(fmaxf(S[0][r], S[1][r]), fmaxf(S[2][r], S[3][r]));
      cm[r] = fmaxf(cm[r], __shfl_xor(cm[r], 1));
      cm[r] = fmaxf(cm[r], __shfl_xor(cm[r], 2));
      cm[r] = fmaxf(cm[r], __shfl_xor(cm[r], 4));
      cm[r] = fmaxf(cm[r], __shfl_xor(cm[r], 8));
    }
    float sc[4];
    #pragma unroll
    for (int r = 0; r < 4; ++r) {
      float mn = fmaxf(mrow[r], cm[r]);
      sc[r] = __expf(mrow[r] - mn);
      mrow[r] = mn;
    }
    float rs[4] = {0.f, 0.f, 0.f, 0.f};
    #pragma unroll
    for (int T = 0; T < 4; ++T) {
      int key = T * 16 + cl;
      #pragma unroll
      for (int r = 0; r < 4; ++r) {
        float sv = S[T][r];
        float pv = sv > -1e8f ? __expf(sv - mrow[r]) : 0.f;
        rs[r] += pv;
        int qloc = w * 16 + g * 4 + r;
        int k8s = (key >> 3) ^ (qloc & 7);
        sP[qloc * 64 + k8s * 8 + (key & 7)] = f2bf(pv);
      }
    }
    #pragma unroll
    for (int r = 0; r < 4; ++r) {
      rs[r] += __shfl_xor(rs[r], 1);
      rs[r] += __shfl_xor(rs[r], 2);
      rs[r] += __shfl_xor(rs[r], 4);
      rs[r] += __shfl_xor(rs[r], 8);
      lrow[r] = lrow[r] * sc[r] + rs[r];
    }
    #pragma unroll
    for (int dt = 0; dt < 4; ++dt)
      #pragma unroll
      for (int r = 0; r < 4; ++r) O[dt][r] *= sc[r];
    int prow = w * 16 + cl;
    #pragma unroll
    for (int ks = 0; ks < 2; ++ks) {
      bf16x8 pf = __builtin_bit_cast(bf16x8, *reinterpret_cast<const us8*>(
          &sP[prow * 64 + (((ks * 4 + g) ^ (prow & 7)) * 8)]));
      #pragma unroll
      for (int dt = 0; dt < 4; ++dt) {
        int dim = dt * 16 + cl;
        bf16x8 vf = __builtin_bit_cast(bf16x8, *reinterpret_cast<const us8*>(
            &sVt[dim * 64 + (((ks * 4 + g) ^ (dim & 7)) * 8)]));
        O[dt] = __builtin_amdgcn_mfma_f32_16x16x32_bf16(pf, vf, O[dt], 0, 0, 0);
      }
    }
    __syncthreads();
  }
  #pragma unroll
  for (int r = 0; r < 4; ++r) {
    float inv = 1.f / lrow[r];
    int qp = q0 + w * 16 + g * 4 + r;
    #pragma unroll
    for (int dt = 0; dt < 4; ++dt)
      out[(size_t)qp * H + h * 64 + dt * 16 + cl] = f2bf(O[dt][r] * inv);
  }
}

// ---------------- global attention: scores S = Qg Kg^T * scale ----------------
// grid (NH, LL/128); sbuf[h][g][key] f32
__global__ __launch_bounds__(256) void ag_score_k(
    const u16* __restrict__ qg, const u16* __restrict__ kg, float* __restrict__ sbuf)
{
  int h = blockIdx.x;
  int kc0 = blockIdx.y * 128;
  int t = threadIdx.x;
  int w = t >> 6, lane = t & 63;
  int cl = lane & 15, g = lane >> 4;
  __shared__ u16 sK[128 * 64];
  #pragma unroll
  for (int it = 0; it < 4; ++it) {
    int c = t + it * 256;
    int key = c >> 3, d8 = c & 7;
    us8 val = *reinterpret_cast<const us8*>(&kg[(size_t)(kc0 + key) * H + h * 64 + d8 * 8]);
    *reinterpret_cast<us8*>(&sK[key * 64 + ((d8 ^ (key & 7)) * 8)]) = val;
  }
  int qrow = w * 16 + cl;
  bf16x8 qa[2];
  #pragma unroll
  for (int ks = 0; ks < 2; ++ks)
    qa[ks] = __builtin_bit_cast(bf16x8, *reinterpret_cast<const us8*>(
        &qg[(size_t)qrow * H + h * 64 + ks * 32 + g * 8]));
  __syncthreads();
  f32x4 zero4 = {0.f, 0.f, 0.f, 0.f};
  #pragma unroll
  for (int j = 0; j < 8; ++j) {
    f32x4 S = zero4;
    int key = j * 16 + cl;
    #pragma unroll
    for (int ks = 0; ks < 2; ++ks) {
      bf16x8 kf = __builtin_bit_cast(bf16x8, *reinterpret_cast<const us8*>(
          &sK[key * 64 + (((ks * 4 + g) ^ (key & 7)) * 8)]));
      S = __builtin_amdgcn_mfma_f32_16x16x32_bf16(qa[ks], kf, S, 0, 0, 0);
    }
    #pragma unroll
    for (int r = 0; r < 4; ++r) {
      int grow = w * 16 + g * 4 + r;
      sbuf[((size_t)(h * 64 + grow)) * 4096 + kc0 + key] = S[r] * 0.125f;
    }
  }
}

// softmax per row (768 rows x 4096); writes NORMALIZED bf16 P packed in-row (stride 8192 u16)
__global__ __launch_bounds__(256) void ag_soft_k(float* __restrict__ sbuf)
{
  int row = blockIdx.x, t = threadIdx.x;
  float* base = sbuf + (size_t)row * 4096;
  u16* pb = (u16*)(sbuf) + (size_t)row * 8192;
  __shared__ float red[4];
  f32x4 rv[4];
  #pragma unroll
  for (int it = 0; it < 4; ++it)
    rv[it] = *reinterpret_cast<const f32x4*>(base + it * 1024 + t * 4);
  float m = -1e30f;
  #pragma unroll
  for (int it = 0; it < 4; ++it)
    #pragma unroll
    for (int u = 0; u < 4; ++u) m = fmaxf(m, rv[it][u]);
  m = wredmax(m);
  if ((t & 63) == 0) red[t >> 6] = m;
  __syncthreads();
  m = fmaxf(fmaxf(red[0], red[1]), fmaxf(red[2], red[3]));
  __syncthreads();
  float s = 0.f;
  #pragma unroll
  for (int it = 0; it < 4; ++it)
    #pragma unroll
    for (int u = 0; u < 4; ++u) {
      float e = __expf(rv[it][u] - m);
      rv[it][u] = e;
      s += e;
    }
  s = wredsum(s);
  if ((t & 63) == 0) red[t >> 6] = s;
  __syncthreads();
  float inv = 1.f / (red[0] + red[1] + red[2] + red[3]);
  #pragma unroll
  for (int it = 0; it < 4; ++it) {
    us4 o;
    #pragma unroll
    for (int u = 0; u < 4; ++u) o[u] = f2bf(rv[it][u] * inv);
    *reinterpret_cast<us4*>(pb + it * 1024 + t * 4) = o;
  }
}

// PV: obuf[h][g][d] += P[h][g][keys] @ Vg[keys][d]; split-K over grid.y, atomicAdd f32
__global__ __launch_bounds__(256) void ag_pv_k(
    const float* __restrict__ sbuf, const u16* __restrict__ vg, float* __restrict__ obuf)
{
  int h = blockIdx.x;
  int kb0 = blockIdx.y * 256;
  int t = threadIdx.x;
  int w = t >> 6, lane = t & 63;
  int cl = lane & 15, g = lane >> 4;
  __shared__ u16 sVt[64 * 64];
  f32x4 zero4 = {0.f, 0.f, 0.f, 0.f};
  f32x4 O[4];
  #pragma unroll
  for (int dt = 0; dt < 4; ++dt) O[dt] = zero4;
  const u16* pb = (const u16*)(sbuf);
  int prow = w * 16 + cl;
  size_t pbase = (size_t)(h * 64 + prow) * 8192;

  for (int cc = 0; cc < 4; ++cc) {
    int kc = kb0 + cc * 64;
    #pragma unroll
    for (int it = 0; it < 2; ++it) {
      int idx = t + it * 256;
      int dim = idx >> 3, k8 = idx & 7;
      us8 val;
      #pragma unroll
      for (int jj = 0; jj < 8; ++jj)
        val[jj] = vg[(size_t)(kc + k8 * 8 + jj) * H + h * 64 + dim];
      *reinterpret_cast<us8*>(&sVt[dim * 64 + ((k8 ^ (dim & 7)) * 8)]) = val;
    }
    __syncthreads();
    #pragma unroll
    for (int ks = 0; ks < 2; ++ks) {
      bf16x8 pf = __builtin_bit_cast(bf16x8, *reinterpret_cast<const us8*>(
          pb + pbase + kc + (ks * 4 + g) * 8));
      #pragma unroll
      for (int dt = 0; dt < 4; ++dt) {
        int dim = dt * 16 + cl;
        bf16x8 vf = __builtin_bit_cast(bf16x8, *reinterpret_cast<const us8*>(
            &sVt[dim * 64 + (((ks * 4 + g) ^ (dim & 7)) * 8)]));
        O[dt] = __builtin_amdgcn_mfma_f32_16x16x32_bf16(pf, vf, O[dt], 0, 0, 0);
      }
    }
    __syncthreads();
  }
  #pragma unroll
  for (int r = 0; r < 4; ++r) {
    int grow = w * 16 + g * 4 + r;
    #pragma unroll
    for (int dt = 0; dt < 4; ++dt)
      atomicAdd(&obuf[((size_t)h * 64 + grow) * 64 + dt * 16 + cl], O[dt][r]);
  }
}

// scatter obuf into ob at gpos rows
__global__ __launch_bounds__(256) void ag_write_k(
    const float* __restrict__ obuf, const int* __restrict__ gpos, u16* __restrict__ out)
{
  int g = blockIdx.x, t = threadIdx.x;
  int gp = gpos[g];
  if (gp < 0) gp = 0;
  if (gp >= LL) gp = LL - 1;
  #pragma unroll
  for (int e = 0; e < 3; ++e) {
    int c = t + e * 256;
    int h = c >> 6, d = c & 63;
    out[(size_t)gp * H + c] = f2bf(obuf[((size_t)h * 64 + g) * 64 + d]);
  }
}

// ---------------- misc small kernels ----------------
__global__ void isglob_k(const int* __restrict__ gpos, unsigned char* __restrict__ isg) {
  int t = threadIdx.x;
  for (int i = t; i < LL; i += 256) isg[i] = 0;
  __syncthreads();
  if (t < GG) {
    int gp = gpos[t];
    if (gp >= 0 && gp < LL) isg[gp] = 1;
  }
}

__global__ void gather_k(const u16* __restrict__ xb, const int* __restrict__ gpos,
                         u16* __restrict__ xgb) {
  int g = blockIdx.x, t = threadIdx.x;
  int p = gpos[g];
  if (p < 0) p = 0;
  if (p >= LL) p = LL - 1;
  #pragma unroll
  for (int e = 0; e < 3; ++e)
    xgb[(size_t)g * H + t + e * 256] = xb[(size_t)p * H + t + e * 256];
}

__global__ void positions_k(const int* __restrict__ ids, const int* __restrict__ candp,
                            int* __restrict__ posb, float* __restrict__ outp) {
  int t = threadIdx.x;
  int cand = candp[0];
  __shared__ int cnt[257];
  int base = t * 16, c0 = 0;
  for (int u = 0; u < 16; ++u) c0 += (ids[base + u] == cand) ? 1 : 0;
  cnt[t + 1] = c0;
  __syncthreads();
  if (t == 0) {
    cnt[0] = 0;
    for (int i2 = 1; i2 <= 256; ++i2) cnt[i2] += cnt[i2 - 1];
  }
  __syncthreads();
  int ncand = cnt[256];
  int cr = cnt[t];
  for (int u = 0; u < 16; ++u) {
    int i2 = base + u;
    bool isC = (ids[i2] == cand);
    if (isC) {
      if (cr < NCMAX) posb[cr] = i2;
      cr++;
    } else {
      int nc = i2 - cr;
      int slot = ncand + nc;
      if (slot < NCMAX && nc >= 0) posb[slot] = i2;
    }
  }
  if (t < NCMAX) outp[NCMAX + t] = (t < ncand) ? 1.f : 0.f;
}

__global__ __launch_bounds__(256) void head_k(
    const float* __restrict__ x, const int* __restrict__ posb,
    const float* __restrict__ Wh1, const float* __restrict__ bh1,
    const float* __restrict__ Wh2, const float* __restrict__ bh2, float* __restrict__ outp) {
  int s = blockIdx.x, t = threadIdx.x;
  int p = posb[s];
  if (p < 0) p = 0;
  if (p >= LL) p = LL - 1;
  __shared__ float sx[H];
  __shared__ float sh[384];
  __shared__ float red[4];
  #pragma unroll
  for (int e = 0; e < 3; ++e) sx[t + e * 256] = x[(size_t)p * H + t + e * 256];
  __syncthreads();
  for (int j = t; j < 384; j += 256) {
    float a = bh1[j];
    for (int c = 0; c < H; ++c) a += sx[c] * Wh1[(size_t)c * 384 + j];
    sh[j] = geluf(a);
  }
  __syncthreads();
  float part = 0.f;
  for (int j = t; j < 384; j += 256) part += sh[j] * Wh2[j];
  part = wredsum(part);
  if ((t & 63) == 0) red[t >> 6] = part;
  __syncthreads();
  if (t == 0) {
    float tot = red[0] + red[1] + red[2] + red[3] + bh2[0];
    outp[s] = tot;
  }
}

// ---------------- launch ----------------
extern "C" void kernel_launch(void* const* d_in, const int* in_sizes, int n_in,
                              void* d_out, int out_size, void* d_ws, size_t ws_size,
                              hipStream_t stream) {
  const float* emb_tok = (const float*)d_in[0];
  const float* emb_pos = (const float*)d_in[1];
  const float* lnes = (const float*)d_in[2];
  const float* lneb = (const float*)d_in[3];
  const float* Wq = (const float*)d_in[4];
  const float* bq = (const float*)d_in[5];
  const float* Wk = (const float*)d_in[6];
  const float* bk = (const float*)d_in[7];
  const float* Wv = (const float*)d_in[8];
  const float* bv = (const float*)d_in[9];
  const float* Wqg = (const float*)d_in[10];
  const float* bqg = (const float*)d_in[11];
  const float* Wkg = (const float*)d_in[12];
  const float* bkg = (const float*)d_in[13];
  const float* Wvg = (const float*)d_in[14];
  const float* bvg = (const float*)d_in[15];
  const float* Wo = (const float*)d_in[16];
  const float* bo = (const float*)d_in[17];
  const float* ln1s = (const float*)d_in[18];
  const float* ln1b = (const float*)d_in[19];
  const float* W1 = (const float*)d_in[20];
  const float* b1 = (const float*)d_in[21];
  const float* W2 = (const float*)d_in[22];
  const float* b2 = (const float*)d_in[23];
  const float* ln2s = (const float*)d_in[24];
  const float* ln2b = (const float*)d_in[25];
  const float* Wh1 = (const float*)d_in[26];
  const float* bh1 = (const float*)d_in[27];
  const float* Wh2 = (const float*)d_in[28];
  const float* bh2 = (const float*)d_in[29];
  const int* ids = (const int*)d_in[30];
  int i_gpos = 32, i_cand = 33;
  if (!(n_in >= 34 && in_sizes[32] == GG)) {
    if (n_in >= 33 && in_sizes[31] == GG) { i_gpos = 31; i_cand = 32; }
  }
  const int* gpos = (const int*)d_in[i_gpos];
  const int* cand = (const int*)d_in[i_cand];
  float* outp = (float*)d_out;

  char* p = (char*)d_ws;
  auto alloc = [&](size_t bytes) {
    char* r = p;
    p += (bytes + 255) & ~(size_t)255;
    return r;
  };
  float* x = (float*)alloc((size_t)LL * H * 4);
  u16* xb = (u16*)alloc((size_t)LL * H * 2);
  u16* qb = (u16*)alloc((size_t)LL * H * 2);   // hb aliases qb..kgb
  u16* kb = (u16*)alloc((size_t)LL * H * 2);
  u16* vb = (u16*)alloc((size_t)LL * H * 2);
  u16* kgb = (u16*)alloc((size_t)LL * H * 2);
  u16* vgb = (u16*)alloc((size_t)LL * H * 2);
  u16* ob = (u16*)alloc((size_t)LL * H * 2);
  u16* qgb = (u16*)alloc((size_t)GG * H * 2);
  u16* xgb = (u16*)alloc((size_t)GG * H * 2);
  unsigned char* isg = (unsigned char*)alloc(LL);
  int* posb = (int*)alloc(64 * 4);
  u16* wtb = (u16*)alloc(WT_ELEMS * 2);
  float* sbuf = (float*)alloc((size_t)NH * 64 * 4096 * 4);
  float* obuf = (float*)alloc((size_t)NH * 64 * 64 * 4);
  u16* hb = qb;

  size_t used = (size_t)(p - (char*)d_ws);
  if (used > ws_size) used = ws_size;
  hipMemsetAsync(d_ws, 0, used, stream);

  embed_ln_k<<<LL, 256, 0, stream>>>(emb_tok, emb_pos, ids, lnes, lneb, x, xb);
  isglob_k<<<1, 256, 0, stream>>>(gpos, isg);
  positions_k<<<1, 256, 0, stream>>>(ids, cand, posb, outp);

  dim3 gP(H / 128, LL / 128);
  dim3 gF(FF / 128, LL / 128);
  dim3 gQKV(H / 128, LL / 128, 5);
  for (int l = 0; l < NL; ++l) {
    size_t lo = (size_t)l * H * H;
    conv_layer_k<<<2160, 256, 0, stream>>>(
        Wq + lo, Wk + lo, Wv + lo, Wkg + lo, Wvg + lo, Wqg + lo, Wo + lo,
        W1 + (size_t)l * H * FF, W2 + (size_t)l * FF * H, wtb);
    gemm_qkv_k<<<gQKV, 256, 0, stream>>>(xb, wtb,
        bq + l * H, bk + l * H, bv + l * H, bkg + l * H, bvg + l * H,
        qb, kb, vb, kgb, vgb);
    gather_k<<<GG, 256, 0, stream>>>(xb, gpos, xgb);
    gemm_bf_k<0, false, false><<<dim3(H / 128, 1), 256, 0, stream>>>(
        xgb, wtb + OFF_QG, bqg + l * H, nullptr, nullptr, qgb, GG, H, H);
    attn_local_k<<<dim3(NH, LL / 64), 256, 0, stream>>>(qb, kb, vb, kgb, vgb, gpos, isg, ob);
    ag_score_k<<<dim3(NH, LL / 128), 256, 0, stream>>>(qgb, kgb, sbuf);
    ag_soft_k<<<NH * 64, 256, 0, stream>>>(sbuf);
    ag_pv_k<<<dim3(NH, LL / 256), 256, 0, stream>>>(sbuf, vgb, obuf);
    ag_write_k<<<GG, 256, 0, stream>>>(obuf, gpos, ob);
    gemm_bf_k<0, true, true><<<gP, 256, 0, stream>>>(
        ob, wtb + OFF_O, bo + l * H, x, x, nullptr, LL, H, H);
    ln_k<<<LL, 256, 0, stream>>>(x, ln1s + l * H, ln1b + l * H, x, xb);
    gemm_bf_k<1, false, false><<<gF, 256, 0, stream>>>(
        xb, wtb + OFF_W1, b1 + l * FF, nullptr, nullptr, hb, LL, FF, H);
    gemm_bf_k<0, true, true><<<gP, 256, 0, stream>>>(
        hb, wtb + OFF_W2, b2 + l * H, x, x, nullptr, LL, H, FF);
    ln_k<<<LL, 256, 0, stream>>>(x, ln2s + l * H, ln2b + l * H, x, xb);
  }
  head_k<<<NCMAX, 256, 0, stream>>>(x, posb, Wh1, bh1, Wh2, bh2, outp);
}

// Round 7
// 1852.392 us; speedup vs baseline: 3.3762x; 1.3286x over previous
//
#include <hip/hip_runtime.h>
#include <hip/hip_bf16.h>
#include <math.h>

#define H 768
#define NH 12
#define DH 64
#define NL 6
#define FF 3072
#define LL 4096
#define GG 64
#define NCMAX 32

#define MATSZ (H * H)
#define OFF_QG ((size_t)5 * MATSZ)
#define OFF_O  ((size_t)6 * MATSZ)
#define OFF_W1 ((size_t)7 * MATSZ)
#define OFF_W2 (OFF_W1 + (size_t)H * FF)
#define WT_ELEMS (OFF_W2 + (size_t)FF * H)

typedef unsigned short u16;
typedef __attribute__((ext_vector_type(8))) unsigned short us8;
typedef __attribute__((ext_vector_type(4))) unsigned short us4;
typedef __attribute__((ext_vector_type(8))) __bf16 bf16x8;
typedef __attribute__((ext_vector_type(4))) float f32x4;

__device__ __forceinline__ float bf2f(u16 u) {
  unsigned v = ((unsigned)u) << 16;
  return __builtin_bit_cast(float, v);
}
__device__ __forceinline__ u16 f2bf(float f) {
  unsigned u = __builtin_bit_cast(unsigned, f);
  unsigned r = (u + 0x7fffu + ((u >> 16) & 1u)) >> 16;
  return (u16)r;
}
__device__ __forceinline__ float geluf(float a) {
  return 0.5f * a * (1.f + erff(a * 0.70710678118654752440f));
}
__device__ __forceinline__ float wredsum(float v) {
  #pragma unroll
  for (int o = 32; o; o >>= 1) v += __shfl_xor(v, o);
  return v;
}
__device__ __forceinline__ float wredmax(float v) {
  #pragma unroll
  for (int o = 32; o; o >>= 1) v = fmaxf(v, __shfl_xor(v, o));
  return v;
}
// async 16B global -> LDS (linear dest: wave-uniform base + lane*16)
__device__ __forceinline__ void gld16(const u16* g, u16* l) {
  __builtin_amdgcn_global_load_lds(
      (const __attribute__((address_space(1))) unsigned int*)(const void*)g,
      (__attribute__((address_space(3))) unsigned int*)(void*)l, 16, 0, 0);
}
// XCD-aware tile swizzle (nwg % 8 == 0 for all our grids)
__device__ __forceinline__ void tswz(int& bx, int& by) {
  int nx = gridDim.x, ny = gridDim.y;
  int flat = blockIdx.y * nx + blockIdx.x;
  int nwg = nx * ny;
  if ((nwg & 7) == 0) {
    int c = nwg >> 3;
    flat = (flat & 7) * c + (flat >> 3);
  }
  bx = flat % nx;
  by = flat / nx;
}

// ---------------- embed + LN (f32 inputs) ----------------
__global__ __launch_bounds__(256) void embed_ln_k(
    const float* __restrict__ et, const float* __restrict__ ep, const int* __restrict__ ids,
    const float* __restrict__ sc, const float* __restrict__ bi,
    float* __restrict__ x, u16* __restrict__ xb)
{
  int r = blockIdx.x, t = threadIdx.x;
  int tok = ids[r];
  if (tok < 0) tok = 0;
  if (tok >= 50272) tok = 50271;
  __shared__ float red[4];
  float v[3];
  #pragma unroll
  for (int e = 0; e < 3; ++e) {
    int c = t + e * 256;
    v[e] = et[(size_t)tok * H + c] + ep[(size_t)r * H + c];
  }
  float s = v[0] + v[1] + v[2];
  s = wredsum(s);
  if ((t & 63) == 0) red[t >> 6] = s;
  __syncthreads();
  float mean = (red[0] + red[1] + red[2] + red[3]) * (1.f / 768.f);
  __syncthreads();
  float q = 0.f;
  #pragma unroll
  for (int e = 0; e < 3; ++e) { float d = v[e] - mean; q += d * d; }
  q = wredsum(q);
  if ((t & 63) == 0) red[t >> 6] = q;
  __syncthreads();
  float var = (red[0] + red[1] + red[2] + red[3]) * (1.f / 768.f);
  float rs = rsqrtf(var + 1e-5f);
  #pragma unroll
  for (int e = 0; e < 3; ++e) {
    int c = t + e * 256;
    float o = (v[e] - mean) * rs * sc[c] + bi[c];
    x[(size_t)r * H + c] = o;
    xb[(size_t)r * H + c] = f2bf(o);
  }
}

// ---------------- LN with bias add: y = x + bias; x = LN(y) ----------------
__global__ __launch_bounds__(256) void ln_res_k(
    float* __restrict__ x, const float* __restrict__ bias,
    const float* __restrict__ sc, const float* __restrict__ bi, u16* __restrict__ xb)
{
  int r = blockIdx.x, t = threadIdx.x;
  __shared__ float red[4];
  float v[3];
  #pragma unroll
  for (int e = 0; e < 3; ++e) {
    int c = t + e * 256;
    v[e] = x[(size_t)r * H + c] + bias[c];
  }
  float s = v[0] + v[1] + v[2];
  s = wredsum(s);
  if ((t & 63) == 0) red[t >> 6] = s;
  __syncthreads();
  float mean = (red[0] + red[1] + red[2] + red[3]) * (1.f / 768.f);
  __syncthreads();
  float q = 0.f;
  #pragma unroll
  for (int e = 0; e < 3; ++e) { float d = v[e] - mean; q += d * d; }
  q = wredsum(q);
  if ((t & 63) == 0) red[t >> 6] = q;
  __syncthreads();
  float var = (red[0] + red[1] + red[2] + red[3]) * (1.f / 768.f);
  float rs = rsqrtf(var + 1e-5f);
  #pragma unroll
  for (int e = 0; e < 3; ++e) {
    int c = t + e * 256;
    float o = (v[e] - mean) * rs * sc[c] + bi[c];
    x[(size_t)r * H + c] = o;
    xb[(size_t)r * H + c] = f2bf(o);
  }
}

// ---------------- per-layer weight convert+transpose ----------------
__global__ __launch_bounds__(256) void conv_layer_k(
    const float* __restrict__ Wq, const float* __restrict__ Wk, const float* __restrict__ Wv,
    const float* __restrict__ Wkg, const float* __restrict__ Wvg, const float* __restrict__ Wqg,
    const float* __restrict__ Wo, const float* __restrict__ W1, const float* __restrict__ W2,
    u16* __restrict__ wt)
{
  int bid = blockIdx.x, t = threadIdx.x;
  const float* src;
  size_t ooff;
  int K, N, tile;
  if (bid < 1008) {
    int m = bid / 144;
    tile = bid % 144;
    K = H; N = H;
    ooff = (size_t)m * MATSZ;
    src = m == 0 ? Wq : m == 1 ? Wk : m == 2 ? Wv : m == 3 ? Wkg : m == 4 ? Wvg : m == 5 ? Wqg : Wo;
  } else if (bid < 1584) {
    tile = bid - 1008;
    K = H; N = FF;
    ooff = OFF_W1;
    src = W1;
  } else {
    tile = bid - 1584;
    K = FF; N = H;
    ooff = OFF_W2;
    src = W2;
  }
  int KT = K / 64;
  int kt = tile % KT, nt = tile / KT;
  __shared__ u16 sT[64 * 72];
  #pragma unroll
  for (int it = 0; it < 16; ++it) {
    int idx = t + it * 256;
    int n = idx & 63, kk = idx >> 6;
    sT[n * 72 + kk] = f2bf(src[(size_t)(kt * 64 + kk) * N + nt * 64 + n]);
  }
  __syncthreads();
  #pragma unroll
  for (int it = 0; it < 2; ++it) {
    int idx = t + it * 256;
    int n = idx >> 3, k8 = idx & 7;
    us8 val = *reinterpret_cast<const us8*>(&sT[n * 72 + k8 * 8]);
    *reinterpret_cast<us8*>(&wt[ooff + (size_t)(nt * 64 + n) * K + kt * 64 + k8 * 8]) = val;
  }
}

// ---- GEMM K-loop core. GLD: async staging (M,N multiples of 128 required). ----
template<bool GLD>
__device__ __forceinline__ void gemm_loop(
    const u16* __restrict__ A, const u16* __restrict__ Bt,
    int M, int N, int K, int m0, int n0, int kb, int ke,
    u16* lsA, u16* lsB, f32x4 acc[4][4])
{
  int t = threadIdx.x;
  int w = t >> 6, lane = t & 63;
  int cl = lane & 15, kgr = lane >> 4;
  int wm = (w >> 1) * 64, wn = (w & 1) * 64;
  us8 z8 = {0, 0, 0, 0, 0, 0, 0, 0};
  for (int k0 = kb; k0 < ke; k0 += 64) {
    if (GLD) {
      int ml = lane >> 3, k8 = lane & 7;
      #pragma unroll
      for (int it = 0; it < 4; ++it) {
        int chunk = it * 4 + w;
        int m = chunk * 8 + ml;
        gld16(A + (size_t)(m0 + m) * K + k0 + ((k8 ^ (m & 7)) * 8),
              &lsA[chunk * 512 + lane * 8]);
      }
      #pragma unroll
      for (int it = 0; it < 4; ++it) {
        int chunk = it * 4 + w;
        int n = chunk * 8 + ml;
        gld16(Bt + (size_t)(n0 + n) * K + k0 + ((k8 ^ (n & 7)) * 8),
              &lsB[chunk * 512 + lane * 8]);
      }
    } else {
      #pragma unroll
      for (int it = 0; it < 4; ++it) {
        int c = t + it * 256;
        int m = c >> 3, k8 = c & 7;
        us8 val = z8;
        int gm = m0 + m;
        if (gm < M) val = *reinterpret_cast<const us8*>(A + (size_t)gm * K + k0 + k8 * 8);
        *reinterpret_cast<us8*>(&lsA[m * 64 + ((k8 ^ (m & 7)) * 8)]) = val;
      }
      #pragma unroll
      for (int it = 0; it < 4; ++it) {
        int c = t + it * 256;
        int n = c >> 3, k8 = c & 7;
        us8 val = *reinterpret_cast<const us8*>(Bt + (size_t)(n0 + n) * K + k0 + k8 * 8);
        *reinterpret_cast<us8*>(&lsB[n * 64 + ((k8 ^ (n & 7)) * 8)]) = val;
      }
    }
    __syncthreads();
    #pragma unroll
    for (int kk = 0; kk < 2; ++kk) {
      bf16x8 fa[4], fb[4];
      int k8 = kk * 4 + kgr;
      #pragma unroll
      for (int i = 0; i < 4; ++i) {
        int mr = wm + i * 16 + cl;
        fa[i] = __builtin_bit_cast(bf16x8,
            *reinterpret_cast<const us8*>(&lsA[mr * 64 + ((k8 ^ (mr & 7)) * 8)]));
        int nr = wn + i * 16 + cl;
        fb[i] = __builtin_bit_cast(bf16x8,
            *reinterpret_cast<const us8*>(&lsB[nr * 64 + ((k8 ^ (nr & 7)) * 8)]));
      }
      #pragma unroll
      for (int i = 0; i < 4; ++i)
        #pragma unroll
        for (int j = 0; j < 4; ++j)
          acc[i][j] = __builtin_amdgcn_mfma_f32_16x16x32_bf16(fa[i], fb[j], acc[i][j], 0, 0, 0);
    }
    __syncthreads();
  }
}

// bf16-out GEMM with bias (+opt GELU)
template<int ACT, bool GLD>
__global__ __launch_bounds__(256) void gemm_bias_k(
    const u16* __restrict__ A, const u16* __restrict__ Bt, const float* __restrict__ bias,
    u16* __restrict__ outB, int M, int N, int K)
{
  __shared__ u16 lsA[128 * 64];
  __shared__ u16 lsB[128 * 64];
  int bx, by;
  tswz(bx, by);
  int m0 = by * 128, n0 = bx * 128;
  f32x4 zero4 = {0.f, 0.f, 0.f, 0.f};
  f32x4 acc[4][4];
  #pragma unroll
  for (int i = 0; i < 4; ++i)
    #pragma unroll
    for (int j = 0; j < 4; ++j) acc[i][j] = zero4;
  gemm_loop<GLD>(A, Bt, M, N, K, m0, n0, 0, K, lsA, lsB, acc);
  int lane = threadIdx.x & 63, w = threadIdx.x >> 6;
  int cl = lane & 15, kgr = lane >> 4;
  int wm = (w >> 1) * 64, wn = (w & 1) * 64;
  #pragma unroll
  for (int j = 0; j < 4; ++j) {
    int n = n0 + wn + j * 16 + cl;
    float bv = bias[n];
    #pragma unroll
    for (int i = 0; i < 4; ++i) {
      #pragma unroll
      for (int r = 0; r < 4; ++r) {
        int m = m0 + wm + i * 16 + kgr * 4 + r;
        if (m < M) {
          float vv = acc[i][j][r] + bv;
          if (ACT == 1) vv = geluf(vv);
          outB[(size_t)m * N + n] = f2bf(vv);
        }
      }
    }
  }
}

// split-K GEMM accumulating f32 partials into outF via atomicAdd (no bias)
__global__ __launch_bounds__(256) void gemm_acc_k(
    const u16* __restrict__ A, const u16* __restrict__ Bt, float* __restrict__ outF,
    int M, int N, int K)
{
  __shared__ u16 lsA[128 * 64];
  __shared__ u16 lsB[128 * 64];
  int bx, by;
  tswz(bx, by);
  int m0 = by * 128, n0 = bx * 128;
  int z = blockIdx.z, ns = gridDim.z;
  int ks = K / ns;
  f32x4 zero4 = {0.f, 0.f, 0.f, 0.f};
  f32x4 acc[4][4];
  #pragma unroll
  for (int i = 0; i < 4; ++i)
    #pragma unroll
    for (int j = 0; j < 4; ++j) acc[i][j] = zero4;
  gemm_loop<true>(A, Bt, M, N, K, m0, n0, z * ks, (z + 1) * ks, lsA, lsB, acc);
  int lane = threadIdx.x & 63, w = threadIdx.x >> 6;
  int cl = lane & 15, kgr = lane >> 4;
  int wm = (w >> 1) * 64, wn = (w & 1) * 64;
  #pragma unroll
  for (int j = 0; j < 4; ++j) {
    int n = n0 + wn + j * 16 + cl;
    #pragma unroll
    for (int i = 0; i < 4; ++i) {
      #pragma unroll
      for (int r = 0; r < 4; ++r) {
        int m = m0 + wm + i * 16 + kgr * 4 + r;
        atomicAdd(&outF[(size_t)m * N + n], acc[i][j][r]);
      }
    }
  }
}

// fused 5-way projection GEMM (z selects weight/bias/out)
__global__ __launch_bounds__(256) void gemm_qkv_k(
    const u16* __restrict__ A, const u16* __restrict__ wt,
    const float* c0, const float* c1, const float* c2, const float* c3, const float* c4,
    u16* o0, u16* o1, u16* o2, u16* o3, u16* o4)
{
  __shared__ u16 lsA[128 * 64];
  __shared__ u16 lsB[128 * 64];
  int z = blockIdx.z;
  const u16* Bt = wt + (size_t)z * MATSZ;
  const float* bias = z == 0 ? c0 : z == 1 ? c1 : z == 2 ? c2 : z == 3 ? c3 : c4;
  u16* outB = z == 0 ? o0 : z == 1 ? o1 : z == 2 ? o2 : z == 3 ? o3 : o4;
  int bx, by;
  tswz(bx, by);
  int m0 = by * 128, n0 = bx * 128;
  f32x4 zero4 = {0.f, 0.f, 0.f, 0.f};
  f32x4 acc[4][4];
  #pragma unroll
  for (int i = 0; i < 4; ++i)
    #pragma unroll
    for (int j = 0; j < 4; ++j) acc[i][j] = zero4;
  gemm_loop<true>(A, Bt, LL, H, H, m0, n0, 0, H, lsA, lsB, acc);
  int lane = threadIdx.x & 63, w = threadIdx.x >> 6;
  int cl = lane & 15, kgr = lane >> 4;
  int wm = (w >> 1) * 64, wn = (w & 1) * 64;
  #pragma unroll
  for (int j = 0; j < 4; ++j) {
    int n = n0 + wn + j * 16 + cl;
    float bv = bias[n];
    #pragma unroll
    for (int i = 0; i < 4; ++i) {
      #pragma unroll
      for (int r = 0; r < 4; ++r) {
        int m = m0 + wm + i * 16 + kgr * 4 + r;
        outB[(size_t)m * H + n] = f2bf(acc[i][j][r] + bv);
      }
    }
  }
}

// ---------------- MFMA flash local attention ----------------
__global__ __launch_bounds__(256) void attn_local_k(
    const u16* __restrict__ q, const u16* __restrict__ k, const u16* __restrict__ v,
    const u16* __restrict__ kgp, const u16* __restrict__ vgp,
    const int* __restrict__ gpos, const unsigned char* __restrict__ isg,
    u16* __restrict__ out)
{
  int h = blockIdx.x;
  int q0 = blockIdx.y * 64;
  int nb = q0 >> 8;
  int cs = (nb - 1) * 256;
  int t = threadIdx.x;
  int w = t >> 6, lane = t & 63;
  int cl = lane & 15, g = lane >> 4;
  __shared__ u16 sK[64 * 64];
  __shared__ u16 sVt[64 * 64];
  __shared__ u16 sP[64 * 64];
  __shared__ unsigned char sOk[64];
  us8 z8 = {0, 0, 0, 0, 0, 0, 0, 0};
  f32x4 zero4 = {0.f, 0.f, 0.f, 0.f};

  int qrow = q0 + w * 16 + cl;
  bf16x8 qa[2];
  #pragma unroll
  for (int ks = 0; ks < 2; ++ks)
    qa[ks] = __builtin_bit_cast(bf16x8, *reinterpret_cast<const us8*>(
        &q[(size_t)qrow * H + h * 64 + ks * 32 + g * 8]));

  f32x4 O[4];
  #pragma unroll
  for (int dt = 0; dt < 4; ++dt) O[dt] = zero4;
  float mrow[4], lrow[4];
  #pragma unroll
  for (int r = 0; r < 4; ++r) { mrow[r] = -1e30f; lrow[r] = 0.f; }

  for (int c = 0; c < 13; ++c) {
    #pragma unroll
    for (int it = 0; it < 2; ++it) {
      int idx = t + it * 256;
      int key = idx >> 3, d8 = idx & 7;
      us8 val = z8;
      if (c < 12) {
        int pos = cs + c * 64 + key;
        if (pos >= 0 && pos < LL)
          val = *reinterpret_cast<const us8*>(&k[(size_t)pos * H + h * 64 + d8 * 8]);
      } else {
        int pos = gpos[key];
        if (pos < 0) pos = 0;
        if (pos >= LL) pos = LL - 1;
        val = *reinterpret_cast<const us8*>(&kgp[(size_t)pos * H + h * 64 + d8 * 8]);
      }
      *reinterpret_cast<us8*>(&sK[key * 64 + ((d8 ^ (key & 7)) * 8)]) = val;
    }
    #pragma unroll
    for (int it = 0; it < 2; ++it) {
      int idx = t + it * 256;
      int dim = idx >> 3, k8 = idx & 7;
      us8 val = z8;
      if (c < 12) {
        #pragma unroll
        for (int jj = 0; jj < 8; ++jj) {
          int pos = cs + c * 64 + k8 * 8 + jj;
          val[jj] = (pos >= 0 && pos < LL) ? v[(size_t)pos * H + h * 64 + dim] : (u16)0;
        }
      } else {
        #pragma unroll
        for (int jj = 0; jj < 8; ++jj) {
          int pos = gpos[k8 * 8 + jj];
          if (pos < 0) pos = 0;
          if (pos >= LL) pos = LL - 1;
          val[jj] = vgp[(size_t)pos * H + h * 64 + dim];
        }
      }
      *reinterpret_cast<us8*>(&sVt[dim * 64 + ((k8 ^ (dim & 7)) * 8)]) = val;
    }
    if (t < 64) {
      int ok = 1;
      if (c < 12) {
        int pos = cs + c * 64 + t;
        ok = (pos >= 0 && pos < LL) ? (isg[pos] ? 0 : 1) : 0;
      }
      sOk[t] = (unsigned char)ok;
    }
    __syncthreads();

    f32x4 S[4];
    #pragma unroll
    for (int T = 0; T < 4; ++T) {
      S[T] = zero4;
      int key = T * 16 + cl;
      #pragma unroll
      for (int ks = 0; ks < 2; ++ks) {
        bf16x8 kf = __builtin_bit_cast(bf16x8, *reinterpret_cast<const us8*>(
            &sK[key * 64 + (((ks * 4 + g) ^ (key & 7)) * 8)]));
        S[T] = __builtin_amdgcn_mfma_f32_16x16x32_bf16(qa[ks], kf, S[T], 0, 0, 0);
      }
    }
    #pragma unroll
    for (int T = 0; T < 4; ++T) {
      int key = T * 16 + cl;
      int okk = sOk[key];
      int pos = cs + c * 64 + key;
      #pragma unroll
      for (int r = 0; r < 4; ++r) {
        int qp = q0 + w * 16 + g * 4 + r;
        int d = pos - qp;
        bool ok = okk && (c == 12 || (d >= -256 && d <= 256));
        S[T][r] = ok ? S[T][r] * 0.125f : -1e9f;
      }
    }
    float cm[4];
    #pragma unroll
    for (int r = 0; r < 4; ++r) {
      cm[r] = fmaxf(fmaxf(S[0][r], S[1][r]), fmaxf(S[2][r], S[3][r]));
      cm[r] = fmaxf(cm[r], __shfl_xor(cm[r], 1));
      cm[r] = fmaxf(cm[r], __shfl_xor(cm[r], 2));
      cm[r] = fmaxf(cm[r], __shfl_xor(cm[r], 4));
      cm[r] = fmaxf(cm[r], __shfl_xor(cm[r], 8));
    }
    float sc[4];
    #pragma unroll
    for (int r = 0; r < 4; ++r) {
      float mn = fmaxf(mrow[r], cm[r]);
      sc[r] = __expf(mrow[r] - mn);
      mrow[r] = mn;
    }
    float rs[4] = {0.f, 0.f, 0.f, 0.f};
    #pragma unroll
    for (int T = 0; T < 4; ++T) {
      int key = T * 16 + cl;
      #pragma unroll
      for (int r = 0; r < 4; ++r) {
        float sv = S[T][r];
        float pv = sv > -1e8f ? __expf(sv - mrow[r]) : 0.f;
        rs[r] += pv;
        int qloc = w * 16 + g * 4 + r;
        int k8s = (key >> 3) ^ (qloc & 7);
        sP[qloc * 64 + k8s * 8 + (key & 7)] = f2bf(pv);
      }
    }
    #pragma unroll
    for (int r = 0; r < 4; ++r) {
      rs[r] += __shfl_xor(rs[r], 1);
      rs[r] += __shfl_xor(rs[r], 2);
      rs[r] += __shfl_xor(rs[r], 4);
      rs[r] += __shfl_xor(rs[r], 8);
      lrow[r] = lrow[r] * sc[r] + rs[r];
    }
    #pragma unroll
    for (int dt = 0; dt < 4; ++dt)
      #pragma unroll
      for (int r = 0; r < 4; ++r) O[dt][r] *= sc[r];
    int prow = w * 16 + cl;
    #pragma unroll
    for (int ks = 0; ks < 2; ++ks) {
      bf16x8 pf = __builtin_bit_cast(bf16x8, *reinterpret_cast<const us8*>(
          &sP[prow * 64 + (((ks * 4 + g) ^ (prow & 7)) * 8)]));
      #pragma unroll
      for (int dt = 0; dt < 4; ++dt) {
        int dim = dt * 16 + cl;
        bf16x8 vf = __builtin_bit_cast(bf16x8, *reinterpret_cast<const us8*>(
            &sVt[dim * 64 + (((ks * 4 + g) ^ (dim & 7)) * 8)]));
        O[dt] = __builtin_amdgcn_mfma_f32_16x16x32_bf16(pf, vf, O[dt], 0, 0, 0);
      }
    }
    __syncthreads();
  }
  #pragma unroll
  for (int r = 0; r < 4; ++r) {
    float inv = 1.f / lrow[r];
    int qp = q0 + w * 16 + g * 4 + r;
    #pragma unroll
    for (int dt = 0; dt < 4; ++dt)
      out[(size_t)qp * H + h * 64 + dt * 16 + cl] = f2bf(O[dt][r] * inv);
  }
}

// ---------------- global attention ----------------
__global__ __launch_bounds__(256) void ag_score_k(
    const u16* __restrict__ qg, const u16* __restrict__ kg, float* __restrict__ sbuf)
{
  int h = blockIdx.x;
  int kc0 = blockIdx.y * 128;
  int t = threadIdx.x;
  int w = t >> 6, lane = t & 63;
  int cl = lane & 15, g = lane >> 4;
  __shared__ u16 sK[128 * 64];
  #pragma unroll
  for (int it = 0; it < 4; ++it) {
    int c = t + it * 256;
    int key = c >> 3, d8 = c & 7;
    us8 val = *reinterpret_cast<const us8*>(&kg[(size_t)(kc0 + key) * H + h * 64 + d8 * 8]);
    *reinterpret_cast<us8*>(&sK[key * 64 + ((d8 ^ (key & 7)) * 8)]) = val;
  }
  int qrow = w * 16 + cl;
  bf16x8 qa[2];
  #pragma unroll
  for (int ks = 0; ks < 2; ++ks)
    qa[ks] = __builtin_bit_cast(bf16x8, *reinterpret_cast<const us8*>(
        &qg[(size_t)qrow * H + h * 64 + ks * 32 + g * 8]));
  __syncthreads();
  f32x4 zero4 = {0.f, 0.f, 0.f, 0.f};
  #pragma unroll
  for (int j = 0; j < 8; ++j) {
    f32x4 S = zero4;
    int key = j * 16 + cl;
    #pragma unroll
    for (int ks = 0; ks < 2; ++ks) {
      bf16x8 kf = __builtin_bit_cast(bf16x8, *reinterpret_cast<const us8*>(
          &sK[key * 64 + (((ks * 4 + g) ^ (key & 7)) * 8)]));
      S = __builtin_amdgcn_mfma_f32_16x16x32_bf16(qa[ks], kf, S, 0, 0, 0);
    }
    #pragma unroll
    for (int r = 0; r < 4; ++r) {
      int grow = w * 16 + g * 4 + r;
      sbuf[((size_t)(h * 64 + grow)) * 4096 + kc0 + key] = S[r] * 0.125f;
    }
  }
}

__global__ __launch_bounds__(256) void ag_soft_k(float* __restrict__ sbuf)
{
  int row = blockIdx.x, t = threadIdx.x;
  float* base = sbuf + (size_t)row * 4096;
  u16* pb = (u16*)(sbuf) + (size_t)row * 8192;
  __shared__ float red[4];
  f32x4 rv[4];
  #pragma unroll
  for (int it = 0; it < 4; ++it)
    rv[it] = *reinterpret_cast<const f32x4*>(base + it * 1024 + t * 4);
  float m = -1e30f;
  #pragma unroll
  for (int it = 0; it < 4; ++it)
    #pragma unroll
    for (int u = 0; u < 4; ++u) m = fmaxf(m, rv[it][u]);
  m = wredmax(m);
  if ((t & 63) == 0) red[t >> 6] = m;
  __syncthreads();
  m = fmaxf(fmaxf(red[0], red[1]), fmaxf(red[2], red[3]));
  __syncthreads();
  float s = 0.f;
  #pragma unroll
  for (int it = 0; it < 4; ++it)
    #pragma unroll
    for (int u = 0; u < 4; ++u) {
      float e = __expf(rv[it][u] - m);
      rv[it][u] = e;
      s += e;
    }
  s = wredsum(s);
  if ((t & 63) == 0) red[t >> 6] = s;
  __syncthreads();
  float inv = 1.f / (red[0] + red[1] + red[2] + red[3]);
  #pragma unroll
  for (int it = 0; it < 4; ++it) {
    us4 o;
    #pragma unroll
    for (int u = 0; u < 4; ++u) o[u] = f2bf(rv[it][u] * inv);
    *reinterpret_cast<us4*>(pb + it * 1024 + t * 4) = o;
  }
}

__global__ __launch_bounds__(256) void ag_pv_k(
    const float* __restrict__ sbuf, const u16* __restrict__ vg, float* __restrict__ obuf)
{
  int h = blockIdx.x;
  int kb0 = blockIdx.y * 256;
  int t = threadIdx.x;
  int w = t >> 6, lane = t & 63;
  int cl = lane & 15, g = lane >> 4;
  __shared__ u16 sVt[64 * 64];
  f32x4 zero4 = {0.f, 0.f, 0.f, 0.f};
  f32x4 O[4];
  #pragma unroll
  for (int dt = 0; dt < 4; ++dt) O[dt] = zero4;
  const u16* pb = (const u16*)(sbuf);
  int prow = w * 16 + cl;
  size_t pbase = (size_t)(h * 64 + prow) * 8192;

  for (int cc = 0; cc < 4; ++cc) {
    int kc = kb0 + cc * 64;
    #pragma unroll
    for (int it = 0; it < 2; ++it) {
      int idx = t + it * 256;
      int dim = idx >> 3, k8 = idx & 7;
      us8 val;
      #pragma unroll
      for (int jj = 0; jj < 8; ++jj)
        val[jj] = vg[(size_t)(kc + k8 * 8 + jj) * H + h * 64 + dim];
      *reinterpret_cast<us8*>(&sVt[dim * 64 + ((k8 ^ (dim & 7)) * 8)]) = val;
    }
    __syncthreads();
    #pragma unroll
    for (int ks = 0; ks < 2; ++ks) {
      bf16x8 pf = __builtin_bit_cast(bf16x8, *reinterpret_cast<const us8*>(
          pb + pbase + kc + (ks * 4 + g) * 8));
      #pragma unroll
      for (int dt = 0; dt < 4; ++dt) {
        int dim = dt * 16 + cl;
        bf16x8 vf = __builtin_bit_cast(bf16x8, *reinterpret_cast<const us8*>(
            &sVt[dim * 64 + (((ks * 4 + g) ^ (dim & 7)) * 8)]));
        O[dt] = __builtin_amdgcn_mfma_f32_16x16x32_bf16(pf, vf, O[dt], 0, 0, 0);
      }
    }
    __syncthreads();
  }
  #pragma unroll
  for (int r = 0; r < 4; ++r) {
    int grow = w * 16 + g * 4 + r;
    #pragma unroll
    for (int dt = 0; dt < 4; ++dt)
      atomicAdd(&obuf[((size_t)h * 64 + grow) * 64 + dt * 16 + cl], O[dt][r]);
  }
}

// scatter obuf rows to ob, then RE-ZERO obuf for next layer (bug fix)
__global__ __launch_bounds__(256) void ag_write_k(
    float* __restrict__ obuf, const int* __restrict__ gpos, u16* __restrict__ out)
{
  int g = blockIdx.x, t = threadIdx.x;
  int gp = gpos[g];
  if (gp < 0) gp = 0;
  if (gp >= LL) gp = LL - 1;
  #pragma unroll
  for (int e = 0; e < 3; ++e) {
    int c = t + e * 256;
    int h = c >> 6, d = c & 63;
    size_t idx = ((size_t)h * 64 + g) * 64 + d;
    out[(size_t)gp * H + c] = f2bf(obuf[idx]);
    obuf[idx] = 0.f;
  }
}

// ---------------- misc small kernels ----------------
__global__ void isglob_k(const int* __restrict__ gpos, unsigned char* __restrict__ isg) {
  int t = threadIdx.x;
  for (int i = t; i < LL; i += 256) isg[i] = 0;
  __syncthreads();
  if (t < GG) {
    int gp = gpos[t];
    if (gp >= 0 && gp < LL) isg[gp] = 1;
  }
}

__global__ void gather_k(const u16* __restrict__ xb, const int* __restrict__ gpos,
                         u16* __restrict__ xgb) {
  int g = blockIdx.x, t = threadIdx.x;
  int p = gpos[g];
  if (p < 0) p = 0;
  if (p >= LL) p = LL - 1;
  #pragma unroll
  for (int e = 0; e < 3; ++e)
    xgb[(size_t)g * H + t + e * 256] = xb[(size_t)p * H + t + e * 256];
}

__global__ void positions_k(const int* __restrict__ ids, const int* __restrict__ candp,
                            int* __restrict__ posb, float* __restrict__ outp) {
  int t = threadIdx.x;
  int cand = candp[0];
  __shared__ int cnt[257];
  int base = t * 16, c0 = 0;
  for (int u = 0; u < 16; ++u) c0 += (ids[base + u] == cand) ? 1 : 0;
  cnt[t + 1] = c0;
  __syncthreads();
  if (t == 0) {
    cnt[0] = 0;
    for (int i2 = 1; i2 <= 256; ++i2) cnt[i2] += cnt[i2 - 1];
  }
  __syncthreads();
  int ncand = cnt[256];
  int cr = cnt[t];
  for (int u = 0; u < 16; ++u) {
    int i2 = base + u;
    bool isC = (ids[i2] == cand);
    if (isC) {
      if (cr < NCMAX) posb[cr] = i2;
      cr++;
    } else {
      int nc = i2 - cr;
      int slot = ncand + nc;
      if (slot < NCMAX && nc >= 0) posb[slot] = i2;
    }
  }
  if (t < NCMAX) outp[NCMAX + t] = (t < ncand) ? 1.f : 0.f;
}

__global__ __launch_bounds__(256) void head_k(
    const float* __restrict__ x, const int* __restrict__ posb,
    const float* __restrict__ Wh1, const float* __restrict__ bh1,
    const float* __restrict__ Wh2, const float* __restrict__ bh2, float* __restrict__ outp) {
  int s = blockIdx.x, t = threadIdx.x;
  int p = posb[s];
  if (p < 0) p = 0;
  if (p >= LL) p = LL - 1;
  __shared__ float sx[H];
  __shared__ float sh[384];
  __shared__ float red[4];
  #pragma unroll
  for (int e = 0; e < 3; ++e) sx[t + e * 256] = x[(size_t)p * H + t + e * 256];
  __syncthreads();
  for (int j = t; j < 384; j += 256) {
    float a = bh1[j];
    for (int c = 0; c < H; ++c) a += sx[c] * Wh1[(size_t)c * 384 + j];
    sh[j] = geluf(a);
  }
  __syncthreads();
  float part = 0.f;
  for (int j = t; j < 384; j += 256) part += sh[j] * Wh2[j];
  part = wredsum(part);
  if ((t & 63) == 0) red[t >> 6] = part;
  __syncthreads();
  if (t == 0) {
    float tot = red[0] + red[1] + red[2] + red[3] + bh2[0];
    outp[s] = tot;
  }
}

// ---------------- launch ----------------
extern "C" void kernel_launch(void* const* d_in, const int* in_sizes, int n_in,
                              void* d_out, int out_size, void* d_ws, size_t ws_size,
                              hipStream_t stream) {
  const float* emb_tok = (const float*)d_in[0];
  const float* emb_pos = (const float*)d_in[1];
  const float* lnes = (const float*)d_in[2];
  const float* lneb = (const float*)d_in[3];
  const float* Wq = (const float*)d_in[4];
  const float* bq = (const float*)d_in[5];
  const float* Wk = (const float*)d_in[6];
  const float* bk = (const float*)d_in[7];
  const float* Wv = (const float*)d_in[8];
  const float* bv = (const float*)d_in[9];
  const float* Wqg = (const float*)d_in[10];
  const float* bqg = (const float*)d_in[11];
  const float* Wkg = (const float*)d_in[12];
  const float* bkg = (const float*)d_in[13];
  const float* Wvg = (const float*)d_in[14];
  const float* bvg = (const float*)d_in[15];
  const float* Wo = (const float*)d_in[16];
  const float* bo = (const float*)d_in[17];
  const float* ln1s = (const float*)d_in[18];
  const float* ln1b = (const float*)d_in[19];
  const float* W1 = (const float*)d_in[20];
  const float* b1 = (const float*)d_in[21];
  const float* W2 = (const float*)d_in[22];
  const float* b2 = (const float*)d_in[23];
  const float* ln2s = (const float*)d_in[24];
  const float* ln2b = (const float*)d_in[25];
  const float* Wh1 = (const float*)d_in[26];
  const float* bh1 = (const float*)d_in[27];
  const float* Wh2 = (const float*)d_in[28];
  const float* bh2 = (const float*)d_in[29];
  const int* ids = (const int*)d_in[30];
  int i_gpos = 32, i_cand = 33;
  if (!(n_in >= 34 && in_sizes[32] == GG)) {
    if (n_in >= 33 && in_sizes[31] == GG) { i_gpos = 31; i_cand = 32; }
  }
  const int* gpos = (const int*)d_in[i_gpos];
  const int* cand = (const int*)d_in[i_cand];
  float* outp = (float*)d_out;

  char* p = (char*)d_ws;
  auto alloc = [&](size_t bytes) {
    char* r = p;
    p += (bytes + 255) & ~(size_t)255;
    return r;
  };
  float* x = (float*)alloc((size_t)LL * H * 4);
  u16* xb = (u16*)alloc((size_t)LL * H * 2);
  u16* qb = (u16*)alloc((size_t)LL * H * 2);   // hb aliases qb..kgb
  u16* kb = (u16*)alloc((size_t)LL * H * 2);
  u16* vb = (u16*)alloc((size_t)LL * H * 2);
  u16* kgb = (u16*)alloc((size_t)LL * H * 2);
  u16* vgb = (u16*)alloc((size_t)LL * H * 2);
  u16* ob = (u16*)alloc((size_t)LL * H * 2);
  u16* qgb = (u16*)alloc((size_t)GG * H * 2);
  u16* xgb = (u16*)alloc((size_t)GG * H * 2);
  unsigned char* isg = (unsigned char*)alloc(LL);
  int* posb = (int*)alloc(64 * 4);
  u16* wtb = (u16*)alloc(WT_ELEMS * 2);
  float* sbuf = (float*)alloc((size_t)NH * 64 * 4096 * 4);
  float* obuf = (float*)alloc((size_t)NH * 64 * 64 * 4);
  u16* hb = qb;

  size_t used = (size_t)(p - (char*)d_ws);
  if (used > ws_size) used = ws_size;
  hipMemsetAsync(d_ws, 0, used, stream);

  embed_ln_k<<<LL, 256, 0, stream>>>(emb_tok, emb_pos, ids, lnes, lneb, x, xb);
  isglob_k<<<1, 256, 0, stream>>>(gpos, isg);
  positions_k<<<1, 256, 0, stream>>>(ids, cand, posb, outp);

  dim3 gP2(H / 128, LL / 128, 2);
  dim3 gP4(H / 128, LL / 128, 4);
  dim3 gF(FF / 128, LL / 128);
  dim3 gQKV(H / 128, LL / 128, 5);
  for (int l = 0; l < NL; ++l) {
    size_t lo = (size_t)l * H * H;
    conv_layer_k<<<2160, 256, 0, stream>>>(
        Wq + lo, Wk + lo, Wv + lo, Wkg + lo, Wvg + lo, Wqg + lo, Wo + lo,
        W1 + (size_t)l * H * FF, W2 + (size_t)l * FF * H, wtb);
    gemm_qkv_k<<<gQKV, 256, 0, stream>>>(xb, wtb,
        bq + l * H, bk + l * H, bv + l * H, bkg + l * H, bvg + l * H,
        qb, kb, vb, kgb, vgb);
    gather_k<<<GG, 256, 0, stream>>>(xb, gpos, xgb);
    gemm_bias_k<0, false><<<dim3(H / 128, 1), 256, 0, stream>>>(
        xgb, wtb + OFF_QG, bqg + l * H, qgb, GG, H, H);
    attn_local_k<<<dim3(NH, LL / 64), 256, 0, stream>>>(qb, kb, vb, kgb, vgb, gpos, isg, ob);
    ag_score_k<<<dim3(NH, LL / 128), 256, 0, stream>>>(qgb, kgb, sbuf);
    ag_soft_k<<<NH * 64, 256, 0, stream>>>(sbuf);
    ag_pv_k<<<dim3(NH, LL / 256), 256, 0, stream>>>(sbuf, vgb, obuf);
    ag_write_k<<<GG, 256, 0, stream>>>(obuf, gpos, ob);
    // x += ob @ Wo (split-K=2, atomic f32); then LN with +bo
    gemm_acc_k<<<gP2, 256, 0, stream>>>(ob, wtb + OFF_O, x, LL, H, H);
    ln_res_k<<<LL, 256, 0, stream>>>(x, bo + l * H, ln1s + l * H, ln1b + l * H, xb);
    gemm_bias_k<1, true><<<gF, 256, 0, stream>>>(
        xb, wtb + OFF_W1, b1 + l * FF, hb, LL, FF, H);
    // x += hb @ W2 (split-K=4, atomic f32); then LN with +b2
    gemm_acc_k<<<gP4, 256, 0, stream>>>(hb, wtb + OFF_W2, x, LL, H, FF);
    ln_res_k<<<LL, 256, 0, stream>>>(x, b2 + l * H, ln2s + l * H, ln2b + l * H, xb);
  }
  head_k<<<NCMAX, 256, 0, stream>>>(x, posb, Wh1, bh1, Wh2, bh2, outp);
}

// Round 8
// 1653.414 us; speedup vs baseline: 3.7825x; 1.1203x over previous
//
#include <hip/hip_runtime.h>
#include <hip/hip_bf16.h>
#include <math.h>

#define H 768
#define NH 12
#define DH 64
#define NL 6
#define FF 3072
#define LL 4096
#define GG 64
#define NCMAX 32

#define MATSZ (H * H)
#define OFF_QG ((size_t)5 * MATSZ)
#define OFF_O  ((size_t)6 * MATSZ)
#define OFF_W1 ((size_t)7 * MATSZ)
#define OFF_W2 (OFF_W1 + (size_t)H * FF)
#define WT_ELEMS (OFF_W2 + (size_t)FF * H)

typedef unsigned short u16;
typedef __attribute__((ext_vector_type(8))) unsigned short us8;
typedef __attribute__((ext_vector_type(4))) unsigned short us4;
typedef __attribute__((ext_vector_type(8))) __bf16 bf16x8;
typedef __attribute__((ext_vector_type(4))) float f32x4;

__device__ __forceinline__ float bf2f(u16 u) {
  unsigned v = ((unsigned)u) << 16;
  return __builtin_bit_cast(float, v);
}
__device__ __forceinline__ u16 f2bf(float f) {
  unsigned u = __builtin_bit_cast(unsigned, f);
  unsigned r = (u + 0x7fffu + ((u >> 16) & 1u)) >> 16;
  return (u16)r;
}
__device__ __forceinline__ float geluf(float a) {
  return 0.5f * a * (1.f + erff(a * 0.70710678118654752440f));
}
__device__ __forceinline__ float wredsum(float v) {
  #pragma unroll
  for (int o = 32; o; o >>= 1) v += __shfl_xor(v, o);
  return v;
}
__device__ __forceinline__ float wredmax(float v) {
  #pragma unroll
  for (int o = 32; o; o >>= 1) v = fmaxf(v, __shfl_xor(v, o));
  return v;
}
__device__ __forceinline__ void gld16(const u16* g, u16* l) {
  __builtin_amdgcn_global_load_lds(
      (const __attribute__((address_space(1))) unsigned int*)(const void*)g,
      (__attribute__((address_space(3))) unsigned int*)(void*)l, 16, 0, 0);
}
__device__ __forceinline__ void tswz(int& bx, int& by) {
  int nx = gridDim.x, ny = gridDim.y;
  int flat = blockIdx.y * nx + blockIdx.x;
  int nwg = nx * ny;
  if ((nwg & 7) == 0) {
    int c = nwg >> 3;
    flat = (flat & 7) * c + (flat >> 3);
  }
  bx = flat % nx;
  by = flat / nx;
}

// ---------------- embed + LN (f32 inputs) ----------------
__global__ __launch_bounds__(256) void embed_ln_k(
    const float* __restrict__ et, const float* __restrict__ ep, const int* __restrict__ ids,
    const float* __restrict__ sc, const float* __restrict__ bi,
    float* __restrict__ x, u16* __restrict__ xb)
{
  int r = blockIdx.x, t = threadIdx.x;
  int tok = ids[r];
  if (tok < 0) tok = 0;
  if (tok >= 50272) tok = 50271;
  __shared__ float red[4];
  float v[3];
  #pragma unroll
  for (int e = 0; e < 3; ++e) {
    int c = t + e * 256;
    v[e] = et[(size_t)tok * H + c] + ep[(size_t)r * H + c];
  }
  float s = v[0] + v[1] + v[2];
  s = wredsum(s);
  if ((t & 63) == 0) red[t >> 6] = s;
  __syncthreads();
  float mean = (red[0] + red[1] + red[2] + red[3]) * (1.f / 768.f);
  __syncthreads();
  float q = 0.f;
  #pragma unroll
  for (int e = 0; e < 3; ++e) { float d = v[e] - mean; q += d * d; }
  q = wredsum(q);
  if ((t & 63) == 0) red[t >> 6] = q;
  __syncthreads();
  float var = (red[0] + red[1] + red[2] + red[3]) * (1.f / 768.f);
  float rs = rsqrtf(var + 1e-5f);
  #pragma unroll
  for (int e = 0; e < 3; ++e) {
    int c = t + e * 256;
    float o = (v[e] - mean) * rs * sc[c] + bi[c];
    x[(size_t)r * H + c] = o;
    xb[(size_t)r * H + c] = f2bf(o);
  }
}

// ---------------- LN with bias add: y = x + bias; x = LN(y) ----------------
__global__ __launch_bounds__(256) void ln_res_k(
    float* __restrict__ x, const float* __restrict__ bias,
    const float* __restrict__ sc, const float* __restrict__ bi, u16* __restrict__ xb)
{
  int r = blockIdx.x, t = threadIdx.x;
  __shared__ float red[4];
  float v[3];
  #pragma unroll
  for (int e = 0; e < 3; ++e) {
    int c = t + e * 256;
    v[e] = x[(size_t)r * H + c] + bias[c];
  }
  float s = v[0] + v[1] + v[2];
  s = wredsum(s);
  if ((t & 63) == 0) red[t >> 6] = s;
  __syncthreads();
  float mean = (red[0] + red[1] + red[2] + red[3]) * (1.f / 768.f);
  __syncthreads();
  float q = 0.f;
  #pragma unroll
  for (int e = 0; e < 3; ++e) { float d = v[e] - mean; q += d * d; }
  q = wredsum(q);
  if ((t & 63) == 0) red[t >> 6] = q;
  __syncthreads();
  float var = (red[0] + red[1] + red[2] + red[3]) * (1.f / 768.f);
  float rs = rsqrtf(var + 1e-5f);
  #pragma unroll
  for (int e = 0; e < 3; ++e) {
    int c = t + e * 256;
    float o = (v[e] - mean) * rs * sc[c] + bi[c];
    x[(size_t)r * H + c] = o;
    xb[(size_t)r * H + c] = f2bf(o);
  }
}

// ---------------- per-layer weight convert+transpose ----------------
__global__ __launch_bounds__(256) void conv_layer_k(
    const float* __restrict__ Wq, const float* __restrict__ Wk, const float* __restrict__ Wv,
    const float* __restrict__ Wkg, const float* __restrict__ Wvg, const float* __restrict__ Wqg,
    const float* __restrict__ Wo, const float* __restrict__ W1, const float* __restrict__ W2,
    u16* __restrict__ wt)
{
  int bid = blockIdx.x, t = threadIdx.x;
  const float* src;
  size_t ooff;
  int K, N, tile;
  if (bid < 1008) {
    int m = bid / 144;
    tile = bid % 144;
    K = H; N = H;
    ooff = (size_t)m * MATSZ;
    src = m == 0 ? Wq : m == 1 ? Wk : m == 2 ? Wv : m == 3 ? Wkg : m == 4 ? Wvg : m == 5 ? Wqg : Wo;
  } else if (bid < 1584) {
    tile = bid - 1008;
    K = H; N = FF;
    ooff = OFF_W1;
    src = W1;
  } else {
    tile = bid - 1584;
    K = FF; N = H;
    ooff = OFF_W2;
    src = W2;
  }
  int KT = K / 64;
  int kt = tile % KT, nt = tile / KT;
  __shared__ u16 sT[64 * 72];
  #pragma unroll
  for (int it = 0; it < 16; ++it) {
    int idx = t + it * 256;
    int n = idx & 63, kk = idx >> 6;
    sT[n * 72 + kk] = f2bf(src[(size_t)(kt * 64 + kk) * N + nt * 64 + n]);
  }
  __syncthreads();
  #pragma unroll
  for (int it = 0; it < 2; ++it) {
    int idx = t + it * 256;
    int n = idx >> 3, k8 = idx & 7;
    us8 val = *reinterpret_cast<const us8*>(&sT[n * 72 + k8 * 8]);
    *reinterpret_cast<us8*>(&wt[ooff + (size_t)(nt * 64 + n) * K + kt * 64 + k8 * 8]) = val;
  }
}

// ---- GEMM K-loop core ----
template<bool GLD>
__device__ __forceinline__ void gemm_loop(
    const u16* __restrict__ A, const u16* __restrict__ Bt,
    int M, int N, int K, int m0, int n0, int kb, int ke,
    u16* lsA, u16* lsB, f32x4 acc[4][4])
{
  int t = threadIdx.x;
  int w = t >> 6, lane = t & 63;
  int cl = lane & 15, kgr = lane >> 4;
  int wm = (w >> 1) * 64, wn = (w & 1) * 64;
  us8 z8 = {0, 0, 0, 0, 0, 0, 0, 0};
  for (int k0 = kb; k0 < ke; k0 += 64) {
    if (GLD) {
      int ml = lane >> 3, k8 = lane & 7;
      #pragma unroll
      for (int it = 0; it < 4; ++it) {
        int chunk = it * 4 + w;
        int m = chunk * 8 + ml;
        gld16(A + (size_t)(m0 + m) * K + k0 + ((k8 ^ (m & 7)) * 8),
              &lsA[chunk * 512 + lane * 8]);
      }
      #pragma unroll
      for (int it = 0; it < 4; ++it) {
        int chunk = it * 4 + w;
        int n = chunk * 8 + ml;
        gld16(Bt + (size_t)(n0 + n) * K + k0 + ((k8 ^ (n & 7)) * 8),
              &lsB[chunk * 512 + lane * 8]);
      }
    } else {
      #pragma unroll
      for (int it = 0; it < 4; ++it) {
        int c = t + it * 256;
        int m = c >> 3, k8 = c & 7;
        us8 val = z8;
        int gm = m0 + m;
        if (gm < M) val = *reinterpret_cast<const us8*>(A + (size_t)gm * K + k0 + k8 * 8);
        *reinterpret_cast<us8*>(&lsA[m * 64 + ((k8 ^ (m & 7)) * 8)]) = val;
      }
      #pragma unroll
      for (int it = 0; it < 4; ++it) {
        int c = t + it * 256;
        int n = c >> 3, k8 = c & 7;
        us8 val = *reinterpret_cast<const us8*>(Bt + (size_t)(n0 + n) * K + k0 + k8 * 8);
        *reinterpret_cast<us8*>(&lsB[n * 64 + ((k8 ^ (n & 7)) * 8)]) = val;
      }
    }
    __syncthreads();
    #pragma unroll
    for (int kk = 0; kk < 2; ++kk) {
      bf16x8 fa[4], fb[4];
      int k8 = kk * 4 + kgr;
      #pragma unroll
      for (int i = 0; i < 4; ++i) {
        int mr = wm + i * 16 + cl;
        fa[i] = __builtin_bit_cast(bf16x8,
            *reinterpret_cast<const us8*>(&lsA[mr * 64 + ((k8 ^ (mr & 7)) * 8)]));
        int nr = wn + i * 16 + cl;
        fb[i] = __builtin_bit_cast(bf16x8,
            *reinterpret_cast<const us8*>(&lsB[nr * 64 + ((k8 ^ (nr & 7)) * 8)]));
      }
      #pragma unroll
      for (int i = 0; i < 4; ++i)
        #pragma unroll
        for (int j = 0; j < 4; ++j)
          acc[i][j] = __builtin_amdgcn_mfma_f32_16x16x32_bf16(fa[i], fb[j], acc[i][j], 0, 0, 0);
    }
    __syncthreads();
  }
}

template<int ACT, bool GLD>
__global__ __launch_bounds__(256) void gemm_bias_k(
    const u16* __restrict__ A, const u16* __restrict__ Bt, const float* __restrict__ bias,
    u16* __restrict__ outB, int M, int N, int K)
{
  __shared__ u16 lsA[128 * 64];
  __shared__ u16 lsB[128 * 64];
  int bx, by;
  tswz(bx, by);
  int m0 = by * 128, n0 = bx * 128;
  f32x4 zero4 = {0.f, 0.f, 0.f, 0.f};
  f32x4 acc[4][4];
  #pragma unroll
  for (int i = 0; i < 4; ++i)
    #pragma unroll
    for (int j = 0; j < 4; ++j) acc[i][j] = zero4;
  gemm_loop<GLD>(A, Bt, M, N, K, m0, n0, 0, K, lsA, lsB, acc);
  int lane = threadIdx.x & 63, w = threadIdx.x >> 6;
  int cl = lane & 15, kgr = lane >> 4;
  int wm = (w >> 1) * 64, wn = (w & 1) * 64;
  #pragma unroll
  for (int j = 0; j < 4; ++j) {
    int n = n0 + wn + j * 16 + cl;
    float bv = bias[n];
    #pragma unroll
    for (int i = 0; i < 4; ++i) {
      #pragma unroll
      for (int r = 0; r < 4; ++r) {
        int m = m0 + wm + i * 16 + kgr * 4 + r;
        if (m < M) {
          float vv = acc[i][j][r] + bv;
          if (ACT == 1) vv = geluf(vv);
          outB[(size_t)m * N + n] = f2bf(vv);
        }
      }
    }
  }
}

__global__ __launch_bounds__(256) void gemm_acc_k(
    const u16* __restrict__ A, const u16* __restrict__ Bt, float* __restrict__ outF,
    int M, int N, int K)
{
  __shared__ u16 lsA[128 * 64];
  __shared__ u16 lsB[128 * 64];
  int bx, by;
  tswz(bx, by);
  int m0 = by * 128, n0 = bx * 128;
  int z = blockIdx.z, ns = gridDim.z;
  int ks = K / ns;
  f32x4 zero4 = {0.f, 0.f, 0.f, 0.f};
  f32x4 acc[4][4];
  #pragma unroll
  for (int i = 0; i < 4; ++i)
    #pragma unroll
    for (int j = 0; j < 4; ++j) acc[i][j] = zero4;
  gemm_loop<true>(A, Bt, M, N, K, m0, n0, z * ks, (z + 1) * ks, lsA, lsB, acc);
  int lane = threadIdx.x & 63, w = threadIdx.x >> 6;
  int cl = lane & 15, kgr = lane >> 4;
  int wm = (w >> 1) * 64, wn = (w & 1) * 64;
  #pragma unroll
  for (int j = 0; j < 4; ++j) {
    int n = n0 + wn + j * 16 + cl;
    #pragma unroll
    for (int i = 0; i < 4; ++i) {
      #pragma unroll
      for (int r = 0; r < 4; ++r) {
        int m = m0 + wm + i * 16 + kgr * 4 + r;
        atomicAdd(&outF[(size_t)m * N + n], acc[i][j][r]);
      }
    }
  }
}

__global__ __launch_bounds__(256) void gemm_qkv_k(
    const u16* __restrict__ A, const u16* __restrict__ wt,
    const float* c0, const float* c1, const float* c2, const float* c3, const float* c4,
    u16* o0, u16* o1, u16* o2, u16* o3, u16* o4)
{
  __shared__ u16 lsA[128 * 64];
  __shared__ u16 lsB[128 * 64];
  int z = blockIdx.z;
  const u16* Bt = wt + (size_t)z * MATSZ;
  const float* bias = z == 0 ? c0 : z == 1 ? c1 : z == 2 ? c2 : z == 3 ? c3 : c4;
  u16* outB = z == 0 ? o0 : z == 1 ? o1 : z == 2 ? o2 : z == 3 ? o3 : o4;
  int bx, by;
  tswz(bx, by);
  int m0 = by * 128, n0 = bx * 128;
  f32x4 zero4 = {0.f, 0.f, 0.f, 0.f};
  f32x4 acc[4][4];
  #pragma unroll
  for (int i = 0; i < 4; ++i)
    #pragma unroll
    for (int j = 0; j < 4; ++j) acc[i][j] = zero4;
  gemm_loop<true>(A, Bt, LL, H, H, m0, n0, 0, H, lsA, lsB, acc);
  int lane = threadIdx.x & 63, w = threadIdx.x >> 6;
  int cl = lane & 15, kgr = lane >> 4;
  int wm = (w >> 1) * 64, wn = (w & 1) * 64;
  #pragma unroll
  for (int j = 0; j < 4; ++j) {
    int n = n0 + wn + j * 16 + cl;
    float bv = bias[n];
    #pragma unroll
    for (int i = 0; i < 4; ++i) {
      #pragma unroll
      for (int r = 0; r < 4; ++r) {
        int m = m0 + wm + i * 16 + kgr * 4 + r;
        outB[(size_t)m * H + n] = f2bf(acc[i][j][r] + bv);
      }
    }
  }
}

// ---------------- MFMA flash local attention (active-chunk version) ----------------
// grid (NH, LL/64). 9 relevant local chunks + 1 global chunk.
// V^T staged via coalesced row loads + in-register transpose; swizzle k8^((dim>>3)&7).
__global__ __launch_bounds__(256) void attn_local_k(
    const u16* __restrict__ q, const u16* __restrict__ k, const u16* __restrict__ v,
    const u16* __restrict__ kgp, const u16* __restrict__ vgp,
    const int* __restrict__ gpos, const unsigned char* __restrict__ isg,
    u16* __restrict__ out)
{
  int h = blockIdx.x;
  int q0 = blockIdx.y * 64;
  int nb = q0 >> 8;
  int cs = (nb - 1) * 256;
  int cstart = (q0 >> 6) & 3;
  int t = threadIdx.x;
  int w = t >> 6, lane = t & 63;
  int cl = lane & 15, g = lane >> 4;
  __shared__ u16 sK[64 * 64];
  __shared__ u16 sVt[64 * 64];
  __shared__ u16 sP[64 * 64];
  __shared__ unsigned char sOk[64];
  us8 z8 = {0, 0, 0, 0, 0, 0, 0, 0};
  f32x4 zero4 = {0.f, 0.f, 0.f, 0.f};

  int qrow = q0 + w * 16 + cl;
  bf16x8 qa[2];
  #pragma unroll
  for (int ks = 0; ks < 2; ++ks)
    qa[ks] = __builtin_bit_cast(bf16x8, *reinterpret_cast<const us8*>(
        &q[(size_t)qrow * H + h * 64 + ks * 32 + g * 8]));

  f32x4 O[4];
  #pragma unroll
  for (int dt = 0; dt < 4; ++dt) O[dt] = zero4;
  float mrow[4], lrow[4];
  #pragma unroll
  for (int r = 0; r < 4; ++r) { mrow[r] = -1e30f; lrow[r] = 0.f; }

  for (int ci = 0; ci < 10; ++ci) {
    bool isLocal = (ci < 9);
    int kbase = cs + (cstart + ci) * 64;   // only meaningful when isLocal
    // ---- stage K [key][dim] ----
    #pragma unroll
    for (int it = 0; it < 2; ++it) {
      int idx = t + it * 256;
      int key = idx >> 3, d8 = idx & 7;
      us8 val = z8;
      if (isLocal) {
        int pos = kbase + key;
        if (pos >= 0 && pos < LL)
          val = *reinterpret_cast<const us8*>(&k[(size_t)pos * H + h * 64 + d8 * 8]);
      } else {
        int pos = gpos[key];
        if (pos < 0) pos = 0;
        if (pos >= LL) pos = LL - 1;
        val = *reinterpret_cast<const us8*>(&kgp[(size_t)pos * H + h * 64 + d8 * 8]);
      }
      *reinterpret_cast<us8*>(&sK[key * 64 + ((d8 ^ (key & 7)) * 8)]) = val;
    }
    // ---- stage V^T: coalesced row load + transposed scalar LDS writes ----
    #pragma unroll
    for (int it = 0; it < 2; ++it) {
      int idx = t + it * 256;
      int key = idx >> 3, d8 = idx & 7;
      us8 val = z8;
      if (isLocal) {
        int pos = kbase + key;
        if (pos >= 0 && pos < LL)
          val = *reinterpret_cast<const us8*>(&v[(size_t)pos * H + h * 64 + d8 * 8]);
      } else {
        int pos = gpos[key];
        if (pos < 0) pos = 0;
        if (pos >= LL) pos = LL - 1;
        val = *reinterpret_cast<const us8*>(&vgp[(size_t)pos * H + h * 64 + d8 * 8]);
      }
      int k8 = key >> 3, klow = key & 7;
      int kswz = (k8 ^ d8) * 8 + klow;     // d8 == (dim>>3)&7 for dims d8*8..d8*8+7
      #pragma unroll
      for (int u = 0; u < 8; ++u)
        sVt[(d8 * 8 + u) * 64 + kswz] = val[u];
    }
    if (t < 64) {
      int ok = 1;
      if (isLocal) {
        int pos = kbase + t;
        ok = (pos >= 0 && pos < LL) ? (isg[pos] ? 0 : 1) : 0;
      }
      sOk[t] = (unsigned char)ok;
    }
    __syncthreads();

    // ---- QK^T ----
    f32x4 S[4];
    #pragma unroll
    for (int T = 0; T < 4; ++T) {
      S[T] = zero4;
      int key = T * 16 + cl;
      #pragma unroll
      for (int ks = 0; ks < 2; ++ks) {
        bf16x8 kf = __builtin_bit_cast(bf16x8, *reinterpret_cast<const us8*>(
            &sK[key * 64 + (((ks * 4 + g) ^ (key & 7)) * 8)]));
        S[T] = __builtin_amdgcn_mfma_f32_16x16x32_bf16(qa[ks], kf, S[T], 0, 0, 0);
      }
    }
    // ---- mask + scale ----
    #pragma unroll
    for (int T = 0; T < 4; ++T) {
      int key = T * 16 + cl;
      int okk = sOk[key];
      int pos = kbase + key;
      #pragma unroll
      for (int r = 0; r < 4; ++r) {
        int qp = q0 + w * 16 + g * 4 + r;
        int d = pos - qp;
        bool ok = okk && (!isLocal || (d >= -256 && d <= 256));
        S[T][r] = ok ? S[T][r] * 0.125f : -1e9f;
      }
    }
    // ---- online softmax ----
    float cm[4];
    #pragma unroll
    for (int r = 0; r < 4; ++r) {
      cm[r] = fmaxf(fmaxf(S[0][r], S[1][r]), fmaxf(S[2][r], S[3][r]));
      cm[r] = fmaxf(cm[r], __shfl_xor(cm[r], 1));
      cm[r] = fmaxf(cm[r], __shfl_xor(cm[r], 2));
      cm[r] = fmaxf(cm[r], __shfl_xor(cm[r], 4));
      cm[r] = fmaxf(cm[r], __shfl_xor(cm[r], 8));
    }
    float sc[4];
    #pragma unroll
    for (int r = 0; r < 4; ++r) {
      float mn = fmaxf(mrow[r], cm[r]);
      sc[r] = __expf(mrow[r] - mn);
      mrow[r] = mn;
    }
    float rs[4] = {0.f, 0.f, 0.f, 0.f};
    #pragma unroll
    for (int T = 0; T < 4; ++T) {
      int key = T * 16 + cl;
      #pragma unroll
      for (int r = 0; r < 4; ++r) {
        float sv = S[T][r];
        float pv = sv > -1e8f ? __expf(sv - mrow[r]) : 0.f;
        rs[r] += pv;
        int qloc = w * 16 + g * 4 + r;
        int k8s = (key >> 3) ^ (qloc & 7);
        sP[qloc * 64 + k8s * 8 + (key & 7)] = f2bf(pv);
      }
    }
    #pragma unroll
    for (int r = 0; r < 4; ++r) {
      rs[r] += __shfl_xor(rs[r], 1);
      rs[r] += __shfl_xor(rs[r], 2);
      rs[r] += __shfl_xor(rs[r], 4);
      rs[r] += __shfl_xor(rs[r], 8);
      lrow[r] = lrow[r] * sc[r] + rs[r];
    }
    #pragma unroll
    for (int dt = 0; dt < 4; ++dt)
      #pragma unroll
      for (int r = 0; r < 4; ++r) O[dt][r] *= sc[r];
    // ---- PV ----
    int prow = w * 16 + cl;
    #pragma unroll
    for (int ks = 0; ks < 2; ++ks) {
      bf16x8 pf = __builtin_bit_cast(bf16x8, *reinterpret_cast<const us8*>(
          &sP[prow * 64 + (((ks * 4 + g) ^ (prow & 7)) * 8)]));
      #pragma unroll
      for (int dt = 0; dt < 4; ++dt) {
        int dim = dt * 16 + cl;
        int k8s = (ks * 4 + g) ^ ((dim >> 3) & 7);
        bf16x8 vf = __builtin_bit_cast(bf16x8, *reinterpret_cast<const us8*>(
            &sVt[dim * 64 + k8s * 8]));
        O[dt] = __builtin_amdgcn_mfma_f32_16x16x32_bf16(pf, vf, O[dt], 0, 0, 0);
      }
    }
    __syncthreads();
  }
  #pragma unroll
  for (int r = 0; r < 4; ++r) {
    float inv = 1.f / lrow[r];
    int qp = q0 + w * 16 + g * 4 + r;
    #pragma unroll
    for (int dt = 0; dt < 4; ++dt)
      out[(size_t)qp * H + h * 64 + dt * 16 + cl] = f2bf(O[dt][r] * inv);
  }
}

// ---------------- global attention ----------------
__global__ __launch_bounds__(256) void ag_score_k(
    const u16* __restrict__ qg, const u16* __restrict__ kg, float* __restrict__ sbuf)
{
  int h = blockIdx.x;
  int kc0 = blockIdx.y * 128;
  int t = threadIdx.x;
  int w = t >> 6, lane = t & 63;
  int cl = lane & 15, g = lane >> 4;
  __shared__ u16 sK[128 * 64];
  #pragma unroll
  for (int it = 0; it < 4; ++it) {
    int c = t + it * 256;
    int key = c >> 3, d8 = c & 7;
    us8 val = *reinterpret_cast<const us8*>(&kg[(size_t)(kc0 + key) * H + h * 64 + d8 * 8]);
    *reinterpret_cast<us8*>(&sK[key * 64 + ((d8 ^ (key & 7)) * 8)]) = val;
  }
  int qrow = w * 16 + cl;
  bf16x8 qa[2];
  #pragma unroll
  for (int ks = 0; ks < 2; ++ks)
    qa[ks] = __builtin_bit_cast(bf16x8, *reinterpret_cast<const us8*>(
        &qg[(size_t)qrow * H + h * 64 + ks * 32 + g * 8]));
  __syncthreads();
  f32x4 zero4 = {0.f, 0.f, 0.f, 0.f};
  #pragma unroll
  for (int j = 0; j < 8; ++j) {
    f32x4 S = zero4;
    int key = j * 16 + cl;
    #pragma unroll
    for (int ks = 0; ks < 2; ++ks) {
      bf16x8 kf = __builtin_bit_cast(bf16x8, *reinterpret_cast<const us8*>(
          &sK[key * 64 + (((ks * 4 + g) ^ (key & 7)) * 8)]));
      S = __builtin_amdgcn_mfma_f32_16x16x32_bf16(qa[ks], kf, S, 0, 0, 0);
    }
    #pragma unroll
    for (int r = 0; r < 4; ++r) {
      int grow = w * 16 + g * 4 + r;
      sbuf[((size_t)(h * 64 + grow)) * 4096 + kc0 + key] = S[r] * 0.125f;
    }
  }
}

__global__ __launch_bounds__(256) void ag_soft_k(float* __restrict__ sbuf)
{
  int row = blockIdx.x, t = threadIdx.x;
  float* base = sbuf + (size_t)row * 4096;
  u16* pb = (u16*)(sbuf) + (size_t)row * 8192;
  __shared__ float red[4];
  f32x4 rv[4];
  #pragma unroll
  for (int it = 0; it < 4; ++it)
    rv[it] = *reinterpret_cast<const f32x4*>(base + it * 1024 + t * 4);
  float m = -1e30f;
  #pragma unroll
  for (int it = 0; it < 4; ++it)
    #pragma unroll
    for (int u = 0; u < 4; ++u) m = fmaxf(m, rv[it][u]);
  m = wredmax(m);
  if ((t & 63) == 0) red[t >> 6] = m;
  __syncthreads();
  m = fmaxf(fmaxf(red[0], red[1]), fmaxf(red[2], red[3]));
  __syncthreads();
  float s = 0.f;
  #pragma unroll
  for (int it = 0; it < 4; ++it)
    #pragma unroll
    for (int u = 0; u < 4; ++u) {
      float e = __expf(rv[it][u] - m);
      rv[it][u] = e;
      s += e;
    }
  s = wredsum(s);
  if ((t & 63) == 0) red[t >> 6] = s;
  __syncthreads();
  float inv = 1.f / (red[0] + red[1] + red[2] + red[3]);
  #pragma unroll
  for (int it = 0; it < 4; ++it) {
    us4 o;
    #pragma unroll
    for (int u = 0; u < 4; ++u) o[u] = f2bf(rv[it][u] * inv);
    *reinterpret_cast<us4*>(pb + it * 1024 + t * 4) = o;
  }
}

__global__ __launch_bounds__(256) void ag_pv_k(
    const float* __restrict__ sbuf, const u16* __restrict__ vg, float* __restrict__ obuf)
{
  int h = blockIdx.x;
  int kb0 = blockIdx.y * 256;
  int t = threadIdx.x;
  int w = t >> 6, lane = t & 63;
  int cl = lane & 15, g = lane >> 4;
  __shared__ u16 sVt[64 * 64];
  f32x4 zero4 = {0.f, 0.f, 0.f, 0.f};
  f32x4 O[4];
  #pragma unroll
  for (int dt = 0; dt < 4; ++dt) O[dt] = zero4;
  const u16* pb = (const u16*)(sbuf);
  int prow = w * 16 + cl;
  size_t pbase = (size_t)(h * 64 + prow) * 8192;

  for (int cc = 0; cc < 4; ++cc) {
    int kc = kb0 + cc * 64;
    // coalesced V row loads + transposed scalar LDS writes (same swizzle as attn_local)
    #pragma unroll
    for (int it = 0; it < 2; ++it) {
      int idx = t + it * 256;
      int key = idx >> 3, d8 = idx & 7;
      us8 val = *reinterpret_cast<const us8*>(&vg[(size_t)(kc + key) * H + h * 64 + d8 * 8]);
      int k8 = key >> 3, klow = key & 7;
      int kswz = (k8 ^ d8) * 8 + klow;
      #pragma unroll
      for (int u = 0; u < 8; ++u)
        sVt[(d8 * 8 + u) * 64 + kswz] = val[u];
    }
    __syncthreads();
    #pragma unroll
    for (int ks = 0; ks < 2; ++ks) {
      bf16x8 pf = __builtin_bit_cast(bf16x8, *reinterpret_cast<const us8*>(
          pb + pbase + kc + (ks * 4 + g) * 8));
      #pragma unroll
      for (int dt = 0; dt < 4; ++dt) {
        int dim = dt * 16 + cl;
        int k8s = (ks * 4 + g) ^ ((dim >> 3) & 7);
        bf16x8 vf = __builtin_bit_cast(bf16x8, *reinterpret_cast<const us8*>(
            &sVt[dim * 64 + k8s * 8]));
        O[dt] = __builtin_amdgcn_mfma_f32_16x16x32_bf16(pf, vf, O[dt], 0, 0, 0);
      }
    }
    __syncthreads();
  }
  #pragma unroll
  for (int r = 0; r < 4; ++r) {
    int grow = w * 16 + g * 4 + r;
    #pragma unroll
    for (int dt = 0; dt < 4; ++dt)
      atomicAdd(&obuf[((size_t)h * 64 + grow) * 64 + dt * 16 + cl], O[dt][r]);
  }
}

__global__ __launch_bounds__(256) void ag_write_k(
    float* __restrict__ obuf, const int* __restrict__ gpos, u16* __restrict__ out)
{
  int g = blockIdx.x, t = threadIdx.x;
  int gp = gpos[g];
  if (gp < 0) gp = 0;
  if (gp >= LL) gp = LL - 1;
  #pragma unroll
  for (int e = 0; e < 3; ++e) {
    int c = t + e * 256;
    int h = c >> 6, d = c & 63;
    size_t idx = ((size_t)h * 64 + g) * 64 + d;
    out[(size_t)gp * H + c] = f2bf(obuf[idx]);
    obuf[idx] = 0.f;
  }
}

// ---------------- misc ----------------
__global__ void isglob_k(const int* __restrict__ gpos, unsigned char* __restrict__ isg) {
  int t = threadIdx.x;
  for (int i = t; i < LL; i += 256) isg[i] = 0;
  __syncthreads();
  if (t < GG) {
    int gp = gpos[t];
    if (gp >= 0 && gp < LL) isg[gp] = 1;
  }
}

__global__ void gather_k(const u16* __restrict__ xb, const int* __restrict__ gpos,
                         u16* __restrict__ xgb) {
  int g = blockIdx.x, t = threadIdx.x;
  int p = gpos[g];
  if (p < 0) p = 0;
  if (p >= LL) p = LL - 1;
  #pragma unroll
  for (int e = 0; e < 3; ++e)
    xgb[(size_t)g * H + t + e * 256] = xb[(size_t)p * H + t + e * 256];
}

__global__ void positions_k(const int* __restrict__ ids, const int* __restrict__ candp,
                            int* __restrict__ posb, float* __restrict__ outp) {
  int t = threadIdx.x;
  int cand = candp[0];
  __shared__ int cnt[257];
  int base = t * 16, c0 = 0;
  for (int u = 0; u < 16; ++u) c0 += (ids[base + u] == cand) ? 1 : 0;
  cnt[t + 1] = c0;
  __syncthreads();
  if (t == 0) {
    cnt[0] = 0;
    for (int i2 = 1; i2 <= 256; ++i2) cnt[i2] += cnt[i2 - 1];
  }
  __syncthreads();
  int ncand = cnt[256];
  int cr = cnt[t];
  for (int u = 0; u < 16; ++u) {
    int i2 = base + u;
    bool isC = (ids[i2] == cand);
    if (isC) {
      if (cr < NCMAX) posb[cr] = i2;
      cr++;
    } else {
      int nc = i2 - cr;
      int slot = ncand + nc;
      if (slot < NCMAX && nc >= 0) posb[slot] = i2;
    }
  }
  if (t < NCMAX) outp[NCMAX + t] = (t < ncand) ? 1.f : 0.f;
}

__global__ __launch_bounds__(256) void head_k(
    const float* __restrict__ x, const int* __restrict__ posb,
    const float* __restrict__ Wh1, const float* __restrict__ bh1,
    const float* __restrict__ Wh2, const float* __restrict__ bh2, float* __restrict__ outp) {
  int s = blockIdx.x, t = threadIdx.x;
  int p = posb[s];
  if (p < 0) p = 0;
  if (p >= LL) p = LL - 1;
  __shared__ float sx[H];
  __shared__ float sh[384];
  __shared__ float red[4];
  #pragma unroll
  for (int e = 0; e < 3; ++e) sx[t + e * 256] = x[(size_t)p * H + t + e * 256];
  __syncthreads();
  for (int j = t; j < 384; j += 256) {
    float a = bh1[j];
    for (int c = 0; c < H; ++c) a += sx[c] * Wh1[(size_t)c * 384 + j];
    sh[j] = geluf(a);
  }
  __syncthreads();
  float part = 0.f;
  for (int j = t; j < 384; j += 256) part += sh[j] * Wh2[j];
  part = wredsum(part);
  if ((t & 63) == 0) red[t >> 6] = part;
  __syncthreads();
  if (t == 0) {
    float tot = red[0] + red[1] + red[2] + red[3] + bh2[0];
    outp[s] = tot;
  }
}

// ---------------- launch ----------------
extern "C" void kernel_launch(void* const* d_in, const int* in_sizes, int n_in,
                              void* d_out, int out_size, void* d_ws, size_t ws_size,
                              hipStream_t stream) {
  const float* emb_tok = (const float*)d_in[0];
  const float* emb_pos = (const float*)d_in[1];
  const float* lnes = (const float*)d_in[2];
  const float* lneb = (const float*)d_in[3];
  const float* Wq = (const float*)d_in[4];
  const float* bq = (const float*)d_in[5];
  const float* Wk = (const float*)d_in[6];
  const float* bk = (const float*)d_in[7];
  const float* Wv = (const float*)d_in[8];
  const float* bv = (const float*)d_in[9];
  const float* Wqg = (const float*)d_in[10];
  const float* bqg = (const float*)d_in[11];
  const float* Wkg = (const float*)d_in[12];
  const float* bkg = (const float*)d_in[13];
  const float* Wvg = (const float*)d_in[14];
  const float* bvg = (const float*)d_in[15];
  const float* Wo = (const float*)d_in[16];
  const float* bo = (const float*)d_in[17];
  const float* ln1s = (const float*)d_in[18];
  const float* ln1b = (const float*)d_in[19];
  const float* W1 = (const float*)d_in[20];
  const float* b1 = (const float*)d_in[21];
  const float* W2 = (const float*)d_in[22];
  const float* b2 = (const float*)d_in[23];
  const float* ln2s = (const float*)d_in[24];
  const float* ln2b = (const float*)d_in[25];
  const float* Wh1 = (const float*)d_in[26];
  const float* bh1 = (const float*)d_in[27];
  const float* Wh2 = (const float*)d_in[28];
  const float* bh2 = (const float*)d_in[29];
  const int* ids = (const int*)d_in[30];
  int i_gpos = 32, i_cand = 33;
  if (!(n_in >= 34 && in_sizes[32] == GG)) {
    if (n_in >= 33 && in_sizes[31] == GG) { i_gpos = 31; i_cand = 32; }
  }
  const int* gpos = (const int*)d_in[i_gpos];
  const int* cand = (const int*)d_in[i_cand];
  float* outp = (float*)d_out;

  char* p = (char*)d_ws;
  auto alloc = [&](size_t bytes) {
    char* r = p;
    p += (bytes + 255) & ~(size_t)255;
    return r;
  };
  float* x = (float*)alloc((size_t)LL * H * 4);
  u16* xb = (u16*)alloc((size_t)LL * H * 2);
  u16* qb = (u16*)alloc((size_t)LL * H * 2);   // hb aliases qb..kgb
  u16* kb = (u16*)alloc((size_t)LL * H * 2);
  u16* vb = (u16*)alloc((size_t)LL * H * 2);
  u16* kgb = (u16*)alloc((size_t)LL * H * 2);
  u16* vgb = (u16*)alloc((size_t)LL * H * 2);
  u16* ob = (u16*)alloc((size_t)LL * H * 2);
  u16* qgb = (u16*)alloc((size_t)GG * H * 2);
  u16* xgb = (u16*)alloc((size_t)GG * H * 2);
  unsigned char* isg = (unsigned char*)alloc(LL);
  int* posb = (int*)alloc(64 * 4);
  u16* wtb = (u16*)alloc(WT_ELEMS * 2);
  float* sbuf = (float*)alloc((size_t)NH * 64 * 4096 * 4);
  float* obuf = (float*)alloc((size_t)NH * 64 * 64 * 4);
  u16* hb = qb;

  // only obuf is read-before-write (ag_pv atomics); everything else is
  // produced before consumption. ag_write re-zeroes obuf per layer.
  hipMemsetAsync(obuf, 0, (size_t)NH * 64 * 64 * 4, stream);

  embed_ln_k<<<LL, 256, 0, stream>>>(emb_tok, emb_pos, ids, lnes, lneb, x, xb);
  isglob_k<<<1, 256, 0, stream>>>(gpos, isg);
  positions_k<<<1, 256, 0, stream>>>(ids, cand, posb, outp);

  dim3 gP2(H / 128, LL / 128, 2);
  dim3 gP4(H / 128, LL / 128, 4);
  dim3 gF(FF / 128, LL / 128);
  dim3 gQKV(H / 128, LL / 128, 5);
  for (int l = 0; l < NL; ++l) {
    size_t lo = (size_t)l * H * H;
    conv_layer_k<<<2160, 256, 0, stream>>>(
        Wq + lo, Wk + lo, Wv + lo, Wkg + lo, Wvg + lo, Wqg + lo, Wo + lo,
        W1 + (size_t)l * H * FF, W2 + (size_t)l * FF * H, wtb);
    gemm_qkv_k<<<gQKV, 256, 0, stream>>>(xb, wtb,
        bq + l * H, bk + l * H, bv + l * H, bkg + l * H, bvg + l * H,
        qb, kb, vb, kgb, vgb);
    gather_k<<<GG, 256, 0, stream>>>(xb, gpos, xgb);
    gemm_bias_k<0, true><<<dim3(H / 128, 1), 256, 0, stream>>>(
        xgb, wtb + OFF_QG, bqg + l * H, qgb, GG, H, H);
    attn_local_k<<<dim3(NH, LL / 64), 256, 0, stream>>>(qb, kb, vb, kgb, vgb, gpos, isg, ob);
    ag_score_k<<<dim3(NH, LL / 128), 256, 0, stream>>>(qgb, kgb, sbuf);
    ag_soft_k<<<NH * 64, 256, 0, stream>>>(sbuf);
    ag_pv_k<<<dim3(NH, LL / 256), 256, 0, stream>>>(sbuf, vgb, obuf);
    ag_write_k<<<GG, 256, 0, stream>>>(obuf, gpos, ob);
    gemm_acc_k<<<gP2, 256, 0, stream>>>(ob, wtb + OFF_O, x, LL, H, H);
    ln_res_k<<<LL, 256, 0, stream>>>(x, bo + l * H, ln1s + l * H, ln1b + l * H, xb);
    gemm_bias_k<1, true><<<gF, 256, 0, stream>>>(
        xb, wtb + OFF_W1, b1 + l * FF, hb, LL, FF, H);
    gemm_acc_k<<<gP4, 256, 0, stream>>>(hb, wtb + OFF_W2, x, LL, H, FF);
    ln_res_k<<<LL, 256, 0, stream>>>(x, b2 + l * H, ln2s + l * H, ln2b + l * H, xb);
  }
  head_k<<<NCMAX, 256, 0, stream>>>(x, posb, Wh1, bh1, Wh2, bh2, outp);
}

// Round 9
// 1459.568 us; speedup vs baseline: 4.2849x; 1.1328x over previous
//
#include <hip/hip_runtime.h>
#include <hip/hip_bf16.h>
#include <math.h>

#define H 768
#define NH 12
#define DH 64
#define NL 6
#define FF 3072
#define LL 4096
#define GG 64
#define NCMAX 32

#define MATSZ (H * H)
#define OFF_QG ((size_t)5 * MATSZ)
#define OFF_O  ((size_t)6 * MATSZ)
#define OFF_W1 ((size_t)7 * MATSZ)
#define OFF_W2 (OFF_W1 + (size_t)H * FF)
#define WT_ELEMS (OFF_W2 + (size_t)FF * H)

typedef unsigned short u16;
typedef __attribute__((ext_vector_type(8))) unsigned short us8;
typedef __attribute__((ext_vector_type(4))) unsigned short us4;
typedef __attribute__((ext_vector_type(8))) __bf16 bf16x8;
typedef __attribute__((ext_vector_type(4))) float f32x4;

__device__ __forceinline__ float bf2f(u16 u) {
  unsigned v = ((unsigned)u) << 16;
  return __builtin_bit_cast(float, v);
}
__device__ __forceinline__ u16 f2bf(float f) {
  unsigned u = __builtin_bit_cast(unsigned, f);
  unsigned r = (u + 0x7fffu + ((u >> 16) & 1u)) >> 16;
  return (u16)r;
}
__device__ __forceinline__ float geluf(float a) {
  return 0.5f * a * (1.f + erff(a * 0.70710678118654752440f));
}
__device__ __forceinline__ float wredsum(float v) {
  #pragma unroll
  for (int o = 32; o; o >>= 1) v += __shfl_xor(v, o);
  return v;
}
__device__ __forceinline__ float wredmax(float v) {
  #pragma unroll
  for (int o = 32; o; o >>= 1) v = fmaxf(v, __shfl_xor(v, o));
  return v;
}
__device__ __forceinline__ void gld16(const u16* g, u16* l) {
  __builtin_amdgcn_global_load_lds(
      (const __attribute__((address_space(1))) unsigned int*)(const void*)g,
      (__attribute__((address_space(3))) unsigned int*)(void*)l, 16, 0, 0);
}
__device__ __forceinline__ void tswz(int& bx, int& by) {
  int nx = gridDim.x, ny = gridDim.y;
  int flat = blockIdx.y * nx + blockIdx.x;
  int nwg = nx * ny;
  if ((nwg & 7) == 0) {
    int c = nwg >> 3;
    flat = (flat & 7) * c + (flat >> 3);
  }
  bx = flat % nx;
  by = flat / nx;
}

// ---------------- embed + LN ----------------
__global__ __launch_bounds__(256) void embed_ln_k(
    const float* __restrict__ et, const float* __restrict__ ep, const int* __restrict__ ids,
    const float* __restrict__ sc, const float* __restrict__ bi,
    float* __restrict__ x, u16* __restrict__ xb)
{
  int r = blockIdx.x, t = threadIdx.x;
  int tok = ids[r];
  if (tok < 0) tok = 0;
  if (tok >= 50272) tok = 50271;
  __shared__ float red[4];
  float v[3];
  #pragma unroll
  for (int e = 0; e < 3; ++e) {
    int c = t + e * 256;
    v[e] = et[(size_t)tok * H + c] + ep[(size_t)r * H + c];
  }
  float s = v[0] + v[1] + v[2];
  s = wredsum(s);
  if ((t & 63) == 0) red[t >> 6] = s;
  __syncthreads();
  float mean = (red[0] + red[1] + red[2] + red[3]) * (1.f / 768.f);
  __syncthreads();
  float q = 0.f;
  #pragma unroll
  for (int e = 0; e < 3; ++e) { float d = v[e] - mean; q += d * d; }
  q = wredsum(q);
  if ((t & 63) == 0) red[t >> 6] = q;
  __syncthreads();
  float var = (red[0] + red[1] + red[2] + red[3]) * (1.f / 768.f);
  float rs = rsqrtf(var + 1e-5f);
  #pragma unroll
  for (int e = 0; e < 3; ++e) {
    int c = t + e * 256;
    float o = (v[e] - mean) * rs * sc[c] + bi[c];
    x[(size_t)r * H + c] = o;
    xb[(size_t)r * H + c] = f2bf(o);
  }
}

// ---------------- LN over x + bias + sum of Z partial buffers ----------------
template<int Z>
__global__ __launch_bounds__(256) void ln_res2_k(
    float* __restrict__ x, const float* __restrict__ part, const float* __restrict__ bias,
    const float* __restrict__ sc, const float* __restrict__ bi, u16* __restrict__ xb)
{
  int r = blockIdx.x, t = threadIdx.x;
  __shared__ float red[4];
  float v[3];
  #pragma unroll
  for (int e = 0; e < 3; ++e) {
    int c = t + e * 256;
    float a = x[(size_t)r * H + c] + bias[c];
    #pragma unroll
    for (int z = 0; z < Z; ++z)
      a += part[(size_t)z * LL * H + (size_t)r * H + c];
    v[e] = a;
  }
  float s = v[0] + v[1] + v[2];
  s = wredsum(s);
  if ((t & 63) == 0) red[t >> 6] = s;
  __syncthreads();
  float mean = (red[0] + red[1] + red[2] + red[3]) * (1.f / 768.f);
  __syncthreads();
  float q = 0.f;
  #pragma unroll
  for (int e = 0; e < 3; ++e) { float d = v[e] - mean; q += d * d; }
  q = wredsum(q);
  if ((t & 63) == 0) red[t >> 6] = q;
  __syncthreads();
  float var = (red[0] + red[1] + red[2] + red[3]) * (1.f / 768.f);
  float rs = rsqrtf(var + 1e-5f);
  #pragma unroll
  for (int e = 0; e < 3; ++e) {
    int c = t + e * 256;
    float o = (v[e] - mean) * rs * sc[c] + bi[c];
    x[(size_t)r * H + c] = o;
    xb[(size_t)r * H + c] = f2bf(o);
  }
}

// ---------------- all-layers weight convert+transpose ----------------
// grid (2160, NL): blockIdx.y = layer
__global__ __launch_bounds__(256) void conv_all_k(
    const float* __restrict__ Wq, const float* __restrict__ Wk, const float* __restrict__ Wv,
    const float* __restrict__ Wkg, const float* __restrict__ Wvg, const float* __restrict__ Wqg,
    const float* __restrict__ Wo, const float* __restrict__ W1, const float* __restrict__ W2,
    u16* __restrict__ wt)
{
  int l = blockIdx.y;
  int bid = blockIdx.x, t = threadIdx.x;
  size_t lo = (size_t)l * MATSZ;
  size_t lf = (size_t)l * H * FF;
  u16* wto = wt + (size_t)l * WT_ELEMS;
  const float* src;
  size_t ooff;
  int K, N, tile;
  if (bid < 1008) {
    int m = bid / 144;
    tile = bid % 144;
    K = H; N = H;
    ooff = (size_t)m * MATSZ;
    src = (m == 0 ? Wq : m == 1 ? Wk : m == 2 ? Wv : m == 3 ? Wkg : m == 4 ? Wvg : m == 5 ? Wqg : Wo) + lo;
  } else if (bid < 1584) {
    tile = bid - 1008;
    K = H; N = FF;
    ooff = OFF_W1;
    src = W1 + lf;
  } else {
    tile = bid - 1584;
    K = FF; N = H;
    ooff = OFF_W2;
    src = W2 + lf;
  }
  int KT = K / 64;
  int kt = tile % KT, nt = tile / KT;
  __shared__ u16 sT[64 * 72];
  #pragma unroll
  for (int it = 0; it < 16; ++it) {
    int idx = t + it * 256;
    int n = idx & 63, kk = idx >> 6;
    sT[n * 72 + kk] = f2bf(src[(size_t)(kt * 64 + kk) * N + nt * 64 + n]);
  }
  __syncthreads();
  #pragma unroll
  for (int it = 0; it < 2; ++it) {
    int idx = t + it * 256;
    int n = idx >> 3, k8 = idx & 7;
    us8 val = *reinterpret_cast<const us8*>(&sT[n * 72 + k8 * 8]);
    *reinterpret_cast<us8*>(&wto[ooff + (size_t)(nt * 64 + n) * K + kt * 64 + k8 * 8]) = val;
  }
}

// ---- GEMM K-loop core (async global_load_lds staging) ----
__device__ __forceinline__ void gemm_loop(
    const u16* __restrict__ A, const u16* __restrict__ Bt,
    int K, int m0, int n0, int kb, int ke,
    u16* lsA, u16* lsB, f32x4 acc[4][4])
{
  int t = threadIdx.x;
  int w = t >> 6, lane = t & 63;
  int cl = lane & 15, kgr = lane >> 4;
  int wm = (w >> 1) * 64, wn = (w & 1) * 64;
  for (int k0 = kb; k0 < ke; k0 += 64) {
    int ml = lane >> 3, k8 = lane & 7;
    #pragma unroll
    for (int it = 0; it < 4; ++it) {
      int chunk = it * 4 + w;
      int m = chunk * 8 + ml;
      gld16(A + (size_t)(m0 + m) * K + k0 + ((k8 ^ (m & 7)) * 8),
            &lsA[chunk * 512 + lane * 8]);
    }
    #pragma unroll
    for (int it = 0; it < 4; ++it) {
      int chunk = it * 4 + w;
      int n = chunk * 8 + ml;
      gld16(Bt + (size_t)(n0 + n) * K + k0 + ((k8 ^ (n & 7)) * 8),
            &lsB[chunk * 512 + lane * 8]);
    }
    __syncthreads();
    #pragma unroll
    for (int kk = 0; kk < 2; ++kk) {
      bf16x8 fa[4], fb[4];
      int k8r = kk * 4 + kgr;
      #pragma unroll
      for (int i = 0; i < 4; ++i) {
        int mr = wm + i * 16 + cl;
        fa[i] = __builtin_bit_cast(bf16x8,
            *reinterpret_cast<const us8*>(&lsA[mr * 64 + ((k8r ^ (mr & 7)) * 8)]));
        int nr = wn + i * 16 + cl;
        fb[i] = __builtin_bit_cast(bf16x8,
            *reinterpret_cast<const us8*>(&lsB[nr * 64 + ((k8r ^ (nr & 7)) * 8)]));
      }
      #pragma unroll
      for (int i = 0; i < 4; ++i)
        #pragma unroll
        for (int j = 0; j < 4; ++j)
          acc[i][j] = __builtin_amdgcn_mfma_f32_16x16x32_bf16(fa[i], fb[j], acc[i][j], 0, 0, 0);
    }
    __syncthreads();
  }
}

// bf16-out GEMM with bias (+opt GELU)
template<int ACT>
__global__ __launch_bounds__(256) void gemm_bias_k(
    const u16* __restrict__ A, const u16* __restrict__ Bt, const float* __restrict__ bias,
    u16* __restrict__ outB, int M, int N, int K)
{
  __shared__ u16 lsA[128 * 64];
  __shared__ u16 lsB[128 * 64];
  int bx, by;
  tswz(bx, by);
  int m0 = by * 128, n0 = bx * 128;
  f32x4 zero4 = {0.f, 0.f, 0.f, 0.f};
  f32x4 acc[4][4];
  #pragma unroll
  for (int i = 0; i < 4; ++i)
    #pragma unroll
    for (int j = 0; j < 4; ++j) acc[i][j] = zero4;
  gemm_loop(A, Bt, K, m0, n0, 0, K, lsA, lsB, acc);
  int lane = threadIdx.x & 63, w = threadIdx.x >> 6;
  int cl = lane & 15, kgr = lane >> 4;
  int wm = (w >> 1) * 64, wn = (w & 1) * 64;
  #pragma unroll
  for (int j = 0; j < 4; ++j) {
    int n = n0 + wn + j * 16 + cl;
    float bv = bias[n];
    #pragma unroll
    for (int i = 0; i < 4; ++i) {
      #pragma unroll
      for (int r = 0; r < 4; ++r) {
        int m = m0 + wm + i * 16 + kgr * 4 + r;
        if (m < M) {
          float vv = acc[i][j][r] + bv;
          if (ACT == 1) vv = geluf(vv);
          outB[(size_t)m * N + n] = f2bf(vv);
        }
      }
    }
  }
}

// split-K GEMM writing f32 partials to part[z][M][N] (pure stores)
__global__ __launch_bounds__(256) void gemm_part_k(
    const u16* __restrict__ A, const u16* __restrict__ Bt, float* __restrict__ part,
    int M, int N, int K)
{
  __shared__ u16 lsA[128 * 64];
  __shared__ u16 lsB[128 * 64];
  int bx, by;
  tswz(bx, by);
  int m0 = by * 128, n0 = bx * 128;
  int z = blockIdx.z, ns = gridDim.z;
  int ks = K / ns;
  f32x4 zero4 = {0.f, 0.f, 0.f, 0.f};
  f32x4 acc[4][4];
  #pragma unroll
  for (int i = 0; i < 4; ++i)
    #pragma unroll
    for (int j = 0; j < 4; ++j) acc[i][j] = zero4;
  gemm_loop(A, Bt, K, m0, n0, z * ks, (z + 1) * ks, lsA, lsB, acc);
  int lane = threadIdx.x & 63, w = threadIdx.x >> 6;
  int cl = lane & 15, kgr = lane >> 4;
  int wm = (w >> 1) * 64, wn = (w & 1) * 64;
  float* po = part + (size_t)z * LL * H;
  #pragma unroll
  for (int j = 0; j < 4; ++j) {
    int n = n0 + wn + j * 16 + cl;
    #pragma unroll
    for (int i = 0; i < 4; ++i) {
      #pragma unroll
      for (int r = 0; r < 4; ++r) {
        int m = m0 + wm + i * 16 + kgr * 4 + r;
        po[(size_t)m * N + n] = acc[i][j][r];
      }
    }
  }
}

// fused 6-way projection GEMM: z<5 -> (q,k,v,kg,vg) from xb; z==5 -> qg from xgb (M=GG)
__global__ __launch_bounds__(256) void gemm_qkv_k(
    const u16* __restrict__ A, const u16* __restrict__ Ag, const u16* __restrict__ wt,
    const float* c0, const float* c1, const float* c2, const float* c3, const float* c4,
    const float* c5,
    u16* o0, u16* o1, u16* o2, u16* o3, u16* o4, u16* o5)
{
  __shared__ u16 lsA[128 * 64];
  __shared__ u16 lsB[128 * 64];
  int z = blockIdx.z;
  int bx, by;
  tswz(bx, by);
  if (z == 5 && by != 0) return;
  const u16* Bt = wt + (size_t)z * MATSZ;
  const float* bias = z == 0 ? c0 : z == 1 ? c1 : z == 2 ? c2 : z == 3 ? c3 : z == 4 ? c4 : c5;
  u16* outB = z == 0 ? o0 : z == 1 ? o1 : z == 2 ? o2 : z == 3 ? o3 : z == 4 ? o4 : o5;
  const u16* Ap = (z == 5) ? Ag : A;
  int M = (z == 5) ? GG : LL;
  int m0 = by * 128, n0 = bx * 128;
  f32x4 zero4 = {0.f, 0.f, 0.f, 0.f};
  f32x4 acc[4][4];
  #pragma unroll
  for (int i = 0; i < 4; ++i)
    #pragma unroll
    for (int j = 0; j < 4; ++j) acc[i][j] = zero4;
  gemm_loop(Ap, Bt, H, m0, n0, 0, H, lsA, lsB, acc);
  int lane = threadIdx.x & 63, w = threadIdx.x >> 6;
  int cl = lane & 15, kgr = lane >> 4;
  int wm = (w >> 1) * 64, wn = (w & 1) * 64;
  #pragma unroll
  for (int j = 0; j < 4; ++j) {
    int n = n0 + wn + j * 16 + cl;
    float bv = bias[n];
    #pragma unroll
    for (int i = 0; i < 4; ++i) {
      #pragma unroll
      for (int r = 0; r < 4; ++r) {
        int m = m0 + wm + i * 16 + kgr * 4 + r;
        if (m < M) outB[(size_t)m * H + n] = f2bf(acc[i][j][r] + bv);
      }
    }
  }
}

// ---------------- MFMA flash local attention ----------------
__global__ __launch_bounds__(256) void attn_local_k(
    const u16* __restrict__ q, const u16* __restrict__ k, const u16* __restrict__ v,
    const u16* __restrict__ kgp, const u16* __restrict__ vgp,
    const int* __restrict__ gpos, const unsigned char* __restrict__ isg,
    u16* __restrict__ out)
{
  int h = blockIdx.x;
  int q0 = blockIdx.y * 64;
  int nb = q0 >> 8;
  int cs = (nb - 1) * 256;
  int cstart = (q0 >> 6) & 3;
  int t = threadIdx.x;
  int w = t >> 6, lane = t & 63;
  int cl = lane & 15, g = lane >> 4;
  __shared__ u16 sK[64 * 64];
  __shared__ u16 sVt[64 * 64];
  __shared__ u16 sP[64 * 64];
  __shared__ unsigned char sOk[64];
  us8 z8 = {0, 0, 0, 0, 0, 0, 0, 0};
  f32x4 zero4 = {0.f, 0.f, 0.f, 0.f};

  int qrow = q0 + w * 16 + cl;
  bf16x8 qa[2];
  #pragma unroll
  for (int ks = 0; ks < 2; ++ks)
    qa[ks] = __builtin_bit_cast(bf16x8, *reinterpret_cast<const us8*>(
        &q[(size_t)qrow * H + h * 64 + ks * 32 + g * 8]));

  f32x4 O[4];
  #pragma unroll
  for (int dt = 0; dt < 4; ++dt) O[dt] = zero4;
  float mrow[4], lrow[4];
  #pragma unroll
  for (int r = 0; r < 4; ++r) { mrow[r] = -1e30f; lrow[r] = 0.f; }

  for (int ci = 0; ci < 10; ++ci) {
    bool isLocal = (ci < 9);
    int kbase = cs + (cstart + ci) * 64;
    // ---- stage K via async gld16: pre-swizzled global src, linear LDS dest.
    // OOB rows are clamped; garbage values are masked before any max/exp.
    #pragma unroll
    for (int it = 0; it < 2; ++it) {
      int idx = it * 256 + t;
      int key = idx >> 3, d8 = idx & 7;
      int pos;
      if (isLocal) {
        pos = kbase + key;
        pos = pos < 0 ? 0 : (pos >= LL ? LL - 1 : pos);
      } else {
        pos = gpos[key];
        pos = pos < 0 ? 0 : (pos >= LL ? LL - 1 : pos);
      }
      const u16* src = (isLocal ? k : kgp) + (size_t)pos * H + h * 64 + ((d8 ^ (key & 7)) * 8);
      gld16(src, &sK[idx * 8]);
    }
    // ---- stage V^T: coalesced row load + transposed scalar LDS writes ----
    #pragma unroll
    for (int it = 0; it < 2; ++it) {
      int idx = t + it * 256;
      int key = idx >> 3, d8 = idx & 7;
      us8 val = z8;
      if (isLocal) {
        int pos = kbase + key;
        if (pos >= 0 && pos < LL)
          val = *reinterpret_cast<const us8*>(&v[(size_t)pos * H + h * 64 + d8 * 8]);
      } else {
        int pos = gpos[key];
        if (pos < 0) pos = 0;
        if (pos >= LL) pos = LL - 1;
        val = *reinterpret_cast<const us8*>(&vgp[(size_t)pos * H + h * 64 + d8 * 8]);
      }
      int k8 = key >> 3, klow = key & 7;
      int kswz = (k8 ^ d8) * 8 + klow;
      #pragma unroll
      for (int u = 0; u < 8; ++u)
        sVt[(d8 * 8 + u) * 64 + kswz] = val[u];
    }
    if (t < 64) {
      int ok = 1;
      if (isLocal) {
        int pos = kbase + t;
        ok = (pos >= 0 && pos < LL) ? (isg[pos] ? 0 : 1) : 0;
      }
      sOk[t] = (unsigned char)ok;
    }
    __syncthreads();

    f32x4 S[4];
    #pragma unroll
    for (int T = 0; T < 4; ++T) {
      S[T] = zero4;
      int key = T * 16 + cl;
      #pragma unroll
      for (int ks = 0; ks < 2; ++ks) {
        bf16x8 kf = __builtin_bit_cast(bf16x8, *reinterpret_cast<const us8*>(
            &sK[key * 64 + (((ks * 4 + g) ^ (key & 7)) * 8)]));
        S[T] = __builtin_amdgcn_mfma_f32_16x16x32_bf16(qa[ks], kf, S[T], 0, 0, 0);
      }
    }
    #pragma unroll
    for (int T = 0; T < 4; ++T) {
      int key = T * 16 + cl;
      int okk = sOk[key];
      int pos = kbase + key;
      #pragma unroll
      for (int r = 0; r < 4; ++r) {
        int qp = q0 + w * 16 + g * 4 + r;
        int d = pos - qp;
        bool ok = okk && (!isLocal || (d >= -256 && d <= 256));
        S[T][r] = ok ? S[T][r] * 0.125f : -1e9f;
      }
    }
    float cm[4];
    #pragma unroll
    for (int r = 0; r < 4; ++r) {
      cm[r] = fmaxf(fmaxf(S[0][r], S[1][r]), fmaxf(S[2][r], S[3][r]));
      cm[r] = fmaxf(cm[r], __shfl_xor(cm[r], 1));
      cm[r] = fmaxf(cm[r], __shfl_xor(cm[r], 2));
      cm[r] = fmaxf(cm[r], __shfl_xor(cm[r], 4));
      cm[r] = fmaxf(cm[r], __shfl_xor(cm[r], 8));
    }
    float sc[4];
    #pragma unroll
    for (int r = 0; r < 4; ++r) {
      float mn = fmaxf(mrow[r], cm[r]);
      sc[r] = __expf(mrow[r] - mn);
      mrow[r] = mn;
    }
    float rs[4] = {0.f, 0.f, 0.f, 0.f};
    #pragma unroll
    for (int T = 0; T < 4; ++T) {
      int key = T * 16 + cl;
      #pragma unroll
      for (int r = 0; r < 4; ++r) {
        float sv = S[T][r];
        float pv = sv > -1e8f ? __expf(sv - mrow[r]) : 0.f;
        rs[r] += pv;
        int qloc = w * 16 + g * 4 + r;
        int k8s = (key >> 3) ^ (qloc & 7);
        sP[qloc * 64 + k8s * 8 + (key & 7)] = f2bf(pv);
      }
    }
    #pragma unroll
    for (int r = 0; r < 4; ++r) {
      rs[r] += __shfl_xor(rs[r], 1);
      rs[r] += __shfl_xor(rs[r], 2);
      rs[r] += __shfl_xor(rs[r], 4);
      rs[r] += __shfl_xor(rs[r], 8);
      lrow[r] = lrow[r] * sc[r] + rs[r];
    }
    #pragma unroll
    for (int dt = 0; dt < 4; ++dt)
      #pragma unroll
      for (int r = 0; r < 4; ++r) O[dt][r] *= sc[r];
    int prow = w * 16 + cl;
    #pragma unroll
    for (int ks = 0; ks < 2; ++ks) {
      bf16x8 pf = __builtin_bit_cast(bf16x8, *reinterpret_cast<const us8*>(
          &sP[prow * 64 + (((ks * 4 + g) ^ (prow & 7)) * 8)]));
      #pragma unroll
      for (int dt = 0; dt < 4; ++dt) {
        int dim = dt * 16 + cl;
        int k8s = (ks * 4 + g) ^ ((dim >> 3) & 7);
        bf16x8 vf = __builtin_bit_cast(bf16x8, *reinterpret_cast<const us8*>(
            &sVt[dim * 64 + k8s * 8]));
        O[dt] = __builtin_amdgcn_mfma_f32_16x16x32_bf16(pf, vf, O[dt], 0, 0, 0);
      }
    }
    __syncthreads();
  }
  #pragma unroll
  for (int r = 0; r < 4; ++r) {
    float inv = 1.f / lrow[r];
    int qp = q0 + w * 16 + g * 4 + r;
    #pragma unroll
    for (int dt = 0; dt < 4; ++dt)
      out[(size_t)qp * H + h * 64 + dt * 16 + cl] = f2bf(O[dt][r] * inv);
  }
}

// ---------------- global attention ----------------
__global__ __launch_bounds__(256) void ag_score_k(
    const u16* __restrict__ qg, const u16* __restrict__ kg, float* __restrict__ sbuf)
{
  int h = blockIdx.x;
  int kc0 = blockIdx.y * 128;
  int t = threadIdx.x;
  int w = t >> 6, lane = t & 63;
  int cl = lane & 15, g = lane >> 4;
  __shared__ u16 sK[128 * 64];
  #pragma unroll
  for (int it = 0; it < 4; ++it) {
    int idx = it * 256 + t;
    int key = idx >> 3, d8 = idx & 7;
    gld16(kg + (size_t)(kc0 + key) * H + h * 64 + ((d8 ^ (key & 7)) * 8), &sK[idx * 8]);
  }
  int qrow = w * 16 + cl;
  bf16x8 qa[2];
  #pragma unroll
  for (int ks = 0; ks < 2; ++ks)
    qa[ks] = __builtin_bit_cast(bf16x8, *reinterpret_cast<const us8*>(
        &qg[(size_t)qrow * H + h * 64 + ks * 32 + g * 8]));
  __syncthreads();
  f32x4 zero4 = {0.f, 0.f, 0.f, 0.f};
  #pragma unroll
  for (int j = 0; j < 8; ++j) {
    f32x4 S = zero4;
    int key = j * 16 + cl;
    #pragma unroll
    for (int ks = 0; ks < 2; ++ks) {
      bf16x8 kf = __builtin_bit_cast(bf16x8, *reinterpret_cast<const us8*>(
          &sK[key * 64 + (((ks * 4 + g) ^ (key & 7)) * 8)]));
      S = __builtin_amdgcn_mfma_f32_16x16x32_bf16(qa[ks], kf, S, 0, 0, 0);
    }
    #pragma unroll
    for (int r = 0; r < 4; ++r) {
      int grow = w * 16 + g * 4 + r;
      sbuf[((size_t)(h * 64 + grow)) * 4096 + kc0 + key] = S[r] * 0.125f;
    }
  }
}

__global__ __launch_bounds__(256) void ag_soft_k(float* __restrict__ sbuf)
{
  int row = blockIdx.x, t = threadIdx.x;
  float* base = sbuf + (size_t)row * 4096;
  u16* pb = (u16*)(sbuf) + (size_t)row * 8192;
  __shared__ float red[4];
  f32x4 rv[4];
  #pragma unroll
  for (int it = 0; it < 4; ++it)
    rv[it] = *reinterpret_cast<const f32x4*>(base + it * 1024 + t * 4);
  float m = -1e30f;
  #pragma unroll
  for (int it = 0; it < 4; ++it)
    #pragma unroll
    for (int u = 0; u < 4; ++u) m = fmaxf(m, rv[it][u]);
  m = wredmax(m);
  if ((t & 63) == 0) red[t >> 6] = m;
  __syncthreads();
  m = fmaxf(fmaxf(red[0], red[1]), fmaxf(red[2], red[3]));
  __syncthreads();
  float s = 0.f;
  #pragma unroll
  for (int it = 0; it < 4; ++it)
    #pragma unroll
    for (int u = 0; u < 4; ++u) {
      float e = __expf(rv[it][u] - m);
      rv[it][u] = e;
      s += e;
    }
  s = wredsum(s);
  if ((t & 63) == 0) red[t >> 6] = s;
  __syncthreads();
  float inv = 1.f / (red[0] + red[1] + red[2] + red[3]);
  #pragma unroll
  for (int it = 0; it < 4; ++it) {
    us4 o;
    #pragma unroll
    for (int u = 0; u < 4; ++u) o[u] = f2bf(rv[it][u] * inv);
    *reinterpret_cast<us4*>(pb + it * 1024 + t * 4) = o;
  }
}

__global__ __launch_bounds__(256) void ag_pv_k(
    const float* __restrict__ sbuf, const u16* __restrict__ vg, float* __restrict__ obuf)
{
  int h = blockIdx.x;
  int kb0 = blockIdx.y * 256;
  int t = threadIdx.x;
  int w = t >> 6, lane = t & 63;
  int cl = lane & 15, g = lane >> 4;
  __shared__ u16 sVt[64 * 64];
  f32x4 zero4 = {0.f, 0.f, 0.f, 0.f};
  f32x4 O[4];
  #pragma unroll
  for (int dt = 0; dt < 4; ++dt) O[dt] = zero4;
  const u16* pb = (const u16*)(sbuf);
  int prow = w * 16 + cl;
  size_t pbase = (size_t)(h * 64 + prow) * 8192;

  for (int cc = 0; cc < 4; ++cc) {
    int kc = kb0 + cc * 64;
    #pragma unroll
    for (int it = 0; it < 2; ++it) {
      int idx = t + it * 256;
      int key = idx >> 3, d8 = idx & 7;
      us8 val = *reinterpret_cast<const us8*>(&vg[(size_t)(kc + key) * H + h * 64 + d8 * 8]);
      int k8 = key >> 3, klow = key & 7;
      int kswz = (k8 ^ d8) * 8 + klow;
      #pragma unroll
      for (int u = 0; u < 8; ++u)
        sVt[(d8 * 8 + u) * 64 + kswz] = val[u];
    }
    __syncthreads();
    #pragma unroll
    for (int ks = 0; ks < 2; ++ks) {
      bf16x8 pf = __builtin_bit_cast(bf16x8, *reinterpret_cast<const us8*>(
          pb + pbase + kc + (ks * 4 + g) * 8));
      #pragma unroll
      for (int dt = 0; dt < 4; ++dt) {
        int dim = dt * 16 + cl;
        int k8s = (ks * 4 + g) ^ ((dim >> 3) & 7);
        bf16x8 vf = __builtin_bit_cast(bf16x8, *reinterpret_cast<const us8*>(
            &sVt[dim * 64 + k8s * 8]));
        O[dt] = __builtin_amdgcn_mfma_f32_16x16x32_bf16(pf, vf, O[dt], 0, 0, 0);
      }
    }
    __syncthreads();
  }
  #pragma unroll
  for (int r = 0; r < 4; ++r) {
    int grow = w * 16 + g * 4 + r;
    #pragma unroll
    for (int dt = 0; dt < 4; ++dt)
      atomicAdd(&obuf[((size_t)h * 64 + grow) * 64 + dt * 16 + cl], O[dt][r]);
  }
}

__global__ __launch_bounds__(256) void ag_write_k(
    float* __restrict__ obuf, const int* __restrict__ gpos, u16* __restrict__ out)
{
  int g = blockIdx.x, t = threadIdx.x;
  int gp = gpos[g];
  if (gp < 0) gp = 0;
  if (gp >= LL) gp = LL - 1;
  #pragma unroll
  for (int e = 0; e < 3; ++e) {
    int c = t + e * 256;
    int h = c >> 6, d = c & 63;
    size_t idx = ((size_t)h * 64 + g) * 64 + d;
    out[(size_t)gp * H + c] = f2bf(obuf[idx]);
    obuf[idx] = 0.f;
  }
}

// ---------------- misc ----------------
__global__ void isglob_k(const int* __restrict__ gpos, unsigned char* __restrict__ isg) {
  int t = threadIdx.x;
  for (int i = t; i < LL; i += 256) isg[i] = 0;
  __syncthreads();
  if (t < GG) {
    int gp = gpos[t];
    if (gp >= 0 && gp < LL) isg[gp] = 1;
  }
}

__global__ void gather_k(const u16* __restrict__ xb, const int* __restrict__ gpos,
                         u16* __restrict__ xgb) {
  int g = blockIdx.x, t = threadIdx.x;
  int p = gpos[g];
  if (p < 0) p = 0;
  if (p >= LL) p = LL - 1;
  #pragma unroll
  for (int e = 0; e < 3; ++e)
    xgb[(size_t)g * H + t + e * 256] = xb[(size_t)p * H + t + e * 256];
}

__global__ void positions_k(const int* __restrict__ ids, const int* __restrict__ candp,
                            int* __restrict__ posb, float* __restrict__ outp) {
  int t = threadIdx.x;
  int cand = candp[0];
  __shared__ int cnt[257];
  int base = t * 16, c0 = 0;
  for (int u = 0; u < 16; ++u) c0 += (ids[base + u] == cand) ? 1 : 0;
  cnt[t + 1] = c0;
  __syncthreads();
  if (t == 0) {
    cnt[0] = 0;
    for (int i2 = 1; i2 <= 256; ++i2) cnt[i2] += cnt[i2 - 1];
  }
  __syncthreads();
  int ncand = cnt[256];
  int cr = cnt[t];
  for (int u = 0; u < 16; ++u) {
    int i2 = base + u;
    bool isC = (ids[i2] == cand);
    if (isC) {
      if (cr < NCMAX) posb[cr] = i2;
      cr++;
    } else {
      int nc = i2 - cr;
      int slot = ncand + nc;
      if (slot < NCMAX && nc >= 0) posb[slot] = i2;
    }
  }
  if (t < NCMAX) outp[NCMAX + t] = (t < ncand) ? 1.f : 0.f;
}

__global__ __launch_bounds__(256) void head_k(
    const float* __restrict__ x, const int* __restrict__ posb,
    const float* __restrict__ Wh1, const float* __restrict__ bh1,
    const float* __restrict__ Wh2, const float* __restrict__ bh2, float* __restrict__ outp) {
  int s = blockIdx.x, t = threadIdx.x;
  int p = posb[s];
  if (p < 0) p = 0;
  if (p >= LL) p = LL - 1;
  __shared__ float sx[H];
  __shared__ float sh[384];
  __shared__ float red[4];
  #pragma unroll
  for (int e = 0; e < 3; ++e) sx[t + e * 256] = x[(size_t)p * H + t + e * 256];
  __syncthreads();
  for (int j = t; j < 384; j += 256) {
    float a = bh1[j];
    for (int c = 0; c < H; ++c) a += sx[c] * Wh1[(size_t)c * 384 + j];
    sh[j] = geluf(a);
  }
  __syncthreads();
  float part = 0.f;
  for (int j = t; j < 384; j += 256) part += sh[j] * Wh2[j];
  part = wredsum(part);
  if ((t & 63) == 0) red[t >> 6] = part;
  __syncthreads();
  if (t == 0) {
    float tot = red[0] + red[1] + red[2] + red[3] + bh2[0];
    outp[s] = tot;
  }
}

// ---------------- launch ----------------
extern "C" void kernel_launch(void* const* d_in, const int* in_sizes, int n_in,
                              void* d_out, int out_size, void* d_ws, size_t ws_size,
                              hipStream_t stream) {
  const float* emb_tok = (const float*)d_in[0];
  const float* emb_pos = (const float*)d_in[1];
  const float* lnes = (const float*)d_in[2];
  const float* lneb = (const float*)d_in[3];
  const float* Wq = (const float*)d_in[4];
  const float* bq = (const float*)d_in[5];
  const float* Wk = (const float*)d_in[6];
  const float* bk = (const float*)d_in[7];
  const float* Wv = (const float*)d_in[8];
  const float* bv = (const float*)d_in[9];
  const float* Wqg = (const float*)d_in[10];
  const float* bqg = (const float*)d_in[11];
  const float* Wkg = (const float*)d_in[12];
  const float* bkg = (const float*)d_in[13];
  const float* Wvg = (const float*)d_in[14];
  const float* bvg = (const float*)d_in[15];
  const float* Wo = (const float*)d_in[16];
  const float* bo = (const float*)d_in[17];
  const float* ln1s = (const float*)d_in[18];
  const float* ln1b = (const float*)d_in[19];
  const float* W1 = (const float*)d_in[20];
  const float* b1 = (const float*)d_in[21];
  const float* W2 = (const float*)d_in[22];
  const float* b2 = (const float*)d_in[23];
  const float* ln2s = (const float*)d_in[24];
  const float* ln2b = (const float*)d_in[25];
  const float* Wh1 = (const float*)d_in[26];
  const float* bh1 = (const float*)d_in[27];
  const float* Wh2 = (const float*)d_in[28];
  const float* bh2 = (const float*)d_in[29];
  const int* ids = (const int*)d_in[30];
  int i_gpos = 32, i_cand = 33;
  if (!(n_in >= 34 && in_sizes[32] == GG)) {
    if (n_in >= 33 && in_sizes[31] == GG) { i_gpos = 31; i_cand = 32; }
  }
  const int* gpos = (const int*)d_in[i_gpos];
  const int* cand = (const int*)d_in[i_cand];
  float* outp = (float*)d_out;

  char* p = (char*)d_ws;
  auto alloc = [&](size_t bytes) {
    char* r = p;
    p += (bytes + 255) & ~(size_t)255;
    return r;
  };
  float* x = (float*)alloc((size_t)LL * H * 4);
  u16* xb = (u16*)alloc((size_t)LL * H * 2);
  u16* qb = (u16*)alloc((size_t)LL * H * 2);   // hb aliases qb..kgb
  u16* kb = (u16*)alloc((size_t)LL * H * 2);
  u16* vb = (u16*)alloc((size_t)LL * H * 2);
  u16* kgb = (u16*)alloc((size_t)LL * H * 2);
  u16* vgb = (u16*)alloc((size_t)LL * H * 2);
  u16* ob = (u16*)alloc((size_t)LL * H * 2);
  u16* qgb = (u16*)alloc((size_t)GG * H * 2);
  u16* xgb = (u16*)alloc((size_t)128 * H * 2);   // 128 rows: qkv z=5 reads 128 rows
  unsigned char* isg = (unsigned char*)alloc(LL);
  int* posb = (int*)alloc(64 * 4);
  u16* wtb = (u16*)alloc((size_t)NL * WT_ELEMS * 2);
  float* sbuf = (float*)alloc((size_t)NH * 64 * 4096 * 4);
  float* obuf = (float*)alloc((size_t)NH * 64 * 64 * 4);
  float* partb = (float*)alloc((size_t)4 * LL * H * 4);
  u16* hb = qb;

  hipMemsetAsync(obuf, 0, (size_t)NH * 64 * 64 * 4, stream);

  conv_all_k<<<dim3(2160, NL), 256, 0, stream>>>(Wq, Wk, Wv, Wkg, Wvg, Wqg, Wo, W1, W2, wtb);
  embed_ln_k<<<LL, 256, 0, stream>>>(emb_tok, emb_pos, ids, lnes, lneb, x, xb);
  isglob_k<<<1, 256, 0, stream>>>(gpos, isg);
  positions_k<<<1, 256, 0, stream>>>(ids, cand, posb, outp);

  dim3 gP2(H / 128, LL / 128, 2);
  dim3 gP4(H / 128, LL / 128, 4);
  dim3 gF(FF / 128, LL / 128);
  dim3 gQKV(H / 128, LL / 128, 6);
  for (int l = 0; l < NL; ++l) {
    u16* wt = wtb + (size_t)l * WT_ELEMS;
    gather_k<<<GG, 256, 0, stream>>>(xb, gpos, xgb);
    gemm_qkv_k<<<gQKV, 256, 0, stream>>>(xb, xgb, wt,
        bq + l * H, bk + l * H, bv + l * H, bkg + l * H, bvg + l * H, bqg + l * H,
        qb, kb, vb, kgb, vgb, qgb);
    attn_local_k<<<dim3(NH, LL / 64), 256, 0, stream>>>(qb, kb, vb, kgb, vgb, gpos, isg, ob);
    ag_score_k<<<dim3(NH, LL / 128), 256, 0, stream>>>(qgb, kgb, sbuf);
    ag_soft_k<<<NH * 64, 256, 0, stream>>>(sbuf);
    ag_pv_k<<<dim3(NH, LL / 256), 256, 0, stream>>>(sbuf, vgb, obuf);
    ag_write_k<<<GG, 256, 0, stream>>>(obuf, gpos, ob);
    gemm_part_k<<<gP2, 256, 0, stream>>>(ob, wt + OFF_O, partb, LL, H, H);
    ln_res2_k<2><<<LL, 256, 0, stream>>>(x, partb, bo + l * H, ln1s + l * H, ln1b + l * H, xb);
    gemm_bias_k<1><<<gF, 256, 0, stream>>>(xb, wt + OFF_W1, b1 + l * FF, hb, LL, FF, H);
    gemm_part_k<<<gP4, 256, 0, stream>>>(hb, wt + OFF_W2, partb, LL, H, FF);
    ln_res2_k<4><<<LL, 256, 0, stream>>>(x, partb, b2 + l * H, ln2s + l * H, ln2b + l * H, xb);
  }
  head_k<<<NCMAX, 256, 0, stream>>>(x, posb, Wh1, bh1, Wh2, bh2, outp);
}